// Round 9
// baseline (322.915 us; speedup 1.0000x reference)
//
#include <hip/hip_runtime.h>
#include <math.h>

#define NH 16
#define TT 1024
#define CC 1024
#define DD 64
#define MM 8192
#define MQ 4
#define MQS (MM / MQ)

typedef __attribute__((ext_vector_type(8))) short short8;
typedef __attribute__((ext_vector_type(4))) float f32x4;

// ---------------- helpers ----------------
__device__ __forceinline__ float wredsum(float x) {
#pragma unroll
  for (int o = 32; o; o >>= 1) x += __shfl_xor(x, o);
  return x;
}
__device__ __forceinline__ unsigned int bf16rn(float x) {
  unsigned int u = __float_as_uint(x);
  return (u + 0x7fffu + ((u >> 16) & 1u)) >> 16;
}
__device__ __forceinline__ float bf16f(unsigned int h) {
  return __uint_as_float(h << 16);
}
// HL layout: element (r,k) of [R][K] matrix; 16B chunks swizzled by r&7 in each 64-elem block
__device__ __forceinline__ size_t hl_off(int r, int k, int K) {
  return (size_t)(r * K + (k & ~63)) * 2 + ((((k >> 3) & 7) ^ (r & 7)) << 4) + ((k & 7) << 1);
}

__device__ __forceinline__ void ins4(float d, int i, float vd[4], int vi[4]) {
  if (d < vd[3] || (d == vd[3] && i < vi[3])) {
    vd[3] = d; vi[3] = i;
#pragma unroll
    for (int s = 3; s > 0; --s) {
      bool sw = (vd[s] < vd[s - 1]) || (vd[s] == vd[s - 1] && vi[s] < vi[s - 1]);
      if (sw) {
        float td = vd[s]; vd[s] = vd[s - 1]; vd[s - 1] = td;
        int ti = vi[s]; vi[s] = vi[s - 1]; vi[s - 1] = ti;
      }
    }
  }
}

// ---------------- staging (global -> LDS direct) ----------------
__device__ __forceinline__ void stage_seg16(const char* gsrc, char* ldst, int lane) {
  __builtin_amdgcn_global_load_lds(
      (const __attribute__((address_space(1))) unsigned int*)(gsrc + lane * 16),
      (__attribute__((address_space(3))) unsigned int*)ldst, 16, 0, 0);
}
__device__ __forceinline__ void stage_rows8(const char* gRow0, size_t gStride, char* lds, int lane) {
  __builtin_amdgcn_global_load_lds(
      (const __attribute__((address_space(1))) unsigned int*)(gRow0 + (size_t)(lane >> 3) * gStride + ((lane & 7) << 4)),
      (__attribute__((address_space(3))) unsigned int*)lds, 16, 0, 0);
}

// ---------------- converts ----------------
__device__ __forceinline__ void conv_chunk(const float* __restrict__ src,
                                           char* __restrict__ hi, char* __restrict__ lo, int gc) {
  int r = gc >> 7, c = gc & 127;  // K=1024: 128 chunks/row
  const float* p = src + ((size_t)r << 10) + (c << 3);
  float4 f0 = *(const float4*)p;
  float4 f1 = *(const float4*)(p + 4);
  float f[8] = {f0.x, f0.y, f0.z, f0.w, f1.x, f1.y, f1.z, f1.w};
  short8 hv, lv;
#pragma unroll
  for (int e = 0; e < 8; ++e) {
    unsigned hb = bf16rn(f[e]);
    hv[e] = (short)hb;
    lv[e] = (short)bf16rn(f[e] - bf16f(hb));
  }
  size_t off = ((size_t)(r << 10) + ((c & ~7) << 3)) * 2 + (((c & 7) ^ (r & 7)) << 4);
  *(short8*)(hi + off) = hv;
  *(short8*)(lo + off) = lv;
}

// fused convert of x (512 blk), Wa (1536 blk), Wp (512 blk)
__global__ void __launch_bounds__(256) convert_all(
    const float* __restrict__ x, char* __restrict__ xhi, char* __restrict__ xlo,
    const float* __restrict__ Wa, char* __restrict__ wahi, char* __restrict__ walo,
    const float* __restrict__ Wp, char* __restrict__ wphi, char* __restrict__ wplo)
{
  int b = blockIdx.x, tid = threadIdx.x;
  if (b < 512) conv_chunk(x, xhi, xlo, b * 256 + tid);
  else if (b < 2048) conv_chunk(Wa, wahi, walo, (b - 512) * 256 + tid);
  else conv_chunk(Wp, wphi, wplo, (b - 2048) * 256 + tid);
}

// ---------------- K_store -> HL(K=64) + pre-scaled norms (-0.5*||K||^2) ----------------
__global__ void __launch_bounds__(256) convert_kernel(
    const float* __restrict__ ks, char* __restrict__ khi,
    char* __restrict__ klo, float* __restrict__ kn2)
{
  int g = blockIdx.x * 256 + threadIdx.x;
  int m = g & (MM - 1);
  const float* src = ks + (size_t)g * DD;
  float nrm = 0.f;
  size_t rowb = (size_t)g * 128;
#pragma unroll
  for (int c = 0; c < 8; ++c) {
    float f[8];
#pragma unroll
    for (int j = 0; j < 8; ++j) {
      f[j] = src[c * 8 + j];
      nrm = fmaf(f[j], f[j], nrm);
    }
    uint4 hv, lv;
    unsigned int hw[4], lw[4];
#pragma unroll
    for (int p = 0; p < 4; ++p) {
      unsigned int h0 = bf16rn(f[2 * p]), h1 = bf16rn(f[2 * p + 1]);
      float r0 = f[2 * p] - bf16f(h0), r1 = f[2 * p + 1] - bf16f(h1);
      hw[p] = h0 | (h1 << 16);
      lw[p] = bf16rn(r0) | (bf16rn(r1) << 16);
    }
    hv.x = hw[0]; hv.y = hw[1]; hv.z = hw[2]; hv.w = hw[3];
    lv.x = lw[0]; lv.y = lw[1]; lv.z = lw[2]; lv.w = lw[3];
    size_t off = rowb + (size_t)(((c ^ (m & 7)) << 4));
    *(uint4*)(khi + off) = hv;
    *(uint4*)(klo + off) = lv;
  }
  kn2[g] = -0.5f * nrm;
}

// ---------------- generic split-bf16 MFMA GEMM: C = scale*(A@B^T)+bias ----------------
__global__ void __launch_bounds__(256) gemm_hl(
    const char* __restrict__ Ahi, const char* __restrict__ Alo, int strideA, int aKb0, int aKbz,
    const char* __restrict__ Bhi, const char* __restrict__ Blo, int strideB, int bKb0, int bKbz,
    int kbBeg, int kbCnt, int kbzStep,
    float* __restrict__ Cf, long long czMul, int ldc,
    char* __restrict__ Chi, char* __restrict__ Clo, int Kc,
    const float* __restrict__ bias, float scale, int causal)
{
  int bx = blockIdx.x, by = blockIdx.y, z = blockIdx.z;
  int n0 = bx * 128, m0 = by * 128;
  if (causal && n0 > m0 + 127) return;
  int tid = threadIdx.x, lane = tid & 63, w = tid >> 6;
  int wr = w >> 1, wc = w & 1;
  __shared__ __align__(16) char smem[65536];
  char* sAhi = smem;
  char* sAlo = smem + 16384;
  char* sBhi = smem + 32768;
  char* sBlo = smem + 49152;
  f32x4 acc[4][4];
#pragma unroll
  for (int i = 0; i < 4; ++i)
#pragma unroll
    for (int j = 0; j < 4; ++j) acc[i][j] = (f32x4){0.f, 0.f, 0.f, 0.f};

  int kb0 = kbBeg + z * kbzStep;
  int lr = lane & 15, lc = lane >> 4;
  for (int i = 0; i < kbCnt; ++i) {
    int kbA = aKb0 + z * aKbz + kb0 + i;
    int kbB = bKb0 + z * bKbz + kb0 + i;
    if (i) __syncthreads();
#pragma unroll
    for (int c8 = 0; c8 < 4; ++c8) {
      int r8 = w * 32 + c8 * 8;
      stage_rows8(Ahi + (size_t)(m0 + r8) * strideA + (size_t)kbA * 128, strideA, sAhi + r8 * 128, lane);
      stage_rows8(Alo + (size_t)(m0 + r8) * strideA + (size_t)kbA * 128, strideA, sAlo + r8 * 128, lane);
      stage_rows8(Bhi + (size_t)(n0 + r8) * strideB + (size_t)kbB * 128, strideB, sBhi + r8 * 128, lane);
      stage_rows8(Blo + (size_t)(n0 + r8) * strideB + (size_t)kbB * 128, strideB, sBlo + r8 * 128, lane);
    }
    __syncthreads();
#pragma unroll
    for (int kh = 0; kh < 2; ++kh) {
      short8 ah[4], al[4], bh[4], bl[4];
#pragma unroll
      for (int f = 0; f < 4; ++f) {
        int ra = wr * 64 + f * 16 + lr;
        int ca = ((kh * 4 + lc) ^ (ra & 7)) << 4;
        ah[f] = *(const short8*)(sAhi + ra * 128 + ca);
        al[f] = *(const short8*)(sAlo + ra * 128 + ca);
        int rb = wc * 64 + f * 16 + lr;
        int cb = ((kh * 4 + lc) ^ (rb & 7)) << 4;
        bh[f] = *(const short8*)(sBhi + rb * 128 + cb);
        bl[f] = *(const short8*)(sBlo + rb * 128 + cb);
      }
#pragma unroll
      for (int mi = 0; mi < 4; ++mi)
#pragma unroll
        for (int nj = 0; nj < 4; ++nj) {
          acc[mi][nj] = __builtin_amdgcn_mfma_f32_16x16x32_bf16(ah[mi], bh[nj], acc[mi][nj], 0, 0, 0);
          acc[mi][nj] = __builtin_amdgcn_mfma_f32_16x16x32_bf16(al[mi], bh[nj], acc[mi][nj], 0, 0, 0);
          acc[mi][nj] = __builtin_amdgcn_mfma_f32_16x16x32_bf16(ah[mi], bl[nj], acc[mi][nj], 0, 0, 0);
        }
    }
  }
#pragma unroll
  for (int mi = 0; mi < 4; ++mi)
#pragma unroll
    for (int nj = 0; nj < 4; ++nj)
#pragma unroll
      for (int r = 0; r < 4; ++r) {
        int m = m0 + wr * 64 + mi * 16 + lc * 4 + r;
        int n = n0 + wc * 64 + nj * 16 + lr;
        float v = acc[mi][nj][r] * scale;
        if (bias) v += bias[n];
        if (Cf) Cf[(size_t)z * czMul + (size_t)m * ldc + n] = v;
        if (Chi) {
          unsigned hb = bf16rn(v);
          *(unsigned short*)(Chi + hl_off(m, n, Kc)) = (unsigned short)hb;
          *(unsigned short*)(Clo + hl_off(m, n, Kc)) = (unsigned short)bf16rn(v - bf16f(hb));
        }
      }
}

// ---------------- reduce qkv K-split(4) partials + bias -> HL ----------------
__global__ void __launch_bounds__(256) reduce_qkv(
    const float* __restrict__ p, const float* __restrict__ bias,
    char* __restrict__ hi, char* __restrict__ lo)
{
  int gc = blockIdx.x * 256 + threadIdx.x;  // 1024*384 chunks of 8
  int t = gc / 384, c = gc - t * 384;
  const float* p0 = p + (size_t)t * 3072 + (c << 3);
  float4 a0 = *(const float4*)(bias + (c << 3));
  float4 a1 = *(const float4*)(bias + (c << 3) + 4);
#pragma unroll
  for (int z = 0; z < 4; ++z) {
    float4 b0 = *(const float4*)(p0 + (size_t)z * 3145728);
    float4 b1 = *(const float4*)(p0 + (size_t)z * 3145728 + 4);
    a0.x += b0.x; a0.y += b0.y; a0.z += b0.z; a0.w += b0.w;
    a1.x += b1.x; a1.y += b1.y; a1.z += b1.z; a1.w += b1.w;
  }
  float f[8] = {a0.x, a0.y, a0.z, a0.w, a1.x, a1.y, a1.z, a1.w};
  short8 hv, lv;
#pragma unroll
  for (int e = 0; e < 8; ++e) {
    unsigned hb = bf16rn(f[e]);
    hv[e] = (short)hb;
    lv[e] = (short)bf16rn(f[e] - bf16f(hb));
  }
  size_t off = ((size_t)t * 3072 + ((c & ~7) << 3)) * 2 + (((c & 7) ^ (t & 7)) << 4);
  *(short8*)(hi + off) = hv;
  *(short8*)(lo + off) = lv;
}

// ---------------- fused QK^T + causal softmax -> att HL + attlast ----------------
// block = (h, 32 q-rows); 8 waves: wr=w>>2 row-group (16 rows), wcg=w&3 col-group (256 cols)
__global__ void __launch_bounds__(512) qk_softmax(
    const char* __restrict__ qhi, const char* __restrict__ qlo,
    char* __restrict__ attB, float* __restrict__ attlast)
{
  int rb = blockIdx.x, h = blockIdx.y;
  int i0 = rb * 32;
  int tid = threadIdx.x, lane = tid & 63, w = tid >> 6;
  int wr = w >> 2, wcg = w & 3;
  int lr = lane & 15, lc = lane >> 4;
  __shared__ float redm[2][16][4];
  __shared__ float reds[2][16][4];

  // q fragments for this wave's 16 rows
  int iq = i0 + wr * 16 + lr;
  short8 ah[2], al[2];
  {
    size_t qb = (size_t)iq * 6144 + h * 128;
#pragma unroll
    for (int kh = 0; kh < 2; ++kh) {
      size_t off = qb + (((kh * 4 + lc) ^ (iq & 7)) << 4);
      ah[kh] = *(const short8*)(qhi + off);
      al[kh] = *(const short8*)(qlo + off);
    }
  }

  f32x4 acc[16];
#pragma unroll
  for (int nt = 0; nt < 16; ++nt) acc[nt] = (f32x4){0.f, 0.f, 0.f, 0.f};

  // causal tile limit for this wave
  int maxj = i0 + 31;
  int rel = maxj - wcg * 256;
  int ntEnd = (rel < 0) ? 0 : ((rel >> 4) + 1);
  if (ntEnd > 16) ntEnd = 16;

  for (int nt = 0; nt < ntEnd; ++nt) {
    int jr = wcg * 256 + nt * 16 + lr;
    size_t kb = (size_t)jr * 6144 + 2048 + h * 128;
    short8 bh[2], bl[2];
#pragma unroll
    for (int kh = 0; kh < 2; ++kh) {
      size_t off = kb + (((kh * 4 + lc) ^ (jr & 7)) << 4);
      bh[kh] = *(const short8*)(qhi + off);
      bl[kh] = *(const short8*)(qlo + off);
    }
#pragma unroll
    for (int kh = 0; kh < 2; ++kh) {
      acc[nt] = __builtin_amdgcn_mfma_f32_16x16x32_bf16(ah[kh], bh[kh], acc[nt], 0, 0, 0);
      acc[nt] = __builtin_amdgcn_mfma_f32_16x16x32_bf16(al[kh], bh[kh], acc[nt], 0, 0, 0);
      acc[nt] = __builtin_amdgcn_mfma_f32_16x16x32_bf16(ah[kh], bl[kh], acc[nt], 0, 0, 0);
    }
  }

  // mask + scale; per-row partial max over this wave's 256 cols
  int iv[4];
  float pmax[4];
#pragma unroll
  for (int r = 0; r < 4; ++r) {
    iv[r] = i0 + wr * 16 + lc * 4 + r;
    pmax[r] = -INFINITY;
  }
#pragma unroll
  for (int nt = 0; nt < 16; ++nt) {
    int j = wcg * 256 + nt * 16 + lr;
#pragma unroll
    for (int r = 0; r < 4; ++r) {
      float v = (j <= iv[r]) ? acc[nt][r] * 0.125f : -INFINITY;
      acc[nt][r] = v;
      pmax[r] = fmaxf(pmax[r], v);
    }
  }
#pragma unroll
  for (int o = 1; o <= 8; o <<= 1)
#pragma unroll
    for (int r = 0; r < 4; ++r) pmax[r] = fmaxf(pmax[r], __shfl_xor(pmax[r], o));
  if (lr == 0) {
#pragma unroll
    for (int r = 0; r < 4; ++r) redm[wr][lc * 4 + r][wcg] = pmax[r];
  }
  __syncthreads();
  float rowm[4];
#pragma unroll
  for (int r = 0; r < 4; ++r) {
    float* q = redm[wr][lc * 4 + r];
    rowm[r] = fmaxf(fmaxf(q[0], q[1]), fmaxf(q[2], q[3]));
  }

  // exp + per-row partial sum
  float psum[4] = {0.f, 0.f, 0.f, 0.f};
#pragma unroll
  for (int nt = 0; nt < 16; ++nt)
#pragma unroll
    for (int r = 0; r < 4; ++r) {
      float e = __expf(acc[nt][r] - rowm[r]);
      acc[nt][r] = e;
      psum[r] += e;
    }
#pragma unroll
  for (int o = 1; o <= 8; o <<= 1)
#pragma unroll
    for (int r = 0; r < 4; ++r) psum[r] += __shfl_xor(psum[r], o);
  if (lr == 0) {
#pragma unroll
    for (int r = 0; r < 4; ++r) reds[wr][lc * 4 + r][wcg] = psum[r];
  }
  __syncthreads();
  float inv[4];
#pragma unroll
  for (int r = 0; r < 4; ++r) {
    float* q = reds[wr][lc * 4 + r];
    inv[r] = 1.0f / (q[0] + q[1] + q[2] + q[3]);
  }

  // normalize, convert to HL, store (+ attlast for row 1023)
#pragma unroll
  for (int r = 0; r < 4; ++r) {
    size_t rowbase = ((size_t)h << 22) + ((size_t)iv[r] << 12);
    int s = iv[r] & 7;
#pragma unroll
    for (int nt = 0; nt < 16; ++nt) {
      int j = wcg * 256 + nt * 16 + lr;
      float v = acc[nt][r] * inv[r];
      unsigned hb = bf16rn(v);
      unsigned lb = bf16rn(v - bf16f(hb));
      size_t off = rowbase + (size_t)(((wcg << 2) + (nt >> 2)) << 7)
                 + (size_t)(((((nt & 3) << 1) | (lr >> 3)) ^ s) << 4) + ((lr & 7) << 1);
      *(unsigned short*)(attB + off) = (unsigned short)hb;
      *(unsigned short*)(attB + off + 2048) = (unsigned short)lb;
      if (iv[r] == 1023) attlast[(h << 10) + j] = v;
    }
  }
}

// ---------------- MFMA distance + top-4 (rank on acc; kn folded into C-init) ----------------
#define BUFB 16384
__global__ void __launch_bounds__(256, 4) topk_mfma(
    const char* __restrict__ qhi, const char* __restrict__ qlo,
    const char* __restrict__ khi, const char* __restrict__ klo,
    const float* __restrict__ kn2, float* __restrict__ pd, int* __restrict__ pi)
{
  int bid = blockIdx.x;
  int h = bid & 15, ttile = (bid >> 4) & 15, mq = bid >> 8;
  int tid = threadIdx.x, lane = tid & 63, w = tid >> 6;
  int t0 = ttile * 64 + w * 16;
  __shared__ __align__(16) char smem[2 * BUFB];

  short8 bhi[2], blo[2];
  {
    int t = t0 + (lane & 15);
    size_t rb = (size_t)t * 6144 + 2048 + h * 128;
#pragma unroll
    for (int kh = 0; kh < 2; ++kh) {
      int chunk = kh * 4 + (lane >> 4);
      size_t off = rb + ((chunk ^ (t & 7)) << 4);
      bhi[kh] = *(const short8*)(qhi + off);
      blo[kh] = *(const short8*)(qlo + off);
    }
  }

  const char* ghi = khi + ((size_t)h * MM + (size_t)mq * MQS) * 128;
  const char* glo = klo + ((size_t)h * MM + (size_t)mq * MQS) * 128;
  const float* gk2 = kn2 + (size_t)h * MM + (size_t)mq * MQS + ((lane >> 4) << 2);

  float ba[4] = {-3.0e38f, -3.0e38f, -3.0e38f, -3.0e38f};
  int   bi_[4] = {-1, -1, -1, -1};

  {
#pragma unroll
    for (int i2 = 0; i2 < 4; ++i2) {
      int s = w * 4 + i2;
      const char* src = (s < 8) ? (ghi + s * 1024) : (glo + (s - 8) * 1024);
      stage_seg16(src, smem + s * 1024, lane);
    }
  }
  __syncthreads();

  int buf = 0;
  const int NIT = MQS / 64;  // 32
  for (int it = 0; it < NIT; ++it) {
    char* cb = smem + buf * BUFB;
    if (it < NIT - 1) {
      char* nb = smem + (buf ^ 1) * BUFB;
      const char* bh = ghi + (size_t)(it + 1) * 8192;
      const char* bl = glo + (size_t)(it + 1) * 8192;
#pragma unroll
      for (int i2 = 0; i2 < 4; ++i2) {
        int s = w * 4 + i2;
        const char* src = (s < 8) ? (bh + s * 1024) : (bl + (s - 8) * 1024);
        stage_seg16(src, nb + s * 1024, lane);
      }
    }

    f32x4 acc[4];
#pragma unroll
    for (int ms = 0; ms < 4; ++ms)
      acc[ms] = *(const f32x4*)(gk2 + it * 64 + ms * 16);
#pragma unroll
    for (int ms = 0; ms < 4; ++ms) {
      int mloc = ms * 16 + (lane & 15);
      short8 ah[2], al[2];
#pragma unroll
      for (int kh = 0; kh < 2; ++kh) {
        int c = kh * 4 + (lane >> 4);
        int off = mloc * 128 + (((c ^ (mloc & 7)) << 4));
        ah[kh] = *(const short8*)(cb + off);
        al[kh] = *(const short8*)(cb + 8192 + off);
      }
#pragma unroll
      for (int kh = 0; kh < 2; ++kh) {
        acc[ms] = __builtin_amdgcn_mfma_f32_16x16x32_bf16(ah[kh], bhi[kh], acc[ms], 0, 0, 0);
        acc[ms] = __builtin_amdgcn_mfma_f32_16x16x32_bf16(al[kh], bhi[kh], acc[ms], 0, 0, 0);
        acc[ms] = __builtin_amdgcn_mfma_f32_16x16x32_bf16(ah[kh], blo[kh], acc[ms], 0, 0, 0);
      }
    }

    float pk[16];
#pragma unroll
    for (int ms = 0; ms < 4; ++ms)
#pragma unroll
      for (int r = 0; r < 4; ++r) {
        unsigned u = __float_as_uint(acc[ms][r]);
        pk[ms * 4 + r] = __uint_as_float((u & ~15u) | (unsigned)(ms * 4 + r));
      }
    float mx = pk[0];
#pragma unroll
    for (int c = 1; c < 16; ++c) mx = fmaxf(mx, pk[c]);

    int mg0 = mq * MQS + it * 64 + ((lane >> 4) << 2);
    while (mx > ba[3]) {
      unsigned pb = __float_as_uint(mx);
      int cl = pb & 15;
      ba[3] = mx; bi_[3] = mg0 + ((cl & 12) << 2) + (cl & 3);
#pragma unroll
      for (int s = 3; s > 0; --s) {
        if (ba[s] > ba[s - 1]) {
          float td = ba[s]; ba[s] = ba[s - 1]; ba[s - 1] = td;
          int ti = bi_[s]; bi_[s] = bi_[s - 1]; bi_[s - 1] = ti;
        }
      }
#pragma unroll
      for (int c2 = 0; c2 < 16; ++c2)
        if (pk[c2] == mx) pk[c2] = -3.0e38f;
      mx = pk[0];
#pragma unroll
      for (int c2 = 1; c2 < 16; ++c2) mx = fmaxf(mx, pk[c2]);
    }

    __syncthreads();
    buf ^= 1;
  }

  float bd[4];
#pragma unroll
  for (int s = 0; s < 4; ++s) bd[s] = ba[s] * -2.0f;
#pragma unroll
  for (int st = 16; st <= 32; st <<= 1) {
    float sd[4]; int si[4];
#pragma unroll
    for (int s = 0; s < 4; ++s) {
      sd[s] = __shfl_xor(bd[s], st);
      si[s] = __shfl_xor(bi_[s], st);
    }
#pragma unroll
    for (int s = 0; s < 4; ++s) ins4(sd[s], si[s], bd, bi_);
  }
  if (lane < 16) {
    size_t o = (((size_t)mq * NH + h) * TT + (t0 + lane)) * 4;
#pragma unroll
    for (int s = 0; s < 4; ++s) { pd[o + s] = bd[s]; pi[o + s] = bi_[s]; }
  }
}

// ---------------- kNN attend (fused 4-way quarter merge; writes v_new^T in HL) ----------------
__global__ void __launch_bounds__(256) knn_attend(
    const char* __restrict__ qhi, const char* __restrict__ qlo,
    const float* __restrict__ attlast,
    const float* __restrict__ pd, const int* __restrict__ pi,
    const float* __restrict__ kstore, const float* __restrict__ vstore,
    char* __restrict__ vThi, char* __restrict__ vTlo)
{
  int gw = (blockIdx.x * 256 + threadIdx.x) >> 6;
  int lane = threadIdx.x & 63;
  int h = gw >> 10, t = gw & 1023;
  int g = (h << 10) + t;

  float fd[4]; int fi[4];
  {
    size_t o = ((size_t)(lane & 3) * (NH * TT) + g) * 4;
#pragma unroll
    for (int s = 0; s < 4; ++s) { fd[s] = pd[o + s]; fi[s] = pi[o + s]; }
#pragma unroll
    for (int st = 1; st <= 2; st <<= 1) {
      float sd[4]; int si[4];
#pragma unroll
      for (int s = 0; s < 4; ++s) {
        sd[s] = __shfl_xor(fd[s], st);
        si[s] = __shfl_xor(fi[s], st);
      }
#pragma unroll
      for (int s = 0; s < 4; ++s) ins4(sd[s], si[s], fd, fi);
    }
  }

  int sw = ((lane >> 3) ^ (t & 7)) << 4;
  int o2 = (lane & 7) << 1;
  size_t rb = (size_t)t * 6144;
  size_t offq = rb + h * 128 + sw + o2;
  float q = bf16f(*(const unsigned short*)(qhi + offq)) + bf16f(*(const unsigned short*)(qlo + offq));
  size_t offk = offq + 2048;
  float k = bf16f(*(const unsigned short*)(qhi + offk)) + bf16f(*(const unsigned short*)(qlo + offk));
  size_t offv = offq + 4096;
  float v = bf16f(*(const unsigned short*)(qhi + offv)) + bf16f(*(const unsigned short*)(qlo + offv));
  float al = attlast[g];
  bool sel = al >= (1.0f / 8192.0f);

  float attf[5], vf[5];
  attf[0] = wredsum(q * k) * 0.125f;
  vf[0] = v;
#pragma unroll
  for (int s = 1; s < 5; ++s) {
    int m = fi[s - 1];
    const float* kp = kstore + ((size_t)h * MM + m) * DD;
    const float* vp = vstore + ((size_t)h * MM + m) * DD;
    attf[s] = wredsum(q * kp[lane]) * 0.125f;
    vf[s] = vp[lane];
  }
  float mx = attf[0];
#pragma unroll
  for (int s = 1; s < 5; ++s) mx = fmaxf(mx, attf[s]);
  float wgt[5], sum = 0.f;
#pragma unroll
  for (int s = 0; s < 5; ++s) { wgt[s] = __expf(attf[s] - mx); sum += wgt[s]; }
  float inv = 1.0f / sum;
  float vals = 0.f;
#pragma unroll
  for (int s = 0; s < 5; ++s) vals = fmaf(wgt[s] * inv, vf[s], vals);
  float r = 0.5f * vals + 0.5f * v;
  float vn = sel ? r : v;

  unsigned hb = bf16rn(vn);
  size_t off = hl_off((h << 6) + lane, t, 1024);
  *(unsigned short*)(vThi + off) = (unsigned short)hb;
  *(unsigned short*)(vTlo + off) = (unsigned short)bf16rn(vn - bf16f(hb));
}

// ---------------- att(HL) @ vnewT -> yhl ----------------
__global__ void __launch_bounds__(256) gemm_attv(
    const char* __restrict__ attB, const char* __restrict__ vThi, const char* __restrict__ vTlo,
    char* __restrict__ Yhi, char* __restrict__ Ylo)
{
  int h = blockIdx.y, m0 = blockIdx.x * 128;
  const char* aBase = attB + (size_t)h * 4194304;
  int tid = threadIdx.x, lane = tid & 63, w = tid >> 6;
  int wr = w >> 1, wc = w & 1;
  __shared__ __align__(16) char smem[49152];
  char* sAhi = smem;
  char* sAlo = smem + 16384;
  char* sBhi = smem + 32768;
  char* sBlo = smem + 40960;
  f32x4 acc[4][2];
#pragma unroll
  for (int i = 0; i < 4; ++i)
#pragma unroll
    for (int j = 0; j < 2; ++j) acc[i][j] = (f32x4){0.f, 0.f, 0.f, 0.f};
  int lr = lane & 15, lc = lane >> 4;
  for (int kb = 0; kb < 16; ++kb) {
    if (kb) __syncthreads();
#pragma unroll
    for (int c8 = 0; c8 < 4; ++c8) {
      int r8 = w * 32 + c8 * 8;
      stage_rows8(aBase + (size_t)(m0 + r8) * 4096 + (size_t)kb * 128, 4096, sAhi + r8 * 128, lane);
      stage_rows8(aBase + (size_t)(m0 + r8) * 4096 + 2048 + (size_t)kb * 128, 4096, sAlo + r8 * 128, lane);
    }
#pragma unroll
    for (int c8 = 0; c8 < 2; ++c8) {
      int r8 = w * 16 + c8 * 8;
      stage_rows8(vThi + (size_t)((h << 6) + r8) * 2048 + (size_t)kb * 128, 2048, sBhi + r8 * 128, lane);
      stage_rows8(vTlo + (size_t)((h << 6) + r8) * 2048 + (size_t)kb * 128, 2048, sBlo + r8 * 128, lane);
    }
    __syncthreads();
#pragma unroll
    for (int kh = 0; kh < 2; ++kh) {
      short8 ah[4], al[4], bh[2], bl[2];
#pragma unroll
      for (int f = 0; f < 4; ++f) {
        int ra = wr * 64 + f * 16 + lr;
        int ca = ((kh * 4 + lc) ^ (ra & 7)) << 4;
        ah[f] = *(const short8*)(sAhi + ra * 128 + ca);
        al[f] = *(const short8*)(sAlo + ra * 128 + ca);
      }
#pragma unroll
      for (int f = 0; f < 2; ++f) {
        int rbr = wc * 32 + f * 16 + lr;
        int cb = ((kh * 4 + lc) ^ (rbr & 7)) << 4;
        bh[f] = *(const short8*)(sBhi + rbr * 128 + cb);
        bl[f] = *(const short8*)(sBlo + rbr * 128 + cb);
      }
#pragma unroll
      for (int mi = 0; mi < 4; ++mi)
#pragma unroll
        for (int nj = 0; nj < 2; ++nj) {
          acc[mi][nj] = __builtin_amdgcn_mfma_f32_16x16x32_bf16(ah[mi], bh[nj], acc[mi][nj], 0, 0, 0);
          acc[mi][nj] = __builtin_amdgcn_mfma_f32_16x16x32_bf16(al[mi], bh[nj], acc[mi][nj], 0, 0, 0);
          acc[mi][nj] = __builtin_amdgcn_mfma_f32_16x16x32_bf16(ah[mi], bl[nj], acc[mi][nj], 0, 0, 0);
        }
    }
  }
#pragma unroll
  for (int mi = 0; mi < 4; ++mi)
#pragma unroll
    for (int nj = 0; nj < 2; ++nj)
#pragma unroll
      for (int r = 0; r < 4; ++r) {
        int m = m0 + wr * 64 + mi * 16 + lc * 4 + r;
        int n = (h << 6) + wc * 32 + nj * 16 + lr;
        float v = acc[mi][nj][r];
        unsigned hb = bf16rn(v);
        *(unsigned short*)(Yhi + hl_off(m, n, 1024)) = (unsigned short)hb;
        *(unsigned short*)(Ylo + hl_off(m, n, 1024)) = (unsigned short)bf16rn(v - bf16f(hb));
      }
}

// ---------------- reduce proj K-split partials + bias ----------------
__global__ void __launch_bounds__(256) reduce_bias(
    const float* __restrict__ p, const float* __restrict__ bias, float* __restrict__ out)
{
  int i4 = blockIdx.x * 256 + threadIdx.x;
  const float4* P = (const float4*)p;
  float4 a = P[i4], b = P[i4 + 262144], c = P[i4 + 524288], d = P[i4 + 786432];
  float4 bb = ((const float4*)bias)[i4 & 255];
  float4 o;
  o.x = a.x + b.x + c.x + d.x + bb.x;
  o.y = a.y + b.y + c.y + d.y + bb.y;
  o.z = a.z + b.z + c.z + d.z + bb.z;
  o.w = a.w + b.w + c.w + d.w + bb.w;
  ((float4*)out)[i4] = o;
}

// ---------------- launch ----------------
extern "C" void kernel_launch(void* const* d_in, const int* in_sizes, int n_in,
                              void* d_out, int out_size, void* d_ws, size_t ws_size,
                              hipStream_t stream) {
  (void)in_sizes; (void)n_in; (void)out_size; (void)ws_size;
  const float* x  = (const float*)d_in[0];
  const float* Wa = (const float*)d_in[1];
  const float* ba = (const float*)d_in[2];
  const float* Wp = (const float*)d_in[3];
  const float* bp = (const float*)d_in[4];
  const float* Ks = (const float*)d_in[5];
  const float* Vs = (const float*)d_in[6];
  float* out = (float*)d_out;

  char* base = (char*)d_ws;
  char* xhi  = base;
  char* xlo  = base + 0x200000;
  char* wahi = base + 0x400000;
  char* walo = base + 0xA00000;
  char* khi  = base + 0x1000000;
  char* klo  = base + 0x2000000;
  float* qkvp = (float*)(base + 0x1000000);  // 4 x 12 MB partials overlay khl (written later)
  char*  attB = base;                        // att HL (h*4MB + i*4KB; hi 2KB + lo 2KB)
  float* pout = (float*)base;
  char* tail = base + 0x4000000;
  char* qhi = tail;
  char* qlo = tail + 0x600000;
  float* attlast = (float*)(tail + 0xC00000);
  float* kn2     = (float*)(tail + 0xC10000);
  float* pd      = (float*)(tail + 0xC90000);
  int*   pi      = (int*)(tail + 0xE90000);
  char* vThi = tail + 0x1090000;
  char* vTlo = tail + 0x1290000;
  char* yhi  = tail + 0x1490000;
  char* ylo  = tail + 0x1690000;
  char* wphi = tail + 0x1890000;
  char* wplo = tail + 0x1A90000;

  // 1) fused convert of x, Wa, Wp
  hipLaunchKernelGGL(convert_all, dim3(2560), dim3(256), 0, stream,
                     x, xhi, xlo, Wa, wahi, walo, Wp, wphi, wplo);
  // 2) qkv = x @ Wa^T (K-split 4, f32 partials into khl region)
  hipLaunchKernelGGL(gemm_hl, dim3(24, 8, 4), dim3(256), 0, stream,
                     (const char*)xhi, (const char*)xlo, 2048, 0, 0,
                     (const char*)wahi, (const char*)walo, 2048, 0, 0,
                     0, 4, 4,
                     qkvp, 3145728LL, 3072,
                     (char*)nullptr, (char*)nullptr, 0,
                     (const float*)nullptr, 1.0f, 0);
  // 3) reduce partials + bias -> qhl
  hipLaunchKernelGGL(reduce_qkv, dim3(1536), dim3(256), 0, stream, qkvp, ba, qhi, qlo);
  // 4) K_store -> khl + pre-scaled norms (overwrites partials)
  hipLaunchKernelGGL(convert_kernel, dim3(NH * MM / 256), dim3(256), 0, stream, Ks, khi, klo, kn2);
  // 5) top-4 over key store (partial per M-quarter; merged inside knn_attend)
  hipLaunchKernelGGL(topk_mfma, dim3(16 * 16 * MQ), dim3(256), 0, stream,
                     (const char*)qhi, (const char*)qlo, (const char*)khi, (const char*)klo,
                     kn2, pd, pi);
  // 6) fused QK^T + causal softmax -> att HL + attlast
  hipLaunchKernelGGL(qk_softmax, dim3(32, 16), dim3(512), 0, stream,
                     (const char*)qhi, (const char*)qlo, attB, attlast);
  // 7) kNN attend (fused quarter merge; writes v_new^T HL directly)
  hipLaunchKernelGGL(knn_attend, dim3(NH * TT / 4), dim3(256), 0, stream,
                     (const char*)qhi, (const char*)qlo, attlast, pd, pi, Ks, Vs, vThi, vTlo);
  // 8) y = att @ v_new -> yhl
  hipLaunchKernelGGL(gemm_attv, dim3(8, 16), dim3(256), 0, stream,
                     (const char*)attB, (const char*)vThi, (const char*)vTlo, yhi, ylo);
  // 9) out = y @ Wp^T + bp (K-split 4 + reduce)
  hipLaunchKernelGGL(gemm_hl, dim3(8, 8, 4), dim3(256), 0, stream,
                     (const char*)yhi, (const char*)ylo, 2048, 0, 0,
                     (const char*)wphi, (const char*)wplo, 2048, 0, 0,
                     0, 4, 4,
                     pout, 1048576LL, 1024,
                     (char*)nullptr, (char*)nullptr, 0,
                     (const float*)nullptr, 1.0f, 0);
  hipLaunchKernelGGL(reduce_bias, dim3(1024), dim3(256), 0, stream, pout, bp, out);
}

// Round 10
// 310.913 us; speedup vs baseline: 1.0386x; 1.0386x over previous
//
#include <hip/hip_runtime.h>
#include <math.h>

#define NH 16
#define TT 1024
#define CC 1024
#define DD 64
#define MM 8192
#define MQ 4
#define MQS (MM / MQ)

typedef __attribute__((ext_vector_type(8))) short short8;
typedef __attribute__((ext_vector_type(4))) float f32x4;

// ---------------- helpers ----------------
__device__ __forceinline__ float wredsum(float x) {
#pragma unroll
  for (int o = 32; o; o >>= 1) x += __shfl_xor(x, o);
  return x;
}
__device__ __forceinline__ unsigned int bf16rn(float x) {
  unsigned int u = __float_as_uint(x);
  return (u + 0x7fffu + ((u >> 16) & 1u)) >> 16;
}
__device__ __forceinline__ float bf16f(unsigned int h) {
  return __uint_as_float(h << 16);
}
// HL layout: element (r,k) of [R][K] matrix; 16B chunks swizzled by r&7 in each 64-elem block
__device__ __forceinline__ size_t hl_off(int r, int k, int K) {
  return (size_t)(r * K + (k & ~63)) * 2 + ((((k >> 3) & 7) ^ (r & 7)) << 4) + ((k & 7) << 1);
}

__device__ __forceinline__ void ins4(float d, int i, float vd[4], int vi[4]) {
  if (d < vd[3] || (d == vd[3] && i < vi[3])) {
    vd[3] = d; vi[3] = i;
#pragma unroll
    for (int s = 3; s > 0; --s) {
      bool sw = (vd[s] < vd[s - 1]) || (vd[s] == vd[s - 1] && vi[s] < vi[s - 1]);
      if (sw) {
        float td = vd[s]; vd[s] = vd[s - 1]; vd[s - 1] = td;
        int ti = vi[s]; vi[s] = vi[s - 1]; vi[s - 1] = ti;
      }
    }
  }
}

// ---------------- staging (global -> LDS direct) ----------------
__device__ __forceinline__ void stage_seg16(const char* gsrc, char* ldst, int lane) {
  __builtin_amdgcn_global_load_lds(
      (const __attribute__((address_space(1))) unsigned int*)(gsrc + lane * 16),
      (__attribute__((address_space(3))) unsigned int*)ldst, 16, 0, 0);
}
__device__ __forceinline__ void stage_rows8(const char* gRow0, size_t gStride, char* lds, int lane) {
  __builtin_amdgcn_global_load_lds(
      (const __attribute__((address_space(1))) unsigned int*)(gRow0 + (size_t)(lane >> 3) * gStride + ((lane & 7) << 4)),
      (__attribute__((address_space(3))) unsigned int*)lds, 16, 0, 0);
}

// ---------------- converts ----------------
__device__ __forceinline__ void conv_chunk(const float* __restrict__ src,
                                           char* __restrict__ hi, char* __restrict__ lo, int gc) {
  int r = gc >> 7, c = gc & 127;  // K=1024: 128 chunks/row
  const float* p = src + ((size_t)r << 10) + (c << 3);
  float4 f0 = *(const float4*)p;
  float4 f1 = *(const float4*)(p + 4);
  float f[8] = {f0.x, f0.y, f0.z, f0.w, f1.x, f1.y, f1.z, f1.w};
  short8 hv, lv;
#pragma unroll
  for (int e = 0; e < 8; ++e) {
    unsigned hb = bf16rn(f[e]);
    hv[e] = (short)hb;
    lv[e] = (short)bf16rn(f[e] - bf16f(hb));
  }
  size_t off = ((size_t)(r << 10) + ((c & ~7) << 3)) * 2 + (((c & 7) ^ (r & 7)) << 4);
  *(short8*)(hi + off) = hv;
  *(short8*)(lo + off) = lv;
}

// fused convert of x (512 blk), Wa (1536 blk), Wp (512 blk)
__global__ void __launch_bounds__(256) convert_all(
    const float* __restrict__ x, char* __restrict__ xhi, char* __restrict__ xlo,
    const float* __restrict__ Wa, char* __restrict__ wahi, char* __restrict__ walo,
    const float* __restrict__ Wp, char* __restrict__ wphi, char* __restrict__ wplo)
{
  int b = blockIdx.x, tid = threadIdx.x;
  if (b < 512) conv_chunk(x, xhi, xlo, b * 256 + tid);
  else if (b < 2048) conv_chunk(Wa, wahi, walo, (b - 512) * 256 + tid);
  else conv_chunk(Wp, wphi, wplo, (b - 2048) * 256 + tid);
}

// ---------------- K_store -> HL(K=64) + pre-scaled norms (-0.5*||K||^2) ----------------
__global__ void __launch_bounds__(256) convert_kernel(
    const float* __restrict__ ks, char* __restrict__ khi,
    char* __restrict__ klo, float* __restrict__ kn2)
{
  int g = blockIdx.x * 256 + threadIdx.x;
  int m = g & (MM - 1);
  const float* src = ks + (size_t)g * DD;
  float nrm = 0.f;
  size_t rowb = (size_t)g * 128;
#pragma unroll
  for (int c = 0; c < 8; ++c) {
    float f[8];
#pragma unroll
    for (int j = 0; j < 8; ++j) {
      f[j] = src[c * 8 + j];
      nrm = fmaf(f[j], f[j], nrm);
    }
    uint4 hv, lv;
    unsigned int hw[4], lw[4];
#pragma unroll
    for (int p = 0; p < 4; ++p) {
      unsigned int h0 = bf16rn(f[2 * p]), h1 = bf16rn(f[2 * p + 1]);
      float r0 = f[2 * p] - bf16f(h0), r1 = f[2 * p + 1] - bf16f(h1);
      hw[p] = h0 | (h1 << 16);
      lw[p] = bf16rn(r0) | (bf16rn(r1) << 16);
    }
    hv.x = hw[0]; hv.y = hw[1]; hv.z = hw[2]; hv.w = hw[3];
    lv.x = lw[0]; lv.y = lw[1]; lv.z = lw[2]; lv.w = lw[3];
    size_t off = rowb + (size_t)(((c ^ (m & 7)) << 4));
    *(uint4*)(khi + off) = hv;
    *(uint4*)(klo + off) = lv;
  }
  kn2[g] = -0.5f * nrm;
}

// ---------------- generic split-bf16 MFMA GEMM: C = scale*(A@B^T)+bias ----------------
__global__ void __launch_bounds__(256) gemm_hl(
    const char* __restrict__ Ahi, const char* __restrict__ Alo, int strideA, int aKb0, int aKbz,
    const char* __restrict__ Bhi, const char* __restrict__ Blo, int strideB, int bKb0, int bKbz,
    int kbBeg, int kbCnt, int kbzStep,
    float* __restrict__ Cf, long long czMul, int ldc,
    char* __restrict__ Chi, char* __restrict__ Clo, int Kc,
    const float* __restrict__ bias, float scale, int causal)
{
  int bx = blockIdx.x, by = blockIdx.y, z = blockIdx.z;
  int n0 = bx * 128, m0 = by * 128;
  if (causal && n0 > m0 + 127) return;
  int tid = threadIdx.x, lane = tid & 63, w = tid >> 6;
  int wr = w >> 1, wc = w & 1;
  __shared__ __align__(16) char smem[65536];
  char* sAhi = smem;
  char* sAlo = smem + 16384;
  char* sBhi = smem + 32768;
  char* sBlo = smem + 49152;
  f32x4 acc[4][4];
#pragma unroll
  for (int i = 0; i < 4; ++i)
#pragma unroll
    for (int j = 0; j < 4; ++j) acc[i][j] = (f32x4){0.f, 0.f, 0.f, 0.f};

  int kb0 = kbBeg + z * kbzStep;
  int lr = lane & 15, lc = lane >> 4;
  for (int i = 0; i < kbCnt; ++i) {
    int kbA = aKb0 + z * aKbz + kb0 + i;
    int kbB = bKb0 + z * bKbz + kb0 + i;
    if (i) __syncthreads();
#pragma unroll
    for (int c8 = 0; c8 < 4; ++c8) {
      int r8 = w * 32 + c8 * 8;
      stage_rows8(Ahi + (size_t)(m0 + r8) * strideA + (size_t)kbA * 128, strideA, sAhi + r8 * 128, lane);
      stage_rows8(Alo + (size_t)(m0 + r8) * strideA + (size_t)kbA * 128, strideA, sAlo + r8 * 128, lane);
      stage_rows8(Bhi + (size_t)(n0 + r8) * strideB + (size_t)kbB * 128, strideB, sBhi + r8 * 128, lane);
      stage_rows8(Blo + (size_t)(n0 + r8) * strideB + (size_t)kbB * 128, strideB, sBlo + r8 * 128, lane);
    }
    __syncthreads();
#pragma unroll
    for (int kh = 0; kh < 2; ++kh) {
      short8 ah[4], al[4], bh[4], bl[4];
#pragma unroll
      for (int f = 0; f < 4; ++f) {
        int ra = wr * 64 + f * 16 + lr;
        int ca = ((kh * 4 + lc) ^ (ra & 7)) << 4;
        ah[f] = *(const short8*)(sAhi + ra * 128 + ca);
        al[f] = *(const short8*)(sAlo + ra * 128 + ca);
        int rb = wc * 64 + f * 16 + lr;
        int cb = ((kh * 4 + lc) ^ (rb & 7)) << 4;
        bh[f] = *(const short8*)(sBhi + rb * 128 + cb);
        bl[f] = *(const short8*)(sBlo + rb * 128 + cb);
      }
#pragma unroll
      for (int mi = 0; mi < 4; ++mi)
#pragma unroll
        for (int nj = 0; nj < 4; ++nj) {
          acc[mi][nj] = __builtin_amdgcn_mfma_f32_16x16x32_bf16(ah[mi], bh[nj], acc[mi][nj], 0, 0, 0);
          acc[mi][nj] = __builtin_amdgcn_mfma_f32_16x16x32_bf16(al[mi], bh[nj], acc[mi][nj], 0, 0, 0);
          acc[mi][nj] = __builtin_amdgcn_mfma_f32_16x16x32_bf16(ah[mi], bl[nj], acc[mi][nj], 0, 0, 0);
        }
    }
  }
#pragma unroll
  for (int mi = 0; mi < 4; ++mi)
#pragma unroll
    for (int nj = 0; nj < 4; ++nj)
#pragma unroll
      for (int r = 0; r < 4; ++r) {
        int m = m0 + wr * 64 + mi * 16 + lc * 4 + r;
        int n = n0 + wc * 64 + nj * 16 + lr;
        float v = acc[mi][nj][r] * scale;
        if (bias) v += bias[n];
        if (Cf) Cf[(size_t)z * czMul + (size_t)m * ldc + n] = v;
        if (Chi) {
          unsigned hb = bf16rn(v);
          *(unsigned short*)(Chi + hl_off(m, n, Kc)) = (unsigned short)hb;
          *(unsigned short*)(Clo + hl_off(m, n, Kc)) = (unsigned short)bf16rn(v - bf16f(hb));
        }
      }
}

// ---------------- reduce qkv K-split(2) partials + bias -> HL ----------------
__global__ void __launch_bounds__(256) reduce_qkv(
    const float* __restrict__ p, const float* __restrict__ bias,
    char* __restrict__ hi, char* __restrict__ lo)
{
  int gc = blockIdx.x * 256 + threadIdx.x;  // 1024*384 chunks of 8
  int t = gc / 384, c = gc - t * 384;
  const float* p0 = p + (size_t)t * 3072 + (c << 3);
  const float* p1 = p0 + (size_t)3072 * 1024;
  float4 a0 = *(const float4*)p0, a1 = *(const float4*)(p0 + 4);
  float4 b0 = *(const float4*)p1, b1 = *(const float4*)(p1 + 4);
  float4 bb0 = *(const float4*)(bias + (c << 3));
  float4 bb1 = *(const float4*)(bias + (c << 3) + 4);
  float f[8] = {a0.x + b0.x + bb0.x, a0.y + b0.y + bb0.y,
                a0.z + b0.z + bb0.z, a0.w + b0.w + bb0.w,
                a1.x + b1.x + bb1.x, a1.y + b1.y + bb1.y,
                a1.z + b1.z + bb1.z, a1.w + b1.w + bb1.w};
  short8 hv, lv;
#pragma unroll
  for (int e = 0; e < 8; ++e) {
    unsigned hb = bf16rn(f[e]);
    hv[e] = (short)hb;
    lv[e] = (short)bf16rn(f[e] - bf16f(hb));
  }
  size_t off = ((size_t)t * 3072 + ((c & ~7) << 3)) * 2 + (((c & 7) ^ (t & 7)) << 4);
  *(short8*)(hi + off) = hv;
  *(short8*)(lo + off) = lv;
}

// ---------------- fused QK^T + causal softmax -> att HL + attlast ----------------
// block = (h, 32 q-rows); 8 waves: wr=w>>2 row-group (16 rows), wcg=w&3 col-group (256 cols)
// Epilogue stages each wave's 16x64 bf16 hi/lo tile in LDS, then stores 16B/lane
// covering full 128B line-groups (avoids partial-line write amplification).
#define QSLDS 2304  // 16 rows * 144B (16B pad per row vs 128 to spread LDS banks)
__global__ void __launch_bounds__(512) qk_softmax(
    const char* __restrict__ qhi, const char* __restrict__ qlo,
    char* __restrict__ attB, float* __restrict__ attlast)
{
  int rb = blockIdx.x, h = blockIdx.y;
  int i0 = rb * 32;
  int tid = threadIdx.x, lane = tid & 63, w = tid >> 6;
  int wr = w >> 2, wcg = w & 3;
  int lr = lane & 15, lc = lane >> 4;
  __shared__ float redm[2][16][4];
  __shared__ float reds[2][16][4];
  __shared__ __align__(16) char tb[8][2 * QSLDS];

  // q fragments for this wave's 16 rows
  int iq = i0 + wr * 16 + lr;
  short8 ah[2], al[2];
  {
    size_t qb = (size_t)iq * 6144 + h * 128;
#pragma unroll
    for (int kh = 0; kh < 2; ++kh) {
      size_t off = qb + (((kh * 4 + lc) ^ (iq & 7)) << 4);
      ah[kh] = *(const short8*)(qhi + off);
      al[kh] = *(const short8*)(qlo + off);
    }
  }

  f32x4 acc[16];
#pragma unroll
  for (int nt = 0; nt < 16; ++nt) acc[nt] = (f32x4){0.f, 0.f, 0.f, 0.f};

  // causal tile limit for this wave
  int maxj = i0 + 31;
  int rel = maxj - wcg * 256;
  int ntEnd = (rel < 0) ? 0 : ((rel >> 4) + 1);
  if (ntEnd > 16) ntEnd = 16;

  for (int nt = 0; nt < ntEnd; ++nt) {
    int jr = wcg * 256 + nt * 16 + lr;
    size_t kb = (size_t)jr * 6144 + 2048 + h * 128;
    short8 bh[2], bl[2];
#pragma unroll
    for (int kh = 0; kh < 2; ++kh) {
      size_t off = kb + (((kh * 4 + lc) ^ (jr & 7)) << 4);
      bh[kh] = *(const short8*)(qhi + off);
      bl[kh] = *(const short8*)(qlo + off);
    }
#pragma unroll
    for (int kh = 0; kh < 2; ++kh) {
      acc[nt] = __builtin_amdgcn_mfma_f32_16x16x32_bf16(ah[kh], bh[kh], acc[nt], 0, 0, 0);
      acc[nt] = __builtin_amdgcn_mfma_f32_16x16x32_bf16(al[kh], bh[kh], acc[nt], 0, 0, 0);
      acc[nt] = __builtin_amdgcn_mfma_f32_16x16x32_bf16(ah[kh], bl[kh], acc[nt], 0, 0, 0);
    }
  }

  // mask + scale; per-row partial max over this wave's 256 cols
  int iv[4];
  float pmax[4];
#pragma unroll
  for (int r = 0; r < 4; ++r) {
    iv[r] = i0 + wr * 16 + lc * 4 + r;
    pmax[r] = -INFINITY;
  }
#pragma unroll
  for (int nt = 0; nt < 16; ++nt) {
    int j = wcg * 256 + nt * 16 + lr;
#pragma unroll
    for (int r = 0; r < 4; ++r) {
      float v = (j <= iv[r]) ? acc[nt][r] * 0.125f : -INFINITY;
      acc[nt][r] = v;
      pmax[r] = fmaxf(pmax[r], v);
    }
  }
#pragma unroll
  for (int o = 1; o <= 8; o <<= 1)
#pragma unroll
    for (int r = 0; r < 4; ++r) pmax[r] = fmaxf(pmax[r], __shfl_xor(pmax[r], o));
  if (lr == 0) {
#pragma unroll
    for (int r = 0; r < 4; ++r) redm[wr][lc * 4 + r][wcg] = pmax[r];
  }
  __syncthreads();
  float rowm[4];
#pragma unroll
  for (int r = 0; r < 4; ++r) {
    float* q = redm[wr][lc * 4 + r];
    rowm[r] = fmaxf(fmaxf(q[0], q[1]), fmaxf(q[2], q[3]));
  }

  // exp + per-row partial sum
  float psum[4] = {0.f, 0.f, 0.f, 0.f};
#pragma unroll
  for (int nt = 0; nt < 16; ++nt)
#pragma unroll
    for (int r = 0; r < 4; ++r) {
      float e = __expf(acc[nt][r] - rowm[r]);
      acc[nt][r] = e;
      psum[r] += e;
    }
#pragma unroll
  for (int o = 1; o <= 8; o <<= 1)
#pragma unroll
    for (int r = 0; r < 4; ++r) psum[r] += __shfl_xor(psum[r], o);
  if (lr == 0) {
#pragma unroll
    for (int r = 0; r < 4; ++r) reds[wr][lc * 4 + r][wcg] = psum[r];
  }
  __syncthreads();
  float inv[4];
#pragma unroll
  for (int r = 0; r < 4; ++r) {
    float* q = reds[wr][lc * 4 + r];
    inv[r] = 1.0f / (q[0] + q[1] + q[2] + q[3]);
  }

  // epilogue: LDS-transposed coalesced stores (64-col chunk at a time)
  char* mybuf = tb[w];
  int iv0 = i0 + wr * 16;
#pragma unroll
  for (int cc = 0; cc < 4; ++cc) {
#pragma unroll
    for (int q = 0; q < 4; ++q) {
      int nt = cc * 4 + q;
      int col = q * 16 + lr;
#pragma unroll
      for (int r = 0; r < 4; ++r) {
        int row = lc * 4 + r;
        float v = acc[nt][r] * inv[r];
        unsigned hb = bf16rn(v);
        unsigned lb = bf16rn(v - bf16f(hb));
        *(unsigned short*)(mybuf + row * 144 + col * 2) = (unsigned short)hb;
        *(unsigned short*)(mybuf + QSLDS + row * 144 + col * 2) = (unsigned short)lb;
        if (iv[r] == 1023) attlast[(h << 10) + wcg * 256 + cc * 64 + col] = v;
      }
    }
    __syncthreads();
#pragma unroll
    for (int half = 0; half < 2; ++half) {
      int rr = (lane >> 3) + half * 8;
      int c = lane & 7;
      int rowg = iv0 + rr;
      uint4 hv = *(const uint4*)(mybuf + rr * 144 + c * 16);
      uint4 lv = *(const uint4*)(mybuf + QSLDS + rr * 144 + c * 16);
      size_t basep = ((size_t)h << 22) + ((size_t)rowg << 12)
                   + (size_t)((((wcg << 2) + cc)) << 7) + (size_t)((c ^ (rowg & 7)) << 4);
      *(uint4*)(attB + basep) = hv;
      *(uint4*)(attB + basep + 2048) = lv;
    }
    __syncthreads();
  }
}

// ---------------- MFMA distance + top-4 (rank on acc; kn folded into C-init) ----------------
#define BUFB 16384
__global__ void __launch_bounds__(256, 4) topk_mfma(
    const char* __restrict__ qhi, const char* __restrict__ qlo,
    const char* __restrict__ khi, const char* __restrict__ klo,
    const float* __restrict__ kn2, float* __restrict__ pd, int* __restrict__ pi)
{
  int bid = blockIdx.x;
  int h = bid & 15, ttile = (bid >> 4) & 15, mq = bid >> 8;
  int tid = threadIdx.x, lane = tid & 63, w = tid >> 6;
  int t0 = ttile * 64 + w * 16;
  __shared__ __align__(16) char smem[2 * BUFB];

  short8 bhi[2], blo[2];
  {
    int t = t0 + (lane & 15);
    size_t rb = (size_t)t * 6144 + 2048 + h * 128;
#pragma unroll
    for (int kh = 0; kh < 2; ++kh) {
      int chunk = kh * 4 + (lane >> 4);
      size_t off = rb + ((chunk ^ (t & 7)) << 4);
      bhi[kh] = *(const short8*)(qhi + off);
      blo[kh] = *(const short8*)(qlo + off);
    }
  }

  const char* ghi = khi + ((size_t)h * MM + (size_t)mq * MQS) * 128;
  const char* glo = klo + ((size_t)h * MM + (size_t)mq * MQS) * 128;
  const float* gk2 = kn2 + (size_t)h * MM + (size_t)mq * MQS + ((lane >> 4) << 2);

  float ba[4] = {-3.0e38f, -3.0e38f, -3.0e38f, -3.0e38f};
  int   bi_[4] = {-1, -1, -1, -1};

  {
#pragma unroll
    for (int i2 = 0; i2 < 4; ++i2) {
      int s = w * 4 + i2;
      const char* src = (s < 8) ? (ghi + s * 1024) : (glo + (s - 8) * 1024);
      stage_seg16(src, smem + s * 1024, lane);
    }
  }
  __syncthreads();

  int buf = 0;
  const int NIT = MQS / 64;  // 32
  for (int it = 0; it < NIT; ++it) {
    char* cb = smem + buf * BUFB;
    if (it < NIT - 1) {
      char* nb = smem + (buf ^ 1) * BUFB;
      const char* bh = ghi + (size_t)(it + 1) * 8192;
      const char* bl = glo + (size_t)(it + 1) * 8192;
#pragma unroll
      for (int i2 = 0; i2 < 4; ++i2) {
        int s = w * 4 + i2;
        const char* src = (s < 8) ? (bh + s * 1024) : (bl + (s - 8) * 1024);
        stage_seg16(src, nb + s * 1024, lane);
      }
    }

    f32x4 acc[4];
#pragma unroll
    for (int ms = 0; ms < 4; ++ms)
      acc[ms] = *(const f32x4*)(gk2 + it * 64 + ms * 16);
#pragma unroll
    for (int ms = 0; ms < 4; ++ms) {
      int mloc = ms * 16 + (lane & 15);
      short8 ah[2], al[2];
#pragma unroll
      for (int kh = 0; kh < 2; ++kh) {
        int c = kh * 4 + (lane >> 4);
        int off = mloc * 128 + (((c ^ (mloc & 7)) << 4));
        ah[kh] = *(const short8*)(cb + off);
        al[kh] = *(const short8*)(cb + 8192 + off);
      }
#pragma unroll
      for (int kh = 0; kh < 2; ++kh) {
        acc[ms] = __builtin_amdgcn_mfma_f32_16x16x32_bf16(ah[kh], bhi[kh], acc[ms], 0, 0, 0);
        acc[ms] = __builtin_amdgcn_mfma_f32_16x16x32_bf16(al[kh], bhi[kh], acc[ms], 0, 0, 0);
        acc[ms] = __builtin_amdgcn_mfma_f32_16x16x32_bf16(ah[kh], blo[kh], acc[ms], 0, 0, 0);
      }
    }

    float pk[16];
#pragma unroll
    for (int ms = 0; ms < 4; ++ms)
#pragma unroll
      for (int r = 0; r < 4; ++r) {
        unsigned u = __float_as_uint(acc[ms][r]);
        pk[ms * 4 + r] = __uint_as_float((u & ~15u) | (unsigned)(ms * 4 + r));
      }
    float mx = pk[0];
#pragma unroll
    for (int c = 1; c < 16; ++c) mx = fmaxf(mx, pk[c]);

    int mg0 = mq * MQS + it * 64 + ((lane >> 4) << 2);
    while (mx > ba[3]) {
      unsigned pb = __float_as_uint(mx);
      int cl = pb & 15;
      ba[3] = mx; bi_[3] = mg0 + ((cl & 12) << 2) + (cl & 3);
#pragma unroll
      for (int s = 3; s > 0; --s) {
        if (ba[s] > ba[s - 1]) {
          float td = ba[s]; ba[s] = ba[s - 1]; ba[s - 1] = td;
          int ti = bi_[s]; bi_[s] = bi_[s - 1]; bi_[s - 1] = ti;
        }
      }
#pragma unroll
      for (int c2 = 0; c2 < 16; ++c2)
        if (pk[c2] == mx) pk[c2] = -3.0e38f;
      mx = pk[0];
#pragma unroll
      for (int c2 = 1; c2 < 16; ++c2) mx = fmaxf(mx, pk[c2]);
    }

    __syncthreads();
    buf ^= 1;
  }

  float bd[4];
#pragma unroll
  for (int s = 0; s < 4; ++s) bd[s] = ba[s] * -2.0f;
#pragma unroll
  for (int st = 16; st <= 32; st <<= 1) {
    float sd[4]; int si[4];
#pragma unroll
    for (int s = 0; s < 4; ++s) {
      sd[s] = __shfl_xor(bd[s], st);
      si[s] = __shfl_xor(bi_[s], st);
    }
#pragma unroll
    for (int s = 0; s < 4; ++s) ins4(sd[s], si[s], bd, bi_);
  }
  if (lane < 16) {
    size_t o = (((size_t)mq * NH + h) * TT + (t0 + lane)) * 4;
#pragma unroll
    for (int s = 0; s < 4; ++s) { pd[o + s] = bd[s]; pi[o + s] = bi_[s]; }
  }
}

// ---------------- kNN attend (fused 4-way quarter merge; writes v_new^T in HL) ----------------
__global__ void __launch_bounds__(256) knn_attend(
    const char* __restrict__ qhi, const char* __restrict__ qlo,
    const float* __restrict__ attlast,
    const float* __restrict__ pd, const int* __restrict__ pi,
    const float* __restrict__ kstore, const float* __restrict__ vstore,
    char* __restrict__ vThi, char* __restrict__ vTlo)
{
  int gw = (blockIdx.x * 256 + threadIdx.x) >> 6;
  int lane = threadIdx.x & 63;
  int h = gw >> 10, t = gw & 1023;
  int g = (h << 10) + t;

  float fd[4]; int fi[4];
  {
    size_t o = ((size_t)(lane & 3) * (NH * TT) + g) * 4;
#pragma unroll
    for (int s = 0; s < 4; ++s) { fd[s] = pd[o + s]; fi[s] = pi[o + s]; }
#pragma unroll
    for (int st = 1; st <= 2; st <<= 1) {
      float sd[4]; int si[4];
#pragma unroll
      for (int s = 0; s < 4; ++s) {
        sd[s] = __shfl_xor(fd[s], st);
        si[s] = __shfl_xor(fi[s], st);
      }
#pragma unroll
      for (int s = 0; s < 4; ++s) ins4(sd[s], si[s], fd, fi);
    }
  }

  int sw = ((lane >> 3) ^ (t & 7)) << 4;
  int o2 = (lane & 7) << 1;
  size_t rb = (size_t)t * 6144;
  size_t offq = rb + h * 128 + sw + o2;
  float q = bf16f(*(const unsigned short*)(qhi + offq)) + bf16f(*(const unsigned short*)(qlo + offq));
  size_t offk = offq + 2048;
  float k = bf16f(*(const unsigned short*)(qhi + offk)) + bf16f(*(const unsigned short*)(qlo + offk));
  size_t offv = offq + 4096;
  float v = bf16f(*(const unsigned short*)(qhi + offv)) + bf16f(*(const unsigned short*)(qlo + offv));
  float al = attlast[g];
  bool sel = al >= (1.0f / 8192.0f);

  float attf[5], vf[5];
  attf[0] = wredsum(q * k) * 0.125f;
  vf[0] = v;
#pragma unroll
  for (int s = 1; s < 5; ++s) {
    int m = fi[s - 1];
    const float* kp = kstore + ((size_t)h * MM + m) * DD;
    const float* vp = vstore + ((size_t)h * MM + m) * DD;
    attf[s] = wredsum(q * kp[lane]) * 0.125f;
    vf[s] = vp[lane];
  }
  float mx = attf[0];
#pragma unroll
  for (int s = 1; s < 5; ++s) mx = fmaxf(mx, attf[s]);
  float wgt[5], sum = 0.f;
#pragma unroll
  for (int s = 0; s < 5; ++s) { wgt[s] = __expf(attf[s] - mx); sum += wgt[s]; }
  float inv = 1.0f / sum;
  float vals = 0.f;
#pragma unroll
  for (int s = 0; s < 5; ++s) vals = fmaf(wgt[s] * inv, vf[s], vals);
  float r = 0.5f * vals + 0.5f * v;
  float vn = sel ? r : v;

  unsigned hb = bf16rn(vn);
  size_t off = hl_off((h << 6) + lane, t, 1024);
  *(unsigned short*)(vThi + off) = (unsigned short)hb;
  *(unsigned short*)(vTlo + off) = (unsigned short)bf16rn(vn - bf16f(hb));
}

// ---------------- att(HL) @ vnewT -> yhl ----------------
__global__ void __launch_bounds__(256) gemm_attv(
    const char* __restrict__ attB, const char* __restrict__ vThi, const char* __restrict__ vTlo,
    char* __restrict__ Yhi, char* __restrict__ Ylo)
{
  int h = blockIdx.y, m0 = blockIdx.x * 128;
  const char* aBase = attB + (size_t)h * 4194304;
  int tid = threadIdx.x, lane = tid & 63, w = tid >> 6;
  int wr = w >> 1, wc = w & 1;
  __shared__ __align__(16) char smem[49152];
  char* sAhi = smem;
  char* sAlo = smem + 16384;
  char* sBhi = smem + 32768;
  char* sBlo = smem + 40960;
  f32x4 acc[4][2];
#pragma unroll
  for (int i = 0; i < 4; ++i)
#pragma unroll
    for (int j = 0; j < 2; ++j) acc[i][j] = (f32x4){0.f, 0.f, 0.f, 0.f};
  int lr = lane & 15, lc = lane >> 4;
  for (int kb = 0; kb < 16; ++kb) {
    if (kb) __syncthreads();
#pragma unroll
    for (int c8 = 0; c8 < 4; ++c8) {
      int r8 = w * 32 + c8 * 8;
      stage_rows8(aBase + (size_t)(m0 + r8) * 4096 + (size_t)kb * 128, 4096, sAhi + r8 * 128, lane);
      stage_rows8(aBase + (size_t)(m0 + r8) * 4096 + 2048 + (size_t)kb * 128, 4096, sAlo + r8 * 128, lane);
    }
#pragma unroll
    for (int c8 = 0; c8 < 2; ++c8) {
      int r8 = w * 16 + c8 * 8;
      stage_rows8(vThi + (size_t)((h << 6) + r8) * 2048 + (size_t)kb * 128, 2048, sBhi + r8 * 128, lane);
      stage_rows8(vTlo + (size_t)((h << 6) + r8) * 2048 + (size_t)kb * 128, 2048, sBlo + r8 * 128, lane);
    }
    __syncthreads();
#pragma unroll
    for (int kh = 0; kh < 2; ++kh) {
      short8 ah[4], al[4], bh[2], bl[2];
#pragma unroll
      for (int f = 0; f < 4; ++f) {
        int ra = wr * 64 + f * 16 + lr;
        int ca = ((kh * 4 + lc) ^ (ra & 7)) << 4;
        ah[f] = *(const short8*)(sAhi + ra * 128 + ca);
        al[f] = *(const short8*)(sAlo + ra * 128 + ca);
      }
#pragma unroll
      for (int f = 0; f < 2; ++f) {
        int rbr = wc * 32 + f * 16 + lr;
        int cb = ((kh * 4 + lc) ^ (rbr & 7)) << 4;
        bh[f] = *(const short8*)(sBhi + rbr * 128 + cb);
        bl[f] = *(const short8*)(sBlo + rbr * 128 + cb);
      }
#pragma unroll
      for (int mi = 0; mi < 4; ++mi)
#pragma unroll
        for (int nj = 0; nj < 2; ++nj) {
          acc[mi][nj] = __builtin_amdgcn_mfma_f32_16x16x32_bf16(ah[mi], bh[nj], acc[mi][nj], 0, 0, 0);
          acc[mi][nj] = __builtin_amdgcn_mfma_f32_16x16x32_bf16(al[mi], bh[nj], acc[mi][nj], 0, 0, 0);
          acc[mi][nj] = __builtin_amdgcn_mfma_f32_16x16x32_bf16(ah[mi], bl[nj], acc[mi][nj], 0, 0, 0);
        }
    }
  }
#pragma unroll
  for (int mi = 0; mi < 4; ++mi)
#pragma unroll
    for (int nj = 0; nj < 2; ++nj)
#pragma unroll
      for (int r = 0; r < 4; ++r) {
        int m = m0 + wr * 64 + mi * 16 + lc * 4 + r;
        int n = (h << 6) + wc * 32 + nj * 16 + lr;
        float v = acc[mi][nj][r];
        unsigned hb = bf16rn(v);
        *(unsigned short*)(Yhi + hl_off(m, n, 1024)) = (unsigned short)hb;
        *(unsigned short*)(Ylo + hl_off(m, n, 1024)) = (unsigned short)bf16rn(v - bf16f(hb));
      }
}

// ---------------- reduce proj K-split partials + bias ----------------
__global__ void __launch_bounds__(256) reduce_bias(
    const float* __restrict__ p, const float* __restrict__ bias, float* __restrict__ out)
{
  int i4 = blockIdx.x * 256 + threadIdx.x;
  const float4* P = (const float4*)p;
  float4 a = P[i4], b = P[i4 + 262144], c = P[i4 + 524288], d = P[i4 + 786432];
  float4 bb = ((const float4*)bias)[i4 & 255];
  float4 o;
  o.x = a.x + b.x + c.x + d.x + bb.x;
  o.y = a.y + b.y + c.y + d.y + bb.y;
  o.z = a.z + b.z + c.z + d.z + bb.z;
  o.w = a.w + b.w + c.w + d.w + bb.w;
  ((float4*)out)[i4] = o;
}

// ---------------- launch ----------------
extern "C" void kernel_launch(void* const* d_in, const int* in_sizes, int n_in,
                              void* d_out, int out_size, void* d_ws, size_t ws_size,
                              hipStream_t stream) {
  (void)in_sizes; (void)n_in; (void)out_size; (void)ws_size;
  const float* x  = (const float*)d_in[0];
  const float* Wa = (const float*)d_in[1];
  const float* ba = (const float*)d_in[2];
  const float* Wp = (const float*)d_in[3];
  const float* bp = (const float*)d_in[4];
  const float* Ks = (const float*)d_in[5];
  const float* Vs = (const float*)d_in[6];
  float* out = (float*)d_out;

  char* base = (char*)d_ws;
  char* xhi  = base;
  char* xlo  = base + 0x200000;
  char* wahi = base + 0x400000;
  char* walo = base + 0xA00000;
  char* khi  = base + 0x1000000;
  char* klo  = base + 0x2000000;
  float* qkvp = (float*)(base + 0x1000000);  // 2 x 12 MB partials overlay khl (written later)
  char*  attB = base;                        // att HL (h*4MB + i*4KB; hi 2KB + lo 2KB)
  float* pout = (float*)base;
  char* tail = base + 0x4000000;
  char* qhi = tail;
  char* qlo = tail + 0x600000;
  float* attlast = (float*)(tail + 0xC00000);
  float* kn2     = (float*)(tail + 0xC10000);
  float* pd      = (float*)(tail + 0xC90000);
  int*   pi      = (int*)(tail + 0xE90000);
  char* vThi = tail + 0x1090000;
  char* vTlo = tail + 0x1290000;
  char* yhi  = tail + 0x1490000;
  char* ylo  = tail + 0x1690000;
  char* wphi = tail + 0x1890000;
  char* wplo = tail + 0x1A90000;

  // 1) fused convert of x, Wa, Wp
  hipLaunchKernelGGL(convert_all, dim3(2560), dim3(256), 0, stream,
                     x, xhi, xlo, Wa, wahi, walo, Wp, wphi, wplo);
  // 2) qkv = x @ Wa^T (K-split 2, f32 partials into khl region)
  hipLaunchKernelGGL(gemm_hl, dim3(24, 8, 2), dim3(256), 0, stream,
                     (const char*)xhi, (const char*)xlo, 2048, 0, 0,
                     (const char*)wahi, (const char*)walo, 2048, 0, 0,
                     0, 8, 8,
                     qkvp, 3145728LL, 3072,
                     (char*)nullptr, (char*)nullptr, 0,
                     (const float*)nullptr, 1.0f, 0);
  // 3) reduce partials + bias -> qhl
  hipLaunchKernelGGL(reduce_qkv, dim3(1536), dim3(256), 0, stream, qkvp, ba, qhi, qlo);
  // 4) K_store -> khl + pre-scaled norms (overwrites partials)
  hipLaunchKernelGGL(convert_kernel, dim3(NH * MM / 256), dim3(256), 0, stream, Ks, khi, klo, kn2);
  // 5) top-4 over key store (partial per M-quarter; merged inside knn_attend)
  hipLaunchKernelGGL(topk_mfma, dim3(16 * 16 * MQ), dim3(256), 0, stream,
                     (const char*)qhi, (const char*)qlo, (const char*)khi, (const char*)klo,
                     kn2, pd, pi);
  // 6) fused QK^T + causal softmax -> att HL + attlast (coalesced epilogue)
  hipLaunchKernelGGL(qk_softmax, dim3(32, 16), dim3(512), 0, stream,
                     (const char*)qhi, (const char*)qlo, attB, attlast);
  // 7) kNN attend (fused quarter merge; writes v_new^T HL directly)
  hipLaunchKernelGGL(knn_attend, dim3(NH * TT / 4), dim3(256), 0, stream,
                     (const char*)qhi, (const char*)qlo, attlast, pd, pi, Ks, Vs, vThi, vTlo);
  // 8) y = att @ v_new -> yhl
  hipLaunchKernelGGL(gemm_attv, dim3(8, 16), dim3(256), 0, stream,
                     (const char*)attB, (const char*)vThi, (const char*)vTlo, yhi, ylo);
  // 9) out = y @ Wp^T + bp (K-split 4 + reduce)
  hipLaunchKernelGGL(gemm_hl, dim3(8, 8, 4), dim3(256), 0, stream,
                     (const char*)yhi, (const char*)ylo, 2048, 0, 0,
                     (const char*)wphi, (const char*)wplo, 2048, 0, 0,
                     0, 4, 4,
                     pout, 1048576LL, 1024,
                     (char*)nullptr, (char*)nullptr, 0,
                     (const float*)nullptr, 1.0f, 0);
  hipLaunchKernelGGL(reduce_bias, dim3(1024), dim3(256), 0, stream, pout, bp, out);
}

// Round 11
// 290.992 us; speedup vs baseline: 1.1097x; 1.0685x over previous
//
#include <hip/hip_runtime.h>
#include <math.h>

#define NH 16
#define TT 1024
#define CC 1024
#define DD 64
#define MM 8192
#define MQ 4
#define MQS (MM / MQ)

typedef __attribute__((ext_vector_type(8))) short short8;
typedef __attribute__((ext_vector_type(4))) float f32x4;

// ---------------- helpers ----------------
__device__ __forceinline__ float wredsum(float x) {
#pragma unroll
  for (int o = 32; o; o >>= 1) x += __shfl_xor(x, o);
  return x;
}
__device__ __forceinline__ unsigned int bf16rn(float x) {
  unsigned int u = __float_as_uint(x);
  return (u + 0x7fffu + ((u >> 16) & 1u)) >> 16;
}
__device__ __forceinline__ float bf16f(unsigned int h) {
  return __uint_as_float(h << 16);
}

__device__ __forceinline__ void ins4(float d, int i, float vd[4], int vi[4]) {
  if (d < vd[3] || (d == vd[3] && i < vi[3])) {
    vd[3] = d; vi[3] = i;
#pragma unroll
    for (int s = 3; s > 0; --s) {
      bool sw = (vd[s] < vd[s - 1]) || (vd[s] == vd[s - 1] && vi[s] < vi[s - 1]);
      if (sw) {
        float td = vd[s]; vd[s] = vd[s - 1]; vd[s - 1] = td;
        int ti = vi[s]; vi[s] = vi[s - 1]; vi[s - 1] = ti;
      }
    }
  }
}

// ---------------- staging (global LINEAR -> LDS swizzled) ----------------
// Stages 8 rows x 128B. Global is linear; per-lane source chunk is XOR-swizzled so
// LDS slot v of row r holds global chunk v^(r&7) (row bases are all multiples of 8).
__device__ __forceinline__ void stage_rows8_swz(const char* gRow0, size_t gStride, char* lds, int lane) {
  int rr = lane >> 3;
  int c = (lane & 7) ^ rr;
  __builtin_amdgcn_global_load_lds(
      (const __attribute__((address_space(1))) unsigned int*)(gRow0 + (size_t)rr * gStride + (c << 4)),
      (__attribute__((address_space(3))) unsigned int*)lds, 16, 0, 0);
}

// ---------------- converts (all outputs LINEAR) ----------------
__device__ __forceinline__ void conv_chunk(const float* __restrict__ src,
                                           char* __restrict__ hi, char* __restrict__ lo, int gc) {
  const float* p = src + ((size_t)gc << 3);
  float4 f0 = *(const float4*)p;
  float4 f1 = *(const float4*)(p + 4);
  float f[8] = {f0.x, f0.y, f0.z, f0.w, f1.x, f1.y, f1.z, f1.w};
  short8 hv, lv;
#pragma unroll
  for (int e = 0; e < 8; ++e) {
    unsigned hb = bf16rn(f[e]);
    hv[e] = (short)hb;
    lv[e] = (short)bf16rn(f[e] - bf16f(hb));
  }
  size_t off = (size_t)gc << 4;
  *(short8*)(hi + off) = hv;
  *(short8*)(lo + off) = lv;
}

// fused convert of x (512 blk), Wa (1536 blk), Wp (512 blk)
__global__ void __launch_bounds__(256) convert_all(
    const float* __restrict__ x, char* __restrict__ xhi, char* __restrict__ xlo,
    const float* __restrict__ Wa, char* __restrict__ wahi, char* __restrict__ walo,
    const float* __restrict__ Wp, char* __restrict__ wphi, char* __restrict__ wplo)
{
  int b = blockIdx.x, tid = threadIdx.x;
  if (b < 512) conv_chunk(x, xhi, xlo, b * 256 + tid);
  else if (b < 2048) conv_chunk(Wa, wahi, walo, (b - 512) * 256 + tid);
  else conv_chunk(Wp, wphi, wplo, (b - 2048) * 256 + tid);
}

// K_store -> linear HL + pre-scaled norms; one thread per 8-elem chunk (8 threads/row)
__global__ void __launch_bounds__(256) convert_kernel(
    const float* __restrict__ ks, char* __restrict__ khi,
    char* __restrict__ klo, float* __restrict__ kn2)
{
  int gc = blockIdx.x * 256 + threadIdx.x;  // chunk id; row = gc>>3
  const float* p = ks + ((size_t)gc << 3);
  float4 f0 = *(const float4*)p;
  float4 f1 = *(const float4*)(p + 4);
  float f[8] = {f0.x, f0.y, f0.z, f0.w, f1.x, f1.y, f1.z, f1.w};
  float s = 0.f;
  short8 hv, lv;
#pragma unroll
  for (int e = 0; e < 8; ++e) {
    s = fmaf(f[e], f[e], s);
    unsigned hb = bf16rn(f[e]);
    hv[e] = (short)hb;
    lv[e] = (short)bf16rn(f[e] - bf16f(hb));
  }
  size_t off = (size_t)gc << 4;
  *(short8*)(khi + off) = hv;
  *(short8*)(klo + off) = lv;
  s += __shfl_xor(s, 1);
  s += __shfl_xor(s, 2);
  s += __shfl_xor(s, 4);
  if ((threadIdx.x & 7) == 0) kn2[gc >> 3] = -0.5f * s;
}

// ---------------- generic split-bf16 MFMA GEMM: C = scale*(A@B^T)+bias ----------------
__global__ void __launch_bounds__(256) gemm_hl(
    const char* __restrict__ Ahi, const char* __restrict__ Alo, int strideA, int aKb0, int aKbz,
    const char* __restrict__ Bhi, const char* __restrict__ Blo, int strideB, int bKb0, int bKbz,
    int kbBeg, int kbCnt, int kbzStep,
    float* __restrict__ Cf, long long czMul, int ldc,
    const float* __restrict__ bias, float scale)
{
  int bx = blockIdx.x, by = blockIdx.y, z = blockIdx.z;
  int n0 = bx * 128, m0 = by * 128;
  int tid = threadIdx.x, lane = tid & 63, w = tid >> 6;
  int wr = w >> 1, wc = w & 1;
  __shared__ __align__(16) char smem[65536];
  char* sAhi = smem;
  char* sAlo = smem + 16384;
  char* sBhi = smem + 32768;
  char* sBlo = smem + 49152;
  f32x4 acc[4][4];
#pragma unroll
  for (int i = 0; i < 4; ++i)
#pragma unroll
    for (int j = 0; j < 4; ++j) acc[i][j] = (f32x4){0.f, 0.f, 0.f, 0.f};

  int kb0 = kbBeg + z * kbzStep;
  int lr = lane & 15, lc = lane >> 4;
  for (int i = 0; i < kbCnt; ++i) {
    int kbA = aKb0 + z * aKbz + kb0 + i;
    int kbB = bKb0 + z * bKbz + kb0 + i;
    if (i) __syncthreads();
#pragma unroll
    for (int c8 = 0; c8 < 4; ++c8) {
      int r8 = w * 32 + c8 * 8;
      stage_rows8_swz(Ahi + (size_t)(m0 + r8) * strideA + (size_t)kbA * 128, strideA, sAhi + r8 * 128, lane);
      stage_rows8_swz(Alo + (size_t)(m0 + r8) * strideA + (size_t)kbA * 128, strideA, sAlo + r8 * 128, lane);
      stage_rows8_swz(Bhi + (size_t)(n0 + r8) * strideB + (size_t)kbB * 128, strideB, sBhi + r8 * 128, lane);
      stage_rows8_swz(Blo + (size_t)(n0 + r8) * strideB + (size_t)kbB * 128, strideB, sBlo + r8 * 128, lane);
    }
    __syncthreads();
#pragma unroll
    for (int kh = 0; kh < 2; ++kh) {
      short8 ah[4], al[4], bh[4], bl[4];
#pragma unroll
      for (int f = 0; f < 4; ++f) {
        int ra = wr * 64 + f * 16 + lr;
        int ca = ((kh * 4 + lc) ^ (ra & 7)) << 4;
        ah[f] = *(const short8*)(sAhi + ra * 128 + ca);
        al[f] = *(const short8*)(sAlo + ra * 128 + ca);
        int rb = wc * 64 + f * 16 + lr;
        int cb = ((kh * 4 + lc) ^ (rb & 7)) << 4;
        bh[f] = *(const short8*)(sBhi + rb * 128 + cb);
        bl[f] = *(const short8*)(sBlo + rb * 128 + cb);
      }
#pragma unroll
      for (int mi = 0; mi < 4; ++mi)
#pragma unroll
        for (int nj = 0; nj < 4; ++nj) {
          acc[mi][nj] = __builtin_amdgcn_mfma_f32_16x16x32_bf16(ah[mi], bh[nj], acc[mi][nj], 0, 0, 0);
          acc[mi][nj] = __builtin_amdgcn_mfma_f32_16x16x32_bf16(al[mi], bh[nj], acc[mi][nj], 0, 0, 0);
          acc[mi][nj] = __builtin_amdgcn_mfma_f32_16x16x32_bf16(ah[mi], bl[nj], acc[mi][nj], 0, 0, 0);
        }
    }
  }
#pragma unroll
  for (int mi = 0; mi < 4; ++mi)
#pragma unroll
    for (int nj = 0; nj < 4; ++nj)
#pragma unroll
      for (int r = 0; r < 4; ++r) {
        int m = m0 + wr * 64 + mi * 16 + lc * 4 + r;
        int n = n0 + wc * 64 + nj * 16 + lr;
        float v = acc[mi][nj][r] * scale;
        if (bias) v += bias[n];
        Cf[(size_t)z * czMul + (size_t)m * ldc + n] = v;
      }
}

// ---------------- reduce qkv K-split(2) partials + bias -> linear HL ----------------
__global__ void __launch_bounds__(256) reduce_qkv(
    const float* __restrict__ p, const float* __restrict__ bias,
    char* __restrict__ hi, char* __restrict__ lo)
{
  int gc = blockIdx.x * 256 + threadIdx.x;  // 1024*384 chunks of 8
  int t = gc / 384, c = gc - t * 384;
  const float* p0 = p + (size_t)t * 3072 + (c << 3);
  const float* p1 = p0 + (size_t)3072 * 1024;
  float4 a0 = *(const float4*)p0, a1 = *(const float4*)(p0 + 4);
  float4 b0 = *(const float4*)p1, b1 = *(const float4*)(p1 + 4);
  float4 bb0 = *(const float4*)(bias + (c << 3));
  float4 bb1 = *(const float4*)(bias + (c << 3) + 4);
  float f[8] = {a0.x + b0.x + bb0.x, a0.y + b0.y + bb0.y,
                a0.z + b0.z + bb0.z, a0.w + b0.w + bb0.w,
                a1.x + b1.x + bb1.x, a1.y + b1.y + bb1.y,
                a1.z + b1.z + bb1.z, a1.w + b1.w + bb1.w};
  short8 hv, lv;
#pragma unroll
  for (int e = 0; e < 8; ++e) {
    unsigned hb = bf16rn(f[e]);
    hv[e] = (short)hb;
    lv[e] = (short)bf16rn(f[e] - bf16f(hb));
  }
  size_t off = (size_t)gc << 4;
  *(short8*)(hi + off) = hv;
  *(short8*)(lo + off) = lv;
}

// ---------------- fused QK^T + causal softmax -> att (linear HL) + attlast ----------------
#define QSLDS 2304  // 16 rows * 144B
__global__ void __launch_bounds__(512) qk_softmax(
    const char* __restrict__ qhi, const char* __restrict__ qlo,
    char* __restrict__ attB, float* __restrict__ attlast)
{
  int rb = blockIdx.x, h = blockIdx.y;
  int i0 = rb * 32;
  int tid = threadIdx.x, lane = tid & 63, w = tid >> 6;
  int wr = w >> 2, wcg = w & 3;
  int lr = lane & 15, lc = lane >> 4;
  __shared__ float redm[2][16][4];
  __shared__ float reds[2][16][4];
  __shared__ __align__(16) char tb[8][2 * QSLDS];

  // q fragments (linear global reads)
  int iq = i0 + wr * 16 + lr;
  short8 ah[2], al[2];
  {
    size_t qb = (size_t)iq * 6144 + h * 128;
#pragma unroll
    for (int kh = 0; kh < 2; ++kh) {
      size_t off = qb + ((kh * 4 + lc) << 4);
      ah[kh] = *(const short8*)(qhi + off);
      al[kh] = *(const short8*)(qlo + off);
    }
  }

  f32x4 acc[16];
#pragma unroll
  for (int nt = 0; nt < 16; ++nt) acc[nt] = (f32x4){0.f, 0.f, 0.f, 0.f};

  int maxj = i0 + 31;
  int rel = maxj - wcg * 256;
  int ntEnd = (rel < 0) ? 0 : ((rel >> 4) + 1);
  if (ntEnd > 16) ntEnd = 16;

  for (int nt = 0; nt < ntEnd; ++nt) {
    int jr = wcg * 256 + nt * 16 + lr;
    size_t kb = (size_t)jr * 6144 + 2048 + h * 128;
    short8 bh[2], bl[2];
#pragma unroll
    for (int kh = 0; kh < 2; ++kh) {
      size_t off = kb + ((kh * 4 + lc) << 4);
      bh[kh] = *(const short8*)(qhi + off);
      bl[kh] = *(const short8*)(qlo + off);
    }
#pragma unroll
    for (int kh = 0; kh < 2; ++kh) {
      acc[nt] = __builtin_amdgcn_mfma_f32_16x16x32_bf16(ah[kh], bh[kh], acc[nt], 0, 0, 0);
      acc[nt] = __builtin_amdgcn_mfma_f32_16x16x32_bf16(al[kh], bh[kh], acc[nt], 0, 0, 0);
      acc[nt] = __builtin_amdgcn_mfma_f32_16x16x32_bf16(ah[kh], bl[kh], acc[nt], 0, 0, 0);
    }
  }

  int iv[4];
  float pmax[4];
#pragma unroll
  for (int r = 0; r < 4; ++r) {
    iv[r] = i0 + wr * 16 + lc * 4 + r;
    pmax[r] = -INFINITY;
  }
#pragma unroll
  for (int nt = 0; nt < 16; ++nt) {
    int j = wcg * 256 + nt * 16 + lr;
#pragma unroll
    for (int r = 0; r < 4; ++r) {
      float v = (j <= iv[r]) ? acc[nt][r] * 0.125f : -INFINITY;
      acc[nt][r] = v;
      pmax[r] = fmaxf(pmax[r], v);
    }
  }
#pragma unroll
  for (int o = 1; o <= 8; o <<= 1)
#pragma unroll
    for (int r = 0; r < 4; ++r) pmax[r] = fmaxf(pmax[r], __shfl_xor(pmax[r], o));
  if (lr == 0) {
#pragma unroll
    for (int r = 0; r < 4; ++r) redm[wr][lc * 4 + r][wcg] = pmax[r];
  }
  __syncthreads();
  float rowm[4];
#pragma unroll
  for (int r = 0; r < 4; ++r) {
    float* q = redm[wr][lc * 4 + r];
    rowm[r] = fmaxf(fmaxf(q[0], q[1]), fmaxf(q[2], q[3]));
  }

  float psum[4] = {0.f, 0.f, 0.f, 0.f};
#pragma unroll
  for (int nt = 0; nt < 16; ++nt)
#pragma unroll
    for (int r = 0; r < 4; ++r) {
      float e = __expf(acc[nt][r] - rowm[r]);
      acc[nt][r] = e;
      psum[r] += e;
    }
#pragma unroll
  for (int o = 1; o <= 8; o <<= 1)
#pragma unroll
    for (int r = 0; r < 4; ++r) psum[r] += __shfl_xor(psum[r], o);
  if (lr == 0) {
#pragma unroll
    for (int r = 0; r < 4; ++r) reds[wr][lc * 4 + r][wcg] = psum[r];
  }
  __syncthreads();
  float inv[4];
#pragma unroll
  for (int r = 0; r < 4; ++r) {
    float* q = reds[wr][lc * 4 + r];
    inv[r] = 1.0f / (q[0] + q[1] + q[2] + q[3]);
  }

  // epilogue: LDS round-trip, then fully-contiguous 128B-per-8-lanes stores (linear layout)
  char* mybuf = tb[w];
  int iv0 = i0 + wr * 16;
#pragma unroll
  for (int cc = 0; cc < 4; ++cc) {
#pragma unroll
    for (int q = 0; q < 4; ++q) {
      int nt = cc * 4 + q;
      int col = q * 16 + lr;
#pragma unroll
      for (int r = 0; r < 4; ++r) {
        int row = lc * 4 + r;
        float v = acc[nt][r] * inv[r];
        unsigned hb = bf16rn(v);
        unsigned lb = bf16rn(v - bf16f(hb));
        *(unsigned short*)(mybuf + row * 144 + col * 2) = (unsigned short)hb;
        *(unsigned short*)(mybuf + QSLDS + row * 144 + col * 2) = (unsigned short)lb;
        if (iv[r] == 1023) attlast[(h << 10) + wcg * 256 + cc * 64 + col] = v;
      }
    }
    __syncthreads();
#pragma unroll
    for (int half = 0; half < 2; ++half) {
      int rr = (lane >> 3) + half * 8;
      int c = lane & 7;
      int rowg = iv0 + rr;
      uint4 hv = *(const uint4*)(mybuf + rr * 144 + c * 16);
      uint4 lv = *(const uint4*)(mybuf + QSLDS + rr * 144 + c * 16);
      size_t basep = ((size_t)h << 22) + ((size_t)rowg << 12)
                   + (size_t)(((wcg << 2) + cc) << 7) + (size_t)(c << 4);
      *(uint4*)(attB + basep) = hv;
      *(uint4*)(attB + basep + 2048) = lv;
    }
    __syncthreads();
  }
}

// ---------------- MFMA distance + top-4 ----------------
#define BUFB 16384
__global__ void __launch_bounds__(256, 4) topk_mfma(
    const char* __restrict__ qhi, const char* __restrict__ qlo,
    const char* __restrict__ khi, const char* __restrict__ klo,
    const float* __restrict__ kn2, float* __restrict__ pd, int* __restrict__ pi)
{
  int bid = blockIdx.x;
  int h = bid & 15, ttile = (bid >> 4) & 15, mq = bid >> 8;
  int tid = threadIdx.x, lane = tid & 63, w = tid >> 6;
  int t0 = ttile * 64 + w * 16;
  __shared__ __align__(16) char smem[2 * BUFB];

  short8 bhi[2], blo[2];
  {
    int t = t0 + (lane & 15);
    size_t rb = (size_t)t * 6144 + 2048 + h * 128;
#pragma unroll
    for (int kh = 0; kh < 2; ++kh) {
      size_t off = rb + ((kh * 4 + (lane >> 4)) << 4);
      bhi[kh] = *(const short8*)(qhi + off);
      blo[kh] = *(const short8*)(qlo + off);
    }
  }

  const char* ghi = khi + ((size_t)h * MM + (size_t)mq * MQS) * 128;
  const char* glo = klo + ((size_t)h * MM + (size_t)mq * MQS) * 128;
  const float* gk2 = kn2 + (size_t)h * MM + (size_t)mq * MQS + ((lane >> 4) << 2);

  float ba[4] = {-3.0e38f, -3.0e38f, -3.0e38f, -3.0e38f};
  int   bi_[4] = {-1, -1, -1, -1};

  {
#pragma unroll
    for (int i2 = 0; i2 < 4; ++i2) {
      int s = w * 4 + i2;
      const char* src = (s < 8) ? (ghi + s * 1024) : (glo + (s - 8) * 1024);
      stage_rows8_swz(src, 128, smem + s * 1024, lane);
    }
  }
  __syncthreads();

  int buf = 0;
  const int NIT = MQS / 64;  // 32
  for (int it = 0; it < NIT; ++it) {
    char* cb = smem + buf * BUFB;
    if (it < NIT - 1) {
      char* nb = smem + (buf ^ 1) * BUFB;
      const char* bh = ghi + (size_t)(it + 1) * 8192;
      const char* bl = glo + (size_t)(it + 1) * 8192;
#pragma unroll
      for (int i2 = 0; i2 < 4; ++i2) {
        int s = w * 4 + i2;
        const char* src = (s < 8) ? (bh + s * 1024) : (bl + (s - 8) * 1024);
        stage_rows8_swz(src, 128, nb + s * 1024, lane);
      }
    }

    f32x4 acc[4];
#pragma unroll
    for (int ms = 0; ms < 4; ++ms)
      acc[ms] = *(const f32x4*)(gk2 + it * 64 + ms * 16);
#pragma unroll
    for (int ms = 0; ms < 4; ++ms) {
      int mloc = ms * 16 + (lane & 15);
      short8 ah[2], al[2];
#pragma unroll
      for (int kh = 0; kh < 2; ++kh) {
        int c = kh * 4 + (lane >> 4);
        int off = mloc * 128 + (((c ^ (mloc & 7)) << 4));
        ah[kh] = *(const short8*)(cb + off);
        al[kh] = *(const short8*)(cb + 8192 + off);
      }
#pragma unroll
      for (int kh = 0; kh < 2; ++kh) {
        acc[ms] = __builtin_amdgcn_mfma_f32_16x16x32_bf16(ah[kh], bhi[kh], acc[ms], 0, 0, 0);
        acc[ms] = __builtin_amdgcn_mfma_f32_16x16x32_bf16(al[kh], bhi[kh], acc[ms], 0, 0, 0);
        acc[ms] = __builtin_amdgcn_mfma_f32_16x16x32_bf16(ah[kh], blo[kh], acc[ms], 0, 0, 0);
      }
    }

    float pk[16];
#pragma unroll
    for (int ms = 0; ms < 4; ++ms)
#pragma unroll
      for (int r = 0; r < 4; ++r) {
        unsigned u = __float_as_uint(acc[ms][r]);
        pk[ms * 4 + r] = __uint_as_float((u & ~15u) | (unsigned)(ms * 4 + r));
      }
    float mx = pk[0];
#pragma unroll
    for (int c = 1; c < 16; ++c) mx = fmaxf(mx, pk[c]);

    int mg0 = mq * MQS + it * 64 + ((lane >> 4) << 2);
    while (mx > ba[3]) {
      unsigned pb = __float_as_uint(mx);
      int cl = pb & 15;
      ba[3] = mx; bi_[3] = mg0 + ((cl & 12) << 2) + (cl & 3);
#pragma unroll
      for (int s = 3; s > 0; --s) {
        if (ba[s] > ba[s - 1]) {
          float td = ba[s]; ba[s] = ba[s - 1]; ba[s - 1] = td;
          int ti = bi_[s]; bi_[s] = bi_[s - 1]; bi_[s - 1] = ti;
        }
      }
#pragma unroll
      for (int c2 = 0; c2 < 16; ++c2)
        if (pk[c2] == mx) pk[c2] = -3.0e38f;
      mx = pk[0];
#pragma unroll
      for (int c2 = 1; c2 < 16; ++c2) mx = fmaxf(mx, pk[c2]);
    }

    __syncthreads();
    buf ^= 1;
  }

  float bd[4];
#pragma unroll
  for (int s = 0; s < 4; ++s) bd[s] = ba[s] * -2.0f;
#pragma unroll
  for (int st = 16; st <= 32; st <<= 1) {
    float sd[4]; int si[4];
#pragma unroll
    for (int s = 0; s < 4; ++s) {
      sd[s] = __shfl_xor(bd[s], st);
      si[s] = __shfl_xor(bi_[s], st);
    }
#pragma unroll
    for (int s = 0; s < 4; ++s) ins4(sd[s], si[s], bd, bi_);
  }
  if (lane < 16) {
    size_t o = (((size_t)mq * NH + h) * TT + (t0 + lane)) * 4;
#pragma unroll
    for (int s = 0; s < 4; ++s) { pd[o + s] = bd[s]; pi[o + s] = bi_[s]; }
  }
}

// ---------------- kNN attend: 1024-thr block = (h, 64 t's); LDS-transposed vT store ----------------
__global__ void __launch_bounds__(1024) knn_attend(
    const char* __restrict__ qhi, const char* __restrict__ qlo,
    const float* __restrict__ attlast,
    const float* __restrict__ pd, const int* __restrict__ pi,
    const float* __restrict__ kstore, const float* __restrict__ vstore,
    char* __restrict__ vThi, char* __restrict__ vTlo)
{
  __shared__ __align__(16) unsigned short hiT[64][72];
  __shared__ __align__(16) unsigned short loT[64][72];
  int tid = threadIdx.x, lane = tid & 63, w = tid >> 6;  // 16 waves
  int h = blockIdx.x >> 4, t0 = (blockIdx.x & 15) << 6;

#pragma unroll
  for (int i = 0; i < 4; ++i) {
    int t = t0 + w * 4 + i;
    int g = (h << 10) + t;

    float fd[4]; int fi[4];
    {
      size_t o = ((size_t)(lane & 3) * (NH * TT) + g) * 4;
#pragma unroll
      for (int s = 0; s < 4; ++s) { fd[s] = pd[o + s]; fi[s] = pi[o + s]; }
#pragma unroll
      for (int st = 1; st <= 2; st <<= 1) {
        float sd[4]; int si[4];
#pragma unroll
        for (int s = 0; s < 4; ++s) {
          sd[s] = __shfl_xor(fd[s], st);
          si[s] = __shfl_xor(fi[s], st);
        }
#pragma unroll
        for (int s = 0; s < 4; ++s) ins4(sd[s], si[s], fd, fi);
      }
    }

    size_t rb = (size_t)t * 6144 + h * 128 + lane * 2;
    float q = bf16f(*(const unsigned short*)(qhi + rb)) + bf16f(*(const unsigned short*)(qlo + rb));
    float k = bf16f(*(const unsigned short*)(qhi + rb + 2048)) + bf16f(*(const unsigned short*)(qlo + rb + 2048));
    float v = bf16f(*(const unsigned short*)(qhi + rb + 4096)) + bf16f(*(const unsigned short*)(qlo + rb + 4096));
    float al = attlast[g];
    bool sel = al >= (1.0f / 8192.0f);

    float attf[5], vf[5];
    attf[0] = wredsum(q * k) * 0.125f;
    vf[0] = v;
#pragma unroll
    for (int s = 1; s < 5; ++s) {
      int m = fi[s - 1];
      const float* kp = kstore + ((size_t)h * MM + m) * DD;
      const float* vp = vstore + ((size_t)h * MM + m) * DD;
      attf[s] = wredsum(q * kp[lane]) * 0.125f;
      vf[s] = vp[lane];
    }
    float mx = attf[0];
#pragma unroll
    for (int s = 1; s < 5; ++s) mx = fmaxf(mx, attf[s]);
    float wgt[5], sum = 0.f;
#pragma unroll
    for (int s = 0; s < 5; ++s) { wgt[s] = __expf(attf[s] - mx); sum += wgt[s]; }
    float inv = 1.0f / sum;
    float vals = 0.f;
#pragma unroll
    for (int s = 0; s < 5; ++s) vals = fmaf(wgt[s] * inv, vf[s], vals);
    float r = 0.5f * vals + 0.5f * v;
    float vn = sel ? r : v;

    unsigned hb = bf16rn(vn);
    hiT[lane][t - t0] = (unsigned short)hb;
    loT[lane][t - t0] = (unsigned short)bf16rn(vn - bf16f(hb));
  }
  __syncthreads();

  // contiguous stores: vT row (h*64+r), cols [t0, t0+64)
  int half = tid >> 9;
  int idx = tid & 511;
  int r = idx >> 3, c = idx & 7;
  const unsigned short* src = half ? &loT[r][c * 8] : &hiT[r][c * 8];
  uint4 vv = *(const uint4*)src;
  char* dst = (half ? vTlo : vThi) + (size_t)((h << 6) + r) * 2048 + ((size_t)t0 << 1) + (c << 4);
  *(uint4*)dst = vv;
}

// ---------------- att(linear HL) @ vnewT(linear HL) -> yhl (linear) ----------------
__global__ void __launch_bounds__(256) gemm_attv(
    const char* __restrict__ attB, const char* __restrict__ vThi, const char* __restrict__ vTlo,
    char* __restrict__ Yhi, char* __restrict__ Ylo)
{
  int h = blockIdx.y, m0 = blockIdx.x * 128;
  const char* aBase = attB + (size_t)h * 4194304;
  int tid = threadIdx.x, lane = tid & 63, w = tid >> 6;
  int wr = w >> 1, wc = w & 1;
  __shared__ __align__(16) char smem[49152];
  char* sAhi = smem;
  char* sAlo = smem + 16384;
  char* sBhi = smem + 32768;
  char* sBlo = smem + 40960;
  f32x4 acc[4][2];
#pragma unroll
  for (int i = 0; i < 4; ++i)
#pragma unroll
    for (int j = 0; j < 2; ++j) acc[i][j] = (f32x4){0.f, 0.f, 0.f, 0.f};
  int lr = lane & 15, lc = lane >> 4;
  for (int kb = 0; kb < 16; ++kb) {
    if (kb) __syncthreads();
#pragma unroll
    for (int c8 = 0; c8 < 4; ++c8) {
      int r8 = w * 32 + c8 * 8;
      stage_rows8_swz(aBase + (size_t)(m0 + r8) * 4096 + (size_t)kb * 128, 4096, sAhi + r8 * 128, lane);
      stage_rows8_swz(aBase + (size_t)(m0 + r8) * 4096 + 2048 + (size_t)kb * 128, 4096, sAlo + r8 * 128, lane);
    }
#pragma unroll
    for (int c8 = 0; c8 < 2; ++c8) {
      int r8 = w * 16 + c8 * 8;
      stage_rows8_swz(vThi + (size_t)((h << 6) + r8) * 2048 + (size_t)kb * 128, 2048, sBhi + r8 * 128, lane);
      stage_rows8_swz(vTlo + (size_t)((h << 6) + r8) * 2048 + (size_t)kb * 128, 2048, sBlo + r8 * 128, lane);
    }
    __syncthreads();
#pragma unroll
    for (int kh = 0; kh < 2; ++kh) {
      short8 ah[4], al[4], bh[2], bl[2];
#pragma unroll
      for (int f = 0; f < 4; ++f) {
        int ra = wr * 64 + f * 16 + lr;
        int ca = ((kh * 4 + lc) ^ (ra & 7)) << 4;
        ah[f] = *(const short8*)(sAhi + ra * 128 + ca);
        al[f] = *(const short8*)(sAlo + ra * 128 + ca);
      }
#pragma unroll
      for (int f = 0; f < 2; ++f) {
        int rbr = wc * 32 + f * 16 + lr;
        int cb = ((kh * 4 + lc) ^ (rbr & 7)) << 4;
        bh[f] = *(const short8*)(sBhi + rbr * 128 + cb);
        bl[f] = *(const short8*)(sBlo + rbr * 128 + cb);
      }
#pragma unroll
      for (int mi = 0; mi < 4; ++mi)
#pragma unroll
        for (int nj = 0; nj < 2; ++nj) {
          acc[mi][nj] = __builtin_amdgcn_mfma_f32_16x16x32_bf16(ah[mi], bh[nj], acc[mi][nj], 0, 0, 0);
          acc[mi][nj] = __builtin_amdgcn_mfma_f32_16x16x32_bf16(al[mi], bh[nj], acc[mi][nj], 0, 0, 0);
          acc[mi][nj] = __builtin_amdgcn_mfma_f32_16x16x32_bf16(ah[mi], bl[nj], acc[mi][nj], 0, 0, 0);
        }
    }
  }
#pragma unroll
  for (int mi = 0; mi < 4; ++mi)
#pragma unroll
    for (int nj = 0; nj < 2; ++nj)
#pragma unroll
      for (int r = 0; r < 4; ++r) {
        int m = m0 + wr * 64 + mi * 16 + lc * 4 + r;
        int n = (h << 6) + wc * 32 + nj * 16 + lr;
        float v = acc[mi][nj][r];
        unsigned hb = bf16rn(v);
        size_t off = ((size_t)m * 1024 + n) * 2;
        *(unsigned short*)(Yhi + off) = (unsigned short)hb;
        *(unsigned short*)(Ylo + off) = (unsigned short)bf16rn(v - bf16f(hb));
      }
}

// ---------------- reduce proj K-split partials + bias ----------------
__global__ void __launch_bounds__(256) reduce_bias(
    const float* __restrict__ p, const float* __restrict__ bias, float* __restrict__ out)
{
  int i4 = blockIdx.x * 256 + threadIdx.x;
  const float4* P = (const float4*)p;
  float4 a = P[i4], b = P[i4 + 262144], c = P[i4 + 524288], d = P[i4 + 786432];
  float4 bb = ((const float4*)bias)[i4 & 255];
  float4 o;
  o.x = a.x + b.x + c.x + d.x + bb.x;
  o.y = a.y + b.y + c.y + d.y + bb.y;
  o.z = a.z + b.z + c.z + d.z + bb.z;
  o.w = a.w + b.w + c.w + d.w + bb.w;
  ((float4*)out)[i4] = o;
}

// ---------------- launch ----------------
extern "C" void kernel_launch(void* const* d_in, const int* in_sizes, int n_in,
                              void* d_out, int out_size, void* d_ws, size_t ws_size,
                              hipStream_t stream) {
  (void)in_sizes; (void)n_in; (void)out_size; (void)ws_size;
  const float* x  = (const float*)d_in[0];
  const float* Wa = (const float*)d_in[1];
  const float* ba = (const float*)d_in[2];
  const float* Wp = (const float*)d_in[3];
  const float* bp = (const float*)d_in[4];
  const float* Ks = (const float*)d_in[5];
  const float* Vs = (const float*)d_in[6];
  float* out = (float*)d_out;

  char* base = (char*)d_ws;
  char* xhi  = base;
  char* xlo  = base + 0x200000;
  char* wahi = base + 0x400000;
  char* walo = base + 0xA00000;
  char* khi  = base + 0x1000000;
  char* klo  = base + 0x2000000;
  float* qkvp = (float*)(base + 0x1000000);  // 2 x 12 MB partials overlay khl
  char*  attB = base;                        // att linear HL (h*4MB + i*4KB; hi 2KB + lo 2KB)
  float* pout = (float*)base;
  char* tail = base + 0x4000000;
  char* qhi = tail;
  char* qlo = tail + 0x600000;
  float* attlast = (float*)(tail + 0xC00000);
  float* kn2     = (float*)(tail + 0xC10000);
  float* pd      = (float*)(tail + 0xC90000);
  int*   pi      = (int*)(tail + 0xE90000);
  char* vThi = tail + 0x1090000;
  char* vTlo = tail + 0x1290000;
  char* yhi  = tail + 0x1490000;
  char* ylo  = tail + 0x1690000;
  char* wphi = tail + 0x1890000;
  char* wplo = tail + 0x1A90000;

  // 1) fused convert of x, Wa, Wp (linear HL)
  hipLaunchKernelGGL(convert_all, dim3(2560), dim3(256), 0, stream,
                     x, xhi, xlo, Wa, wahi, walo, Wp, wphi, wplo);
  // 2) qkv = x @ Wa^T (K-split 2, f32 partials into khl region)
  hipLaunchKernelGGL(gemm_hl, dim3(24, 8, 2), dim3(256), 0, stream,
                     (const char*)xhi, (const char*)xlo, 2048, 0, 0,
                     (const char*)wahi, (const char*)walo, 2048, 0, 0,
                     0, 8, 8,
                     qkvp, 3145728LL, 3072,
                     (const float*)nullptr, 1.0f);
  // 3) reduce partials + bias -> qhl (linear)
  hipLaunchKernelGGL(reduce_qkv, dim3(1536), dim3(256), 0, stream, qkvp, ba, qhi, qlo);
  // 4) K_store -> khl (linear) + pre-scaled norms (overwrites partials)
  hipLaunchKernelGGL(convert_kernel, dim3(NH * MM * 8 / 256), dim3(256), 0, stream, Ks, khi, klo, kn2);
  // 5) top-4 over key store
  hipLaunchKernelGGL(topk_mfma, dim3(16 * 16 * MQ), dim3(256), 0, stream,
                     (const char*)qhi, (const char*)qlo, (const char*)khi, (const char*)klo,
                     kn2, pd, pi);
  // 6) fused QK^T + causal softmax -> att linear HL + attlast
  hipLaunchKernelGGL(qk_softmax, dim3(32, 16), dim3(512), 0, stream,
                     (const char*)qhi, (const char*)qlo, attB, attlast);
  // 7) kNN attend (fused quarter merge; LDS-transposed linear vT stores)
  hipLaunchKernelGGL(knn_attend, dim3(256), dim3(1024), 0, stream,
                     (const char*)qhi, (const char*)qlo, attlast, pd, pi, Ks, Vs, vThi, vTlo);
  // 8) y = att @ v_new -> yhl (linear)
  hipLaunchKernelGGL(gemm_attv, dim3(8, 16), dim3(256), 0, stream,
                     (const char*)attB, (const char*)vThi, (const char*)vTlo, yhi, ylo);
  // 9) out = y @ Wp^T + bp (K-split 4 + reduce)
  hipLaunchKernelGGL(gemm_hl, dim3(8, 8, 4), dim3(256), 0, stream,
                     (const char*)yhi, (const char*)ylo, 2048, 0, 0,
                     (const char*)wphi, (const char*)wplo, 2048, 0, 0,
                     0, 4, 4,
                     pout, 1048576LL, 1024,
                     (const float*)nullptr, 1.0f);
  hipLaunchKernelGGL(reduce_bias, dim3(1024), dim3(256), 0, stream, pout, bp, out);
}

// Round 12
// 232.372 us; speedup vs baseline: 1.3896x; 1.2523x over previous
//
#include <hip/hip_runtime.h>
#include <math.h>

#define NH 16
#define TT 1024
#define CC 1024
#define DD 64
#define MM 8192
#define MQ 4
#define MQS (MM / MQ)

typedef __attribute__((ext_vector_type(8))) short short8;
typedef __attribute__((ext_vector_type(4))) float f32x4;

// ---------------- helpers ----------------
__device__ __forceinline__ float wredsum(float x) {
#pragma unroll
  for (int o = 32; o; o >>= 1) x += __shfl_xor(x, o);
  return x;
}
__device__ __forceinline__ unsigned int bf16rn(float x) {
  unsigned int u = __float_as_uint(x);
  return (u + 0x7fffu + ((u >> 16) & 1u)) >> 16;
}
__device__ __forceinline__ float bf16f(unsigned int h) {
  return __uint_as_float(h << 16);
}

__device__ __forceinline__ void ins4(float d, int i, float vd[4], int vi[4]) {
  if (d < vd[3] || (d == vd[3] && i < vi[3])) {
    vd[3] = d; vi[3] = i;
#pragma unroll
    for (int s = 3; s > 0; --s) {
      bool sw = (vd[s] < vd[s - 1]) || (vd[s] == vd[s - 1] && vi[s] < vi[s - 1]);
      if (sw) {
        float td = vd[s]; vd[s] = vd[s - 1]; vd[s - 1] = td;
        int ti = vi[s]; vi[s] = vi[s - 1]; vi[s - 1] = ti;
      }
    }
  }
}

// ---------------- staging (global LINEAR -> LDS swizzled) ----------------
__device__ __forceinline__ void stage_rows8_swz(const char* gRow0, size_t gStride, char* lds, int lane) {
  int rr = lane >> 3;
  int c = (lane & 7) ^ rr;
  __builtin_amdgcn_global_load_lds(
      (const __attribute__((address_space(1))) unsigned int*)(gRow0 + (size_t)rr * gStride + (c << 4)),
      (__attribute__((address_space(3))) unsigned int*)lds, 16, 0, 0);
}

// ---------------- converts (all outputs LINEAR) ----------------
__device__ __forceinline__ void conv_chunk(const float* __restrict__ src,
                                           char* __restrict__ hi, char* __restrict__ lo, int gc) {
  const float* p = src + ((size_t)gc << 3);
  float4 f0 = *(const float4*)p;
  float4 f1 = *(const float4*)(p + 4);
  float f[8] = {f0.x, f0.y, f0.z, f0.w, f1.x, f1.y, f1.z, f1.w};
  short8 hv, lv;
#pragma unroll
  for (int e = 0; e < 8; ++e) {
    unsigned hb = bf16rn(f[e]);
    hv[e] = (short)hb;
    lv[e] = (short)bf16rn(f[e] - bf16f(hb));
  }
  size_t off = (size_t)gc << 4;
  *(short8*)(hi + off) = hv;
  *(short8*)(lo + off) = lv;
}

// fused convert of x (512 blk), Wa (1536 blk), Wp (512 blk)
__global__ void __launch_bounds__(256) convert_all(
    const float* __restrict__ x, char* __restrict__ xhi, char* __restrict__ xlo,
    const float* __restrict__ Wa, char* __restrict__ wahi, char* __restrict__ walo,
    const float* __restrict__ Wp, char* __restrict__ wphi, char* __restrict__ wplo)
{
  int b = blockIdx.x, tid = threadIdx.x;
  if (b < 512) conv_chunk(x, xhi, xlo, b * 256 + tid);
  else if (b < 2048) conv_chunk(Wa, wahi, walo, (b - 512) * 256 + tid);
  else conv_chunk(Wp, wphi, wplo, (b - 2048) * 256 + tid);
}

// K_store -> linear HL + pre-scaled norms; one thread per 8-elem chunk
__global__ void __launch_bounds__(256) convert_kernel(
    const float* __restrict__ ks, char* __restrict__ khi,
    char* __restrict__ klo, float* __restrict__ kn2)
{
  int gc = blockIdx.x * 256 + threadIdx.x;  // chunk id; row = gc>>3
  const float* p = ks + ((size_t)gc << 3);
  float4 f0 = *(const float4*)p;
  float4 f1 = *(const float4*)(p + 4);
  float f[8] = {f0.x, f0.y, f0.z, f0.w, f1.x, f1.y, f1.z, f1.w};
  float s = 0.f;
  short8 hv, lv;
#pragma unroll
  for (int e = 0; e < 8; ++e) {
    s = fmaf(f[e], f[e], s);
    unsigned hb = bf16rn(f[e]);
    hv[e] = (short)hb;
    lv[e] = (short)bf16rn(f[e] - bf16f(hb));
  }
  size_t off = (size_t)gc << 4;
  *(short8*)(khi + off) = hv;
  *(short8*)(klo + off) = lv;
  s += __shfl_xor(s, 1);
  s += __shfl_xor(s, 2);
  s += __shfl_xor(s, 4);
  if ((threadIdx.x & 7) == 0) kn2[gc >> 3] = -0.5f * s;
}

// ---------------- generic split-bf16 MFMA GEMM: C = scale*(A@B^T)+bias ----------------
__global__ void __launch_bounds__(256) gemm_hl(
    const char* __restrict__ Ahi, const char* __restrict__ Alo, int strideA, int aKb0, int aKbz,
    const char* __restrict__ Bhi, const char* __restrict__ Blo, int strideB, int bKb0, int bKbz,
    int kbBeg, int kbCnt, int kbzStep,
    float* __restrict__ Cf, long long czMul, int ldc,
    const float* __restrict__ bias, float scale)
{
  int bx = blockIdx.x, by = blockIdx.y, z = blockIdx.z;
  int n0 = bx * 128, m0 = by * 128;
  int tid = threadIdx.x, lane = tid & 63, w = tid >> 6;
  int wr = w >> 1, wc = w & 1;
  __shared__ __align__(16) char smem[65536];
  char* sAhi = smem;
  char* sAlo = smem + 16384;
  char* sBhi = smem + 32768;
  char* sBlo = smem + 49152;
  f32x4 acc[4][4];
#pragma unroll
  for (int i = 0; i < 4; ++i)
#pragma unroll
    for (int j = 0; j < 4; ++j) acc[i][j] = (f32x4){0.f, 0.f, 0.f, 0.f};

  int kb0 = kbBeg + z * kbzStep;
  int lr = lane & 15, lc = lane >> 4;
  for (int i = 0; i < kbCnt; ++i) {
    int kbA = aKb0 + z * aKbz + kb0 + i;
    int kbB = bKb0 + z * bKbz + kb0 + i;
    if (i) __syncthreads();
#pragma unroll
    for (int c8 = 0; c8 < 4; ++c8) {
      int r8 = w * 32 + c8 * 8;
      stage_rows8_swz(Ahi + (size_t)(m0 + r8) * strideA + (size_t)kbA * 128, strideA, sAhi + r8 * 128, lane);
      stage_rows8_swz(Alo + (size_t)(m0 + r8) * strideA + (size_t)kbA * 128, strideA, sAlo + r8 * 128, lane);
      stage_rows8_swz(Bhi + (size_t)(n0 + r8) * strideB + (size_t)kbB * 128, strideB, sBhi + r8 * 128, lane);
      stage_rows8_swz(Blo + (size_t)(n0 + r8) * strideB + (size_t)kbB * 128, strideB, sBlo + r8 * 128, lane);
    }
    __syncthreads();
#pragma unroll
    for (int kh = 0; kh < 2; ++kh) {
      short8 ah[4], al[4], bh[4], bl[4];
#pragma unroll
      for (int f = 0; f < 4; ++f) {
        int ra = wr * 64 + f * 16 + lr;
        int ca = ((kh * 4 + lc) ^ (ra & 7)) << 4;
        ah[f] = *(const short8*)(sAhi + ra * 128 + ca);
        al[f] = *(const short8*)(sAlo + ra * 128 + ca);
        int rb = wc * 64 + f * 16 + lr;
        int cb = ((kh * 4 + lc) ^ (rb & 7)) << 4;
        bh[f] = *(const short8*)(sBhi + rb * 128 + cb);
        bl[f] = *(const short8*)(sBlo + rb * 128 + cb);
      }
#pragma unroll
      for (int mi = 0; mi < 4; ++mi)
#pragma unroll
        for (int nj = 0; nj < 4; ++nj) {
          acc[mi][nj] = __builtin_amdgcn_mfma_f32_16x16x32_bf16(ah[mi], bh[nj], acc[mi][nj], 0, 0, 0);
          acc[mi][nj] = __builtin_amdgcn_mfma_f32_16x16x32_bf16(al[mi], bh[nj], acc[mi][nj], 0, 0, 0);
          acc[mi][nj] = __builtin_amdgcn_mfma_f32_16x16x32_bf16(ah[mi], bl[nj], acc[mi][nj], 0, 0, 0);
        }
    }
  }
#pragma unroll
  for (int mi = 0; mi < 4; ++mi)
#pragma unroll
    for (int nj = 0; nj < 4; ++nj)
#pragma unroll
      for (int r = 0; r < 4; ++r) {
        int m = m0 + wr * 64 + mi * 16 + lc * 4 + r;
        int n = n0 + wc * 64 + nj * 16 + lr;
        float v = acc[mi][nj][r] * scale;
        if (bias) v += bias[n];
        Cf[(size_t)z * czMul + (size_t)m * ldc + n] = v;
      }
}

// ---------------- reduce qkv K-split(2) partials + bias -> linear HL ----------------
__global__ void __launch_bounds__(256) reduce_qkv(
    const float* __restrict__ p, const float* __restrict__ bias,
    char* __restrict__ hi, char* __restrict__ lo)
{
  int gc = blockIdx.x * 256 + threadIdx.x;  // 1024*384 chunks of 8
  int t = gc / 384, c = gc - t * 384;
  const float* p0 = p + (size_t)t * 3072 + (c << 3);
  const float* p1 = p0 + (size_t)3072 * 1024;
  float4 a0 = *(const float4*)p0, a1 = *(const float4*)(p0 + 4);
  float4 b0 = *(const float4*)p1, b1 = *(const float4*)(p1 + 4);
  float4 bb0 = *(const float4*)(bias + (c << 3));
  float4 bb1 = *(const float4*)(bias + (c << 3) + 4);
  float f[8] = {a0.x + b0.x + bb0.x, a0.y + b0.y + bb0.y,
                a0.z + b0.z + bb0.z, a0.w + b0.w + bb0.w,
                a1.x + b1.x + bb1.x, a1.y + b1.y + bb1.y,
                a1.z + b1.z + bb1.z, a1.w + b1.w + bb1.w};
  short8 hv, lv;
#pragma unroll
  for (int e = 0; e < 8; ++e) {
    unsigned hb = bf16rn(f[e]);
    hv[e] = (short)hb;
    lv[e] = (short)bf16rn(f[e] - bf16f(hb));
  }
  size_t off = (size_t)gc << 4;
  *(short8*)(hi + off) = hv;
  *(short8*)(lo + off) = lv;
}

// ---------------- fused QK^T + causal softmax -> att (linear HL) + attlast ----------------
// FIX vs R11: K-tile loop statically unrolled (16 iters); causal skip is a
// wave-uniform branch INSIDE the unrolled body so acc[] stays in registers
// (runtime trip-count had forced acc to scratch: VGPR=36, 287MB scratch writes).
#define QSLDS 2304  // 16 rows * 144B
__global__ void __launch_bounds__(512) qk_softmax(
    const char* __restrict__ qhi, const char* __restrict__ qlo,
    char* __restrict__ attB, float* __restrict__ attlast)
{
  int rb = blockIdx.x, h = blockIdx.y;
  int i0 = rb * 32;
  int tid = threadIdx.x, lane = tid & 63, w = tid >> 6;
  int wr = w >> 2, wcg = w & 3;
  int lr = lane & 15, lc = lane >> 4;
  __shared__ float redm[2][16][4];
  __shared__ float reds[2][16][4];
  __shared__ __align__(16) char tb[8][2 * QSLDS];

  // q fragments (linear global reads)
  int iq = i0 + wr * 16 + lr;
  short8 ah[2], al[2];
  {
    size_t qb = (size_t)iq * 6144 + h * 128;
#pragma unroll
    for (int kh = 0; kh < 2; ++kh) {
      size_t off = qb + ((kh * 4 + lc) << 4);
      ah[kh] = *(const short8*)(qhi + off);
      al[kh] = *(const short8*)(qlo + off);
    }
  }

  f32x4 acc[16];
#pragma unroll
  for (int nt = 0; nt < 16; ++nt) acc[nt] = (f32x4){0.f, 0.f, 0.f, 0.f};

  int maxj = i0 + 31;  // wave-uniform causal bound
#pragma unroll
  for (int nt = 0; nt < 16; ++nt) {
    if (wcg * 256 + nt * 16 <= maxj) {  // uniform branch; acc index static
      int jr = wcg * 256 + nt * 16 + lr;
      size_t kb = (size_t)jr * 6144 + 2048 + h * 128;
      short8 bh[2], bl[2];
#pragma unroll
      for (int kh = 0; kh < 2; ++kh) {
        size_t off = kb + ((kh * 4 + lc) << 4);
        bh[kh] = *(const short8*)(qhi + off);
        bl[kh] = *(const short8*)(qlo + off);
      }
#pragma unroll
      for (int kh = 0; kh < 2; ++kh) {
        acc[nt] = __builtin_amdgcn_mfma_f32_16x16x32_bf16(ah[kh], bh[kh], acc[nt], 0, 0, 0);
        acc[nt] = __builtin_amdgcn_mfma_f32_16x16x32_bf16(al[kh], bh[kh], acc[nt], 0, 0, 0);
        acc[nt] = __builtin_amdgcn_mfma_f32_16x16x32_bf16(ah[kh], bl[kh], acc[nt], 0, 0, 0);
      }
    }
  }

  int iv[4];
  float pmax[4];
#pragma unroll
  for (int r = 0; r < 4; ++r) {
    iv[r] = i0 + wr * 16 + lc * 4 + r;
    pmax[r] = -INFINITY;
  }
#pragma unroll
  for (int nt = 0; nt < 16; ++nt) {
    int j = wcg * 256 + nt * 16 + lr;
#pragma unroll
    for (int r = 0; r < 4; ++r) {
      float v = (j <= iv[r]) ? acc[nt][r] * 0.125f : -INFINITY;
      acc[nt][r] = v;
      pmax[r] = fmaxf(pmax[r], v);
    }
  }
#pragma unroll
  for (int o = 1; o <= 8; o <<= 1)
#pragma unroll
    for (int r = 0; r < 4; ++r) pmax[r] = fmaxf(pmax[r], __shfl_xor(pmax[r], o));
  if (lr == 0) {
#pragma unroll
    for (int r = 0; r < 4; ++r) redm[wr][lc * 4 + r][wcg] = pmax[r];
  }
  __syncthreads();
  float rowm[4];
#pragma unroll
  for (int r = 0; r < 4; ++r) {
    float* q = redm[wr][lc * 4 + r];
    rowm[r] = fmaxf(fmaxf(q[0], q[1]), fmaxf(q[2], q[3]));
  }

  float psum[4] = {0.f, 0.f, 0.f, 0.f};
#pragma unroll
  for (int nt = 0; nt < 16; ++nt)
#pragma unroll
    for (int r = 0; r < 4; ++r) {
      float e = __expf(acc[nt][r] - rowm[r]);
      acc[nt][r] = e;
      psum[r] += e;
    }
#pragma unroll
  for (int o = 1; o <= 8; o <<= 1)
#pragma unroll
    for (int r = 0; r < 4; ++r) psum[r] += __shfl_xor(psum[r], o);
  if (lr == 0) {
#pragma unroll
    for (int r = 0; r < 4; ++r) reds[wr][lc * 4 + r][wcg] = psum[r];
  }
  __syncthreads();
  float inv[4];
#pragma unroll
  for (int r = 0; r < 4; ++r) {
    float* q = reds[wr][lc * 4 + r];
    inv[r] = 1.0f / (q[0] + q[1] + q[2] + q[3]);
  }

  // epilogue: LDS round-trip, then fully-contiguous 128B-per-8-lanes stores
  char* mybuf = tb[w];
  int iv0 = i0 + wr * 16;
#pragma unroll
  for (int cc = 0; cc < 4; ++cc) {
#pragma unroll
    for (int q = 0; q < 4; ++q) {
      int nt = cc * 4 + q;
      int col = q * 16 + lr;
#pragma unroll
      for (int r = 0; r < 4; ++r) {
        int row = lc * 4 + r;
        float v = acc[nt][r] * inv[r];
        unsigned hb = bf16rn(v);
        unsigned lb = bf16rn(v - bf16f(hb));
        *(unsigned short*)(mybuf + row * 144 + col * 2) = (unsigned short)hb;
        *(unsigned short*)(mybuf + QSLDS + row * 144 + col * 2) = (unsigned short)lb;
        if (iv[r] == 1023) attlast[(h << 10) + wcg * 256 + cc * 64 + col] = v;
      }
    }
    __syncthreads();
#pragma unroll
    for (int half = 0; half < 2; ++half) {
      int rr = (lane >> 3) + half * 8;
      int c = lane & 7;
      int rowg = iv0 + rr;
      uint4 hv = *(const uint4*)(mybuf + rr * 144 + c * 16);
      uint4 lv = *(const uint4*)(mybuf + QSLDS + rr * 144 + c * 16);
      size_t basep = ((size_t)h << 22) + ((size_t)rowg << 12)
                   + (size_t)(((wcg << 2) + cc) << 7) + (size_t)(c << 4);
      *(uint4*)(attB + basep) = hv;
      *(uint4*)(attB + basep + 2048) = lv;
    }
    __syncthreads();
  }
}

// ---------------- MFMA distance + top-4 ----------------
#define BUFB 16384
__global__ void __launch_bounds__(256, 4) topk_mfma(
    const char* __restrict__ qhi, const char* __restrict__ qlo,
    const char* __restrict__ khi, const char* __restrict__ klo,
    const float* __restrict__ kn2, float* __restrict__ pd, int* __restrict__ pi)
{
  int bid = blockIdx.x;
  int h = bid & 15, ttile = (bid >> 4) & 15, mq = bid >> 8;
  int tid = threadIdx.x, lane = tid & 63, w = tid >> 6;
  int t0 = ttile * 64 + w * 16;
  __shared__ __align__(16) char smem[2 * BUFB];

  short8 bhi[2], blo[2];
  {
    int t = t0 + (lane & 15);
    size_t rb = (size_t)t * 6144 + 2048 + h * 128;
#pragma unroll
    for (int kh = 0; kh < 2; ++kh) {
      size_t off = rb + ((kh * 4 + (lane >> 4)) << 4);
      bhi[kh] = *(const short8*)(qhi + off);
      blo[kh] = *(const short8*)(qlo + off);
    }
  }

  const char* ghi = khi + ((size_t)h * MM + (size_t)mq * MQS) * 128;
  const char* glo = klo + ((size_t)h * MM + (size_t)mq * MQS) * 128;
  const float* gk2 = kn2 + (size_t)h * MM + (size_t)mq * MQS + ((lane >> 4) << 2);

  float ba[4] = {-3.0e38f, -3.0e38f, -3.0e38f, -3.0e38f};
  int   bi_[4] = {-1, -1, -1, -1};

  {
#pragma unroll
    for (int i2 = 0; i2 < 4; ++i2) {
      int s = w * 4 + i2;
      const char* src = (s < 8) ? (ghi + s * 1024) : (glo + (s - 8) * 1024);
      stage_rows8_swz(src, 128, smem + s * 1024, lane);
    }
  }
  __syncthreads();

  int buf = 0;
  const int NIT = MQS / 64;  // 32
  for (int it = 0; it < NIT; ++it) {
    char* cb = smem + buf * BUFB;
    if (it < NIT - 1) {
      char* nb = smem + (buf ^ 1) * BUFB;
      const char* bh = ghi + (size_t)(it + 1) * 8192;
      const char* bl = glo + (size_t)(it + 1) * 8192;
#pragma unroll
      for (int i2 = 0; i2 < 4; ++i2) {
        int s = w * 4 + i2;
        const char* src = (s < 8) ? (bh + s * 1024) : (bl + (s - 8) * 1024);
        stage_rows8_swz(src, 128, nb + s * 1024, lane);
      }
    }

    f32x4 acc[4];
#pragma unroll
    for (int ms = 0; ms < 4; ++ms)
      acc[ms] = *(const f32x4*)(gk2 + it * 64 + ms * 16);
#pragma unroll
    for (int ms = 0; ms < 4; ++ms) {
      int mloc = ms * 16 + (lane & 15);
      short8 ah[2], al[2];
#pragma unroll
      for (int kh = 0; kh < 2; ++kh) {
        int c = kh * 4 + (lane >> 4);
        int off = mloc * 128 + (((c ^ (mloc & 7)) << 4));
        ah[kh] = *(const short8*)(cb + off);
        al[kh] = *(const short8*)(cb + 8192 + off);
      }
#pragma unroll
      for (int kh = 0; kh < 2; ++kh) {
        acc[ms] = __builtin_amdgcn_mfma_f32_16x16x32_bf16(ah[kh], bhi[kh], acc[ms], 0, 0, 0);
        acc[ms] = __builtin_amdgcn_mfma_f32_16x16x32_bf16(al[kh], bhi[kh], acc[ms], 0, 0, 0);
        acc[ms] = __builtin_amdgcn_mfma_f32_16x16x32_bf16(ah[kh], blo[kh], acc[ms], 0, 0, 0);
      }
    }

    float pk[16];
#pragma unroll
    for (int ms = 0; ms < 4; ++ms)
#pragma unroll
      for (int r = 0; r < 4; ++r) {
        unsigned u = __float_as_uint(acc[ms][r]);
        pk[ms * 4 + r] = __uint_as_float((u & ~15u) | (unsigned)(ms * 4 + r));
      }
    float mx = pk[0];
#pragma unroll
    for (int c = 1; c < 16; ++c) mx = fmaxf(mx, pk[c]);

    int mg0 = mq * MQS + it * 64 + ((lane >> 4) << 2);
    while (mx > ba[3]) {
      unsigned pb = __float_as_uint(mx);
      int cl = pb & 15;
      ba[3] = mx; bi_[3] = mg0 + ((cl & 12) << 2) + (cl & 3);
#pragma unroll
      for (int s = 3; s > 0; --s) {
        if (ba[s] > ba[s - 1]) {
          float td = ba[s]; ba[s] = ba[s - 1]; ba[s - 1] = td;
          int ti = bi_[s]; bi_[s] = bi_[s - 1]; bi_[s - 1] = ti;
        }
      }
#pragma unroll
      for (int c2 = 0; c2 < 16; ++c2)
        if (pk[c2] == mx) pk[c2] = -3.0e38f;
      mx = pk[0];
#pragma unroll
      for (int c2 = 1; c2 < 16; ++c2) mx = fmaxf(mx, pk[c2]);
    }

    __syncthreads();
    buf ^= 1;
  }

  float bd[4];
#pragma unroll
  for (int s = 0; s < 4; ++s) bd[s] = ba[s] * -2.0f;
#pragma unroll
  for (int st = 16; st <= 32; st <<= 1) {
    float sd[4]; int si[4];
#pragma unroll
    for (int s = 0; s < 4; ++s) {
      sd[s] = __shfl_xor(bd[s], st);
      si[s] = __shfl_xor(bi_[s], st);
    }
#pragma unroll
    for (int s = 0; s < 4; ++s) ins4(sd[s], si[s], bd, bi_);
  }
  if (lane < 16) {
    size_t o = (((size_t)mq * NH + h) * TT + (t0 + lane)) * 4;
#pragma unroll
    for (int s = 0; s < 4; ++s) { pd[o + s] = bd[s]; pi[o + s] = bi_[s]; }
  }
}

// ---------------- kNN attend: 1024-thr block = (h, 64 t's); LDS-transposed vT store ----------------
__global__ void __launch_bounds__(1024) knn_attend(
    const char* __restrict__ qhi, const char* __restrict__ qlo,
    const float* __restrict__ attlast,
    const float* __restrict__ pd, const int* __restrict__ pi,
    const float* __restrict__ kstore, const float* __restrict__ vstore,
    char* __restrict__ vThi, char* __restrict__ vTlo)
{
  __shared__ __align__(16) unsigned short hiT[64][72];
  __shared__ __align__(16) unsigned short loT[64][72];
  int tid = threadIdx.x, lane = tid & 63, w = tid >> 6;  // 16 waves
  int h = blockIdx.x >> 4, t0 = (blockIdx.x & 15) << 6;

#pragma unroll
  for (int i = 0; i < 4; ++i) {
    int t = t0 + w * 4 + i;
    int g = (h << 10) + t;

    float fd[4]; int fi[4];
    {
      size_t o = ((size_t)(lane & 3) * (NH * TT) + g) * 4;
#pragma unroll
      for (int s = 0; s < 4; ++s) { fd[s] = pd[o + s]; fi[s] = pi[o + s]; }
#pragma unroll
      for (int st = 1; st <= 2; st <<= 1) {
        float sd[4]; int si[4];
#pragma unroll
        for (int s = 0; s < 4; ++s) {
          sd[s] = __shfl_xor(fd[s], st);
          si[s] = __shfl_xor(fi[s], st);
        }
#pragma unroll
        for (int s = 0; s < 4; ++s) ins4(sd[s], si[s], fd, fi);
      }
    }

    size_t rb = (size_t)t * 6144 + h * 128 + lane * 2;
    float q = bf16f(*(const unsigned short*)(qhi + rb)) + bf16f(*(const unsigned short*)(qlo + rb));
    float k = bf16f(*(const unsigned short*)(qhi + rb + 2048)) + bf16f(*(const unsigned short*)(qlo + rb + 2048));
    float v = bf16f(*(const unsigned short*)(qhi + rb + 4096)) + bf16f(*(const unsigned short*)(qlo + rb + 4096));
    float al = attlast[g];
    bool sel = al >= (1.0f / 8192.0f);

    float attf[5], vf[5];
    attf[0] = wredsum(q * k) * 0.125f;
    vf[0] = v;
#pragma unroll
    for (int s = 1; s < 5; ++s) {
      int m = fi[s - 1];
      const float* kp = kstore + ((size_t)h * MM + m) * DD;
      const float* vp = vstore + ((size_t)h * MM + m) * DD;
      attf[s] = wredsum(q * kp[lane]) * 0.125f;
      vf[s] = vp[lane];
    }
    float mx = attf[0];
#pragma unroll
    for (int s = 1; s < 5; ++s) mx = fmaxf(mx, attf[s]);
    float wgt[5], sum = 0.f;
#pragma unroll
    for (int s = 0; s < 5; ++s) { wgt[s] = __expf(attf[s] - mx); sum += wgt[s]; }
    float inv = 1.0f / sum;
    float vals = 0.f;
#pragma unroll
    for (int s = 0; s < 5; ++s) vals = fmaf(wgt[s] * inv, vf[s], vals);
    float r = 0.5f * vals + 0.5f * v;
    float vn = sel ? r : v;

    unsigned hb = bf16rn(vn);
    hiT[lane][t - t0] = (unsigned short)hb;
    loT[lane][t - t0] = (unsigned short)bf16rn(vn - bf16f(hb));
  }
  __syncthreads();

  // contiguous stores: vT row (h*64+r), cols [t0, t0+64)
  int half = tid >> 9;
  int idx = tid & 511;
  int r = idx >> 3, c = idx & 7;
  const unsigned short* src = half ? &loT[r][c * 8] : &hiT[r][c * 8];
  uint4 vv = *(const uint4*)src;
  char* dst = (half ? vTlo : vThi) + (size_t)((h << 6) + r) * 2048 + ((size_t)t0 << 1) + (c << 4);
  *(uint4*)dst = vv;
}

// ---------------- att(linear HL) @ vnewT(linear HL) -> yhl (linear) ----------------
__global__ void __launch_bounds__(256) gemm_attv(
    const char* __restrict__ attB, const char* __restrict__ vThi, const char* __restrict__ vTlo,
    char* __restrict__ Yhi, char* __restrict__ Ylo)
{
  int h = blockIdx.y, m0 = blockIdx.x * 128;
  const char* aBase = attB + (size_t)h * 4194304;
  int tid = threadIdx.x, lane = tid & 63, w = tid >> 6;
  int wr = w >> 1, wc = w & 1;
  __shared__ __align__(16) char smem[49152];
  char* sAhi = smem;
  char* sAlo = smem + 16384;
  char* sBhi = smem + 32768;
  char* sBlo = smem + 40960;
  f32x4 acc[4][2];
#pragma unroll
  for (int i = 0; i < 4; ++i)
#pragma unroll
    for (int j = 0; j < 2; ++j) acc[i][j] = (f32x4){0.f, 0.f, 0.f, 0.f};
  int lr = lane & 15, lc = lane >> 4;
  for (int kb = 0; kb < 16; ++kb) {
    if (kb) __syncthreads();
#pragma unroll
    for (int c8 = 0; c8 < 4; ++c8) {
      int r8 = w * 32 + c8 * 8;
      stage_rows8_swz(aBase + (size_t)(m0 + r8) * 4096 + (size_t)kb * 128, 4096, sAhi + r8 * 128, lane);
      stage_rows8_swz(aBase + (size_t)(m0 + r8) * 4096 + 2048 + (size_t)kb * 128, 4096, sAlo + r8 * 128, lane);
    }
#pragma unroll
    for (int c8 = 0; c8 < 2; ++c8) {
      int r8 = w * 16 + c8 * 8;
      stage_rows8_swz(vThi + (size_t)((h << 6) + r8) * 2048 + (size_t)kb * 128, 2048, sBhi + r8 * 128, lane);
      stage_rows8_swz(vTlo + (size_t)((h << 6) + r8) * 2048 + (size_t)kb * 128, 2048, sBlo + r8 * 128, lane);
    }
    __syncthreads();
#pragma unroll
    for (int kh = 0; kh < 2; ++kh) {
      short8 ah[4], al[4], bh[2], bl[2];
#pragma unroll
      for (int f = 0; f < 4; ++f) {
        int ra = wr * 64 + f * 16 + lr;
        int ca = ((kh * 4 + lc) ^ (ra & 7)) << 4;
        ah[f] = *(const short8*)(sAhi + ra * 128 + ca);
        al[f] = *(const short8*)(sAlo + ra * 128 + ca);
      }
#pragma unroll
      for (int f = 0; f < 2; ++f) {
        int rbr = wc * 32 + f * 16 + lr;
        int cb = ((kh * 4 + lc) ^ (rbr & 7)) << 4;
        bh[f] = *(const short8*)(sBhi + rbr * 128 + cb);
        bl[f] = *(const short8*)(sBlo + rbr * 128 + cb);
      }
#pragma unroll
      for (int mi = 0; mi < 4; ++mi)
#pragma unroll
        for (int nj = 0; nj < 2; ++nj) {
          acc[mi][nj] = __builtin_amdgcn_mfma_f32_16x16x32_bf16(ah[mi], bh[nj], acc[mi][nj], 0, 0, 0);
          acc[mi][nj] = __builtin_amdgcn_mfma_f32_16x16x32_bf16(al[mi], bh[nj], acc[mi][nj], 0, 0, 0);
          acc[mi][nj] = __builtin_amdgcn_mfma_f32_16x16x32_bf16(ah[mi], bl[nj], acc[mi][nj], 0, 0, 0);
        }
    }
  }
#pragma unroll
  for (int mi = 0; mi < 4; ++mi)
#pragma unroll
    for (int nj = 0; nj < 2; ++nj)
#pragma unroll
      for (int r = 0; r < 4; ++r) {
        int m = m0 + wr * 64 + mi * 16 + lc * 4 + r;
        int n = (h << 6) + wc * 32 + nj * 16 + lr;
        float v = acc[mi][nj][r];
        unsigned hb = bf16rn(v);
        size_t off = ((size_t)m * 1024 + n) * 2;
        *(unsigned short*)(Yhi + off) = (unsigned short)hb;
        *(unsigned short*)(Ylo + off) = (unsigned short)bf16rn(v - bf16f(hb));
      }
}

// ---------------- reduce proj K-split partials + bias ----------------
__global__ void __launch_bounds__(256) reduce_bias(
    const float* __restrict__ p, const float* __restrict__ bias, float* __restrict__ out)
{
  int i4 = blockIdx.x * 256 + threadIdx.x;
  const float4* P = (const float4*)p;
  float4 a = P[i4], b = P[i4 + 262144], c = P[i4 + 524288], d = P[i4 + 786432];
  float4 bb = ((const float4*)bias)[i4 & 255];
  float4 o;
  o.x = a.x + b.x + c.x + d.x + bb.x;
  o.y = a.y + b.y + c.y + d.y + bb.y;
  o.z = a.z + b.z + c.z + d.z + bb.z;
  o.w = a.w + b.w + c.w + d.w + bb.w;
  ((float4*)out)[i4] = o;
}

// ---------------- launch ----------------
extern "C" void kernel_launch(void* const* d_in, const int* in_sizes, int n_in,
                              void* d_out, int out_size, void* d_ws, size_t ws_size,
                              hipStream_t stream) {
  (void)in_sizes; (void)n_in; (void)out_size; (void)ws_size;
  const float* x  = (const float*)d_in[0];
  const float* Wa = (const float*)d_in[1];
  const float* ba = (const float*)d_in[2];
  const float* Wp = (const float*)d_in[3];
  const float* bp = (const float*)d_in[4];
  const float* Ks = (const float*)d_in[5];
  const float* Vs = (const float*)d_in[6];
  float* out = (float*)d_out;

  char* base = (char*)d_ws;
  char* xhi  = base;
  char* xlo  = base + 0x200000;
  char* wahi = base + 0x400000;
  char* walo = base + 0xA00000;
  char* khi  = base + 0x1000000;
  char* klo  = base + 0x2000000;
  float* qkvp = (float*)(base + 0x1000000);  // 2 x 12 MB partials overlay khl
  char*  attB = base;                        // att linear HL (h*4MB + i*4KB; hi 2KB + lo 2KB)
  float* pout = (float*)base;
  char* tail = base + 0x4000000;
  char* qhi = tail;
  char* qlo = tail + 0x600000;
  float* attlast = (float*)(tail + 0xC00000);
  float* kn2     = (float*)(tail + 0xC10000);
  float* pd      = (float*)(tail + 0xC90000);
  int*   pi      = (int*)(tail + 0xE90000);
  char* vThi = tail + 0x1090000;
  char* vTlo = tail + 0x1290000;
  char* yhi  = tail + 0x1490000;
  char* ylo  = tail + 0x1690000;
  char* wphi = tail + 0x1890000;
  char* wplo = tail + 0x1A90000;

  // 1) fused convert of x, Wa, Wp (linear HL)
  hipLaunchKernelGGL(convert_all, dim3(2560), dim3(256), 0, stream,
                     x, xhi, xlo, Wa, wahi, walo, Wp, wphi, wplo);
  // 2) qkv = x @ Wa^T (K-split 2, f32 partials into khl region)
  hipLaunchKernelGGL(gemm_hl, dim3(24, 8, 2), dim3(256), 0, stream,
                     (const char*)xhi, (const char*)xlo, 2048, 0, 0,
                     (const char*)wahi, (const char*)walo, 2048, 0, 0,
                     0, 8, 8,
                     qkvp, 3145728LL, 3072,
                     (const float*)nullptr, 1.0f);
  // 3) reduce partials + bias -> qhl (linear)
  hipLaunchKernelGGL(reduce_qkv, dim3(1536), dim3(256), 0, stream, qkvp, ba, qhi, qlo);
  // 4) K_store -> khl (linear) + pre-scaled norms (overwrites partials)
  hipLaunchKernelGGL(convert_kernel, dim3(NH * MM * 8 / 256), dim3(256), 0, stream, Ks, khi, klo, kn2);
  // 5) top-4 over key store
  hipLaunchKernelGGL(topk_mfma, dim3(16 * 16 * MQ), dim3(256), 0, stream,
                     (const char*)qhi, (const char*)qlo, (const char*)khi, (const char*)klo,
                     kn2, pd, pi);
  // 6) fused QK^T + causal softmax -> att linear HL + attlast
  hipLaunchKernelGGL(qk_softmax, dim3(32, 16), dim3(512), 0, stream,
                     (const char*)qhi, (const char*)qlo, attB, attlast);
  // 7) kNN attend (fused quarter merge; LDS-transposed linear vT stores)
  hipLaunchKernelGGL(knn_attend, dim3(256), dim3(1024), 0, stream,
                     (const char*)qhi, (const char*)qlo, attlast, pd, pi, Ks, Vs, vThi, vTlo);
  // 8) y = att @ v_new -> yhl (linear)
  hipLaunchKernelGGL(gemm_attv, dim3(8, 16), dim3(256), 0, stream,
                     (const char*)attB, (const char*)vThi, (const char*)vTlo, yhi, ylo);
  // 9) out = y @ Wp^T + bp (K-split 4 + reduce)
  hipLaunchKernelGGL(gemm_hl, dim3(8, 8, 4), dim3(256), 0, stream,
                     (const char*)yhi, (const char*)ylo, 2048, 0, 0,
                     (const char*)wphi, (const char*)wplo, 2048, 0, 0,
                     0, 4, 4,
                     pout, 1048576LL, 1024,
                     (const float*)nullptr, 1.0f);
  hipLaunchKernelGGL(reduce_bias, dim3(1024), dim3(256), 0, stream, pout, bp, out);
}

// Round 13
// 225.902 us; speedup vs baseline: 1.4294x; 1.0286x over previous
//
#include <hip/hip_runtime.h>
#include <math.h>

#define NH 16
#define TT 1024
#define CC 1024
#define DD 64
#define MM 8192
#define MQ 4
#define MQS (MM / MQ)

typedef __attribute__((ext_vector_type(8))) short short8;
typedef __attribute__((ext_vector_type(4))) float f32x4;

// ---------------- helpers ----------------
__device__ __forceinline__ float wredsum(float x) {
#pragma unroll
  for (int o = 32; o; o >>= 1) x += __shfl_xor(x, o);
  return x;
}
__device__ __forceinline__ unsigned int bf16rn(float x) {
  unsigned int u = __float_as_uint(x);
  return (u + 0x7fffu + ((u >> 16) & 1u)) >> 16;
}
__device__ __forceinline__ float bf16f(unsigned int h) {
  return __uint_as_float(h << 16);
}

__device__ __forceinline__ void ins4(float d, int i, float vd[4], int vi[4]) {
  if (d < vd[3] || (d == vd[3] && i < vi[3])) {
    vd[3] = d; vi[3] = i;
#pragma unroll
    for (int s = 3; s > 0; --s) {
      bool sw = (vd[s] < vd[s - 1]) || (vd[s] == vd[s - 1] && vi[s] < vi[s - 1]);
      if (sw) {
        float td = vd[s]; vd[s] = vd[s - 1]; vd[s - 1] = td;
        int ti = vi[s]; vi[s] = vi[s - 1]; vi[s - 1] = ti;
      }
    }
  }
}

// ---------------- staging (global LINEAR -> LDS swizzled) ----------------
__device__ __forceinline__ void stage_rows8_swz(const char* gRow0, size_t gStride, char* lds, int lane) {
  int rr = lane >> 3;
  int c = (lane & 7) ^ rr;
  __builtin_amdgcn_global_load_lds(
      (const __attribute__((address_space(1))) unsigned int*)(gRow0 + (size_t)rr * gStride + (c << 4)),
      (__attribute__((address_space(3))) unsigned int*)lds, 16, 0, 0);
}

// ---------------- converts (all outputs LINEAR) ----------------
__device__ __forceinline__ void conv_chunk(const float* __restrict__ src,
                                           char* __restrict__ hi, char* __restrict__ lo, int gc) {
  const float* p = src + ((size_t)gc << 3);
  float4 f0 = *(const float4*)p;
  float4 f1 = *(const float4*)(p + 4);
  float f[8] = {f0.x, f0.y, f0.z, f0.w, f1.x, f1.y, f1.z, f1.w};
  short8 hv, lv;
#pragma unroll
  for (int e = 0; e < 8; ++e) {
    unsigned hb = bf16rn(f[e]);
    hv[e] = (short)hb;
    lv[e] = (short)bf16rn(f[e] - bf16f(hb));
  }
  size_t off = (size_t)gc << 4;
  *(short8*)(hi + off) = hv;
  *(short8*)(lo + off) = lv;
}

// fused convert of x (512 blk), Wa (1536 blk), Wp (512 blk)
__global__ void __launch_bounds__(256) convert_all(
    const float* __restrict__ x, char* __restrict__ xhi, char* __restrict__ xlo,
    const float* __restrict__ Wa, char* __restrict__ wahi, char* __restrict__ walo,
    const float* __restrict__ Wp, char* __restrict__ wphi, char* __restrict__ wplo)
{
  int b = blockIdx.x, tid = threadIdx.x;
  if (b < 512) conv_chunk(x, xhi, xlo, b * 256 + tid);
  else if (b < 2048) conv_chunk(Wa, wahi, walo, (b - 512) * 256 + tid);
  else conv_chunk(Wp, wphi, wplo, (b - 2048) * 256 + tid);
}

// K_store -> linear HL + pre-scaled norms; one thread per 8-elem chunk
__global__ void __launch_bounds__(256) convert_kernel(
    const float* __restrict__ ks, char* __restrict__ khi,
    char* __restrict__ klo, float* __restrict__ kn2)
{
  int gc = blockIdx.x * 256 + threadIdx.x;  // chunk id; row = gc>>3
  const float* p = ks + ((size_t)gc << 3);
  float4 f0 = *(const float4*)p;
  float4 f1 = *(const float4*)(p + 4);
  float f[8] = {f0.x, f0.y, f0.z, f0.w, f1.x, f1.y, f1.z, f1.w};
  float s = 0.f;
  short8 hv, lv;
#pragma unroll
  for (int e = 0; e < 8; ++e) {
    s = fmaf(f[e], f[e], s);
    unsigned hb = bf16rn(f[e]);
    hv[e] = (short)hb;
    lv[e] = (short)bf16rn(f[e] - bf16f(hb));
  }
  size_t off = (size_t)gc << 4;
  *(short8*)(khi + off) = hv;
  *(short8*)(klo + off) = lv;
  s += __shfl_xor(s, 1);
  s += __shfl_xor(s, 2);
  s += __shfl_xor(s, 4);
  if ((threadIdx.x & 7) == 0) kn2[gc >> 3] = -0.5f * s;
}

// ---------------- generic split-bf16 MFMA GEMM: C = scale*(A@B^T)+bias ----------------
__global__ void __launch_bounds__(256) gemm_hl(
    const char* __restrict__ Ahi, const char* __restrict__ Alo, int strideA, int aKb0, int aKbz,
    const char* __restrict__ Bhi, const char* __restrict__ Blo, int strideB, int bKb0, int bKbz,
    int kbBeg, int kbCnt, int kbzStep,
    float* __restrict__ Cf, long long czMul, int ldc,
    const float* __restrict__ bias, float scale)
{
  int bx = blockIdx.x, by = blockIdx.y, z = blockIdx.z;
  int n0 = bx * 128, m0 = by * 128;
  int tid = threadIdx.x, lane = tid & 63, w = tid >> 6;
  int wr = w >> 1, wc = w & 1;
  __shared__ __align__(16) char smem[65536];
  char* sAhi = smem;
  char* sAlo = smem + 16384;
  char* sBhi = smem + 32768;
  char* sBlo = smem + 49152;
  f32x4 acc[4][4];
#pragma unroll
  for (int i = 0; i < 4; ++i)
#pragma unroll
    for (int j = 0; j < 4; ++j) acc[i][j] = (f32x4){0.f, 0.f, 0.f, 0.f};

  int kb0 = kbBeg + z * kbzStep;
  int lr = lane & 15, lc = lane >> 4;
  for (int i = 0; i < kbCnt; ++i) {
    int kbA = aKb0 + z * aKbz + kb0 + i;
    int kbB = bKb0 + z * bKbz + kb0 + i;
    if (i) __syncthreads();
#pragma unroll
    for (int c8 = 0; c8 < 4; ++c8) {
      int r8 = w * 32 + c8 * 8;
      stage_rows8_swz(Ahi + (size_t)(m0 + r8) * strideA + (size_t)kbA * 128, strideA, sAhi + r8 * 128, lane);
      stage_rows8_swz(Alo + (size_t)(m0 + r8) * strideA + (size_t)kbA * 128, strideA, sAlo + r8 * 128, lane);
      stage_rows8_swz(Bhi + (size_t)(n0 + r8) * strideB + (size_t)kbB * 128, strideB, sBhi + r8 * 128, lane);
      stage_rows8_swz(Blo + (size_t)(n0 + r8) * strideB + (size_t)kbB * 128, strideB, sBlo + r8 * 128, lane);
    }
    __syncthreads();
#pragma unroll
    for (int kh = 0; kh < 2; ++kh) {
      short8 ah[4], al[4], bh[4], bl[4];
#pragma unroll
      for (int f = 0; f < 4; ++f) {
        int ra = wr * 64 + f * 16 + lr;
        int ca = ((kh * 4 + lc) ^ (ra & 7)) << 4;
        ah[f] = *(const short8*)(sAhi + ra * 128 + ca);
        al[f] = *(const short8*)(sAlo + ra * 128 + ca);
        int rb = wc * 64 + f * 16 + lr;
        int cb = ((kh * 4 + lc) ^ (rb & 7)) << 4;
        bh[f] = *(const short8*)(sBhi + rb * 128 + cb);
        bl[f] = *(const short8*)(sBlo + rb * 128 + cb);
      }
#pragma unroll
      for (int mi = 0; mi < 4; ++mi)
#pragma unroll
        for (int nj = 0; nj < 4; ++nj) {
          acc[mi][nj] = __builtin_amdgcn_mfma_f32_16x16x32_bf16(ah[mi], bh[nj], acc[mi][nj], 0, 0, 0);
          acc[mi][nj] = __builtin_amdgcn_mfma_f32_16x16x32_bf16(al[mi], bh[nj], acc[mi][nj], 0, 0, 0);
          acc[mi][nj] = __builtin_amdgcn_mfma_f32_16x16x32_bf16(ah[mi], bl[nj], acc[mi][nj], 0, 0, 0);
        }
    }
  }
#pragma unroll
  for (int mi = 0; mi < 4; ++mi)
#pragma unroll
    for (int nj = 0; nj < 4; ++nj)
#pragma unroll
      for (int r = 0; r < 4; ++r) {
        int m = m0 + wr * 64 + mi * 16 + lc * 4 + r;
        int n = n0 + wc * 64 + nj * 16 + lr;
        float v = acc[mi][nj][r] * scale;
        if (bias) v += bias[n];
        Cf[(size_t)z * czMul + (size_t)m * ldc + n] = v;
      }
}

// ---------------- reduce qkv K-split(2) partials + bias -> linear HL ----------------
__global__ void __launch_bounds__(256) reduce_qkv(
    const float* __restrict__ p, const float* __restrict__ bias,
    char* __restrict__ hi, char* __restrict__ lo)
{
  int gc = blockIdx.x * 256 + threadIdx.x;  // 1024*384 chunks of 8
  int t = gc / 384, c = gc - t * 384;
  const float* p0 = p + (size_t)t * 3072 + (c << 3);
  const float* p1 = p0 + (size_t)3072 * 1024;
  float4 a0 = *(const float4*)p0, a1 = *(const float4*)(p0 + 4);
  float4 b0 = *(const float4*)p1, b1 = *(const float4*)(p1 + 4);
  float4 bb0 = *(const float4*)(bias + (c << 3));
  float4 bb1 = *(const float4*)(bias + (c << 3) + 4);
  float f[8] = {a0.x + b0.x + bb0.x, a0.y + b0.y + bb0.y,
                a0.z + b0.z + bb0.z, a0.w + b0.w + bb0.w,
                a1.x + b1.x + bb1.x, a1.y + b1.y + bb1.y,
                a1.z + b1.z + bb1.z, a1.w + b1.w + bb1.w};
  short8 hv, lv;
#pragma unroll
  for (int e = 0; e < 8; ++e) {
    unsigned hb = bf16rn(f[e]);
    hv[e] = (short)hb;
    lv[e] = (short)bf16rn(f[e] - bf16f(hb));
  }
  size_t off = (size_t)gc << 4;
  *(short8*)(hi + off) = hv;
  *(short8*)(lo + off) = lv;
}

// ---------------- fused QK^T + causal softmax -> att (linear HL) + attlast ----------------
#define QSLDS 2304  // 16 rows * 144B
__global__ void __launch_bounds__(512) qk_softmax(
    const char* __restrict__ qhi, const char* __restrict__ qlo,
    char* __restrict__ attB, float* __restrict__ attlast)
{
  int rb = blockIdx.x, h = blockIdx.y;
  int i0 = rb * 32;
  int tid = threadIdx.x, lane = tid & 63, w = tid >> 6;
  int wr = w >> 2, wcg = w & 3;
  int lr = lane & 15, lc = lane >> 4;
  __shared__ float redm[2][16][4];
  __shared__ float reds[2][16][4];
  __shared__ __align__(16) char tb[8][2 * QSLDS];

  int iq = i0 + wr * 16 + lr;
  short8 ah[2], al[2];
  {
    size_t qb = (size_t)iq * 6144 + h * 128;
#pragma unroll
    for (int kh = 0; kh < 2; ++kh) {
      size_t off = qb + ((kh * 4 + lc) << 4);
      ah[kh] = *(const short8*)(qhi + off);
      al[kh] = *(const short8*)(qlo + off);
    }
  }

  f32x4 acc[16];
#pragma unroll
  for (int nt = 0; nt < 16; ++nt) acc[nt] = (f32x4){0.f, 0.f, 0.f, 0.f};

  int maxj = i0 + 31;  // wave-uniform causal bound
#pragma unroll
  for (int nt = 0; nt < 16; ++nt) {
    if (wcg * 256 + nt * 16 <= maxj) {  // uniform branch; acc index static
      int jr = wcg * 256 + nt * 16 + lr;
      size_t kb = (size_t)jr * 6144 + 2048 + h * 128;
      short8 bh[2], bl[2];
#pragma unroll
      for (int kh = 0; kh < 2; ++kh) {
        size_t off = kb + ((kh * 4 + lc) << 4);
        bh[kh] = *(const short8*)(qhi + off);
        bl[kh] = *(const short8*)(qlo + off);
      }
#pragma unroll
      for (int kh = 0; kh < 2; ++kh) {
        acc[nt] = __builtin_amdgcn_mfma_f32_16x16x32_bf16(ah[kh], bh[kh], acc[nt], 0, 0, 0);
        acc[nt] = __builtin_amdgcn_mfma_f32_16x16x32_bf16(al[kh], bh[kh], acc[nt], 0, 0, 0);
        acc[nt] = __builtin_amdgcn_mfma_f32_16x16x32_bf16(ah[kh], bl[kh], acc[nt], 0, 0, 0);
      }
    }
  }

  int iv[4];
  float pmax[4];
#pragma unroll
  for (int r = 0; r < 4; ++r) {
    iv[r] = i0 + wr * 16 + lc * 4 + r;
    pmax[r] = -INFINITY;
  }
#pragma unroll
  for (int nt = 0; nt < 16; ++nt) {
    int j = wcg * 256 + nt * 16 + lr;
#pragma unroll
    for (int r = 0; r < 4; ++r) {
      float v = (j <= iv[r]) ? acc[nt][r] * 0.125f : -INFINITY;
      acc[nt][r] = v;
      pmax[r] = fmaxf(pmax[r], v);
    }
  }
#pragma unroll
  for (int o = 1; o <= 8; o <<= 1)
#pragma unroll
    for (int r = 0; r < 4; ++r) pmax[r] = fmaxf(pmax[r], __shfl_xor(pmax[r], o));
  if (lr == 0) {
#pragma unroll
    for (int r = 0; r < 4; ++r) redm[wr][lc * 4 + r][wcg] = pmax[r];
  }
  __syncthreads();
  float rowm[4];
#pragma unroll
  for (int r = 0; r < 4; ++r) {
    float* q = redm[wr][lc * 4 + r];
    rowm[r] = fmaxf(fmaxf(q[0], q[1]), fmaxf(q[2], q[3]));
  }

  float psum[4] = {0.f, 0.f, 0.f, 0.f};
#pragma unroll
  for (int nt = 0; nt < 16; ++nt)
#pragma unroll
    for (int r = 0; r < 4; ++r) {
      float e = __expf(acc[nt][r] - rowm[r]);
      acc[nt][r] = e;
      psum[r] += e;
    }
#pragma unroll
  for (int o = 1; o <= 8; o <<= 1)
#pragma unroll
    for (int r = 0; r < 4; ++r) psum[r] += __shfl_xor(psum[r], o);
  if (lr == 0) {
#pragma unroll
    for (int r = 0; r < 4; ++r) reds[wr][lc * 4 + r][wcg] = psum[r];
  }
  __syncthreads();
  float inv[4];
#pragma unroll
  for (int r = 0; r < 4; ++r) {
    float* q = reds[wr][lc * 4 + r];
    inv[r] = 1.0f / (q[0] + q[1] + q[2] + q[3]);
  }

  // epilogue: LDS round-trip, then fully-contiguous 128B-per-8-lanes stores
  char* mybuf = tb[w];
  int iv0 = i0 + wr * 16;
#pragma unroll
  for (int cc = 0; cc < 4; ++cc) {
#pragma unroll
    for (int q = 0; q < 4; ++q) {
      int nt = cc * 4 + q;
      int col = q * 16 + lr;
#pragma unroll
      for (int r = 0; r < 4; ++r) {
        int row = lc * 4 + r;
        float v = acc[nt][r] * inv[r];
        unsigned hb = bf16rn(v);
        unsigned lb = bf16rn(v - bf16f(hb));
        *(unsigned short*)(mybuf + row * 144 + col * 2) = (unsigned short)hb;
        *(unsigned short*)(mybuf + QSLDS + row * 144 + col * 2) = (unsigned short)lb;
        if (iv[r] == 1023) attlast[(h << 10) + wcg * 256 + cc * 64 + col] = v;
      }
    }
    __syncthreads();
#pragma unroll
    for (int half = 0; half < 2; ++half) {
      int rr = (lane >> 3) + half * 8;
      int c = lane & 7;
      int rowg = iv0 + rr;
      uint4 hv = *(const uint4*)(mybuf + rr * 144 + c * 16);
      uint4 lv = *(const uint4*)(mybuf + QSLDS + rr * 144 + c * 16);
      size_t basep = ((size_t)h << 22) + ((size_t)rowg << 12)
                   + (size_t)(((wcg << 2) + cc) << 7) + (size_t)(c << 4);
      *(uint4*)(attB + basep) = hv;
      *(uint4*)(attB + basep + 2048) = lv;
    }
    __syncthreads();
  }
}

// ---------------- MFMA distance + top-4 (static addressing, 2-phase unroll) ----------------
#define BUFB 16384

#define TOPK_STEP(PAR, DO_STAGE)                                              \
  {                                                                           \
    if (DO_STAGE) {                                                           \
      _Pragma("unroll")                                                       \
      for (int i2 = 0; i2 < 4; ++i2) {                                        \
        __builtin_amdgcn_global_load_lds(                                     \
            (const __attribute__((address_space(1))) unsigned int*)stsrc[i2], \
            (__attribute__((address_space(3))) unsigned int*)(stdst[i2] + ((PAR) ^ 16384)), \
            16, 0, 0);                                                        \
        stsrc[i2] += 8192;                                                    \
      }                                                                       \
    }                                                                         \
    f32x4 acc[4];                                                             \
    _Pragma("unroll")                                                         \
    for (int ms = 0; ms < 4; ++ms)                                            \
      acc[ms] = *(const f32x4*)(knp + ms * 64);                               \
    knp += 256;                                                               \
    _Pragma("unroll")                                                         \
    for (int ms = 0; ms < 4; ++ms) {                                          \
      short8 ah0 = *(const short8*)(frg[ms * 2 + 0] + (PAR));                 \
      short8 al0 = *(const short8*)(frg[ms * 2 + 0] + (PAR) + 8192);          \
      short8 ah1 = *(const short8*)(frg[ms * 2 + 1] + (PAR));                 \
      short8 al1 = *(const short8*)(frg[ms * 2 + 1] + (PAR) + 8192);          \
      acc[ms] = __builtin_amdgcn_mfma_f32_16x16x32_bf16(ah0, bhi[0], acc[ms], 0, 0, 0); \
      acc[ms] = __builtin_amdgcn_mfma_f32_16x16x32_bf16(al0, bhi[0], acc[ms], 0, 0, 0); \
      acc[ms] = __builtin_amdgcn_mfma_f32_16x16x32_bf16(ah0, blo[0], acc[ms], 0, 0, 0); \
      acc[ms] = __builtin_amdgcn_mfma_f32_16x16x32_bf16(ah1, bhi[1], acc[ms], 0, 0, 0); \
      acc[ms] = __builtin_amdgcn_mfma_f32_16x16x32_bf16(al1, bhi[1], acc[ms], 0, 0, 0); \
      acc[ms] = __builtin_amdgcn_mfma_f32_16x16x32_bf16(ah1, blo[1], acc[ms], 0, 0, 0); \
    }                                                                         \
    float pk[16];                                                             \
    _Pragma("unroll")                                                         \
    for (int ms = 0; ms < 4; ++ms)                                            \
      _Pragma("unroll")                                                       \
      for (int r = 0; r < 4; ++r) {                                           \
        unsigned u = __float_as_uint(acc[ms][r]);                             \
        pk[ms * 4 + r] = __uint_as_float((u & ~15u) | (unsigned)(ms * 4 + r)); \
      }                                                                       \
    float mx = pk[0];                                                         \
    _Pragma("unroll")                                                         \
    for (int c = 1; c < 16; ++c) mx = fmaxf(mx, pk[c]);                       \
    while (mx > ba[3]) {                                                      \
      unsigned pb = __float_as_uint(mx);                                      \
      int cl = pb & 15;                                                       \
      ba[3] = mx; bi_[3] = mg0 + ((cl & 12) << 2) + (cl & 3);                 \
      _Pragma("unroll")                                                       \
      for (int s = 3; s > 0; --s)                                             \
        if (ba[s] > ba[s - 1]) {                                              \
          float td = ba[s]; ba[s] = ba[s - 1]; ba[s - 1] = td;                \
          int ti = bi_[s]; bi_[s] = bi_[s - 1]; bi_[s - 1] = ti;              \
        }                                                                     \
      _Pragma("unroll")                                                       \
      for (int c2 = 0; c2 < 16; ++c2)                                         \
        if (pk[c2] == mx) pk[c2] = -3.0e38f;                                  \
      mx = pk[0];                                                             \
      _Pragma("unroll")                                                       \
      for (int c2 = 1; c2 < 16; ++c2) mx = fmaxf(mx, pk[c2]);                 \
    }                                                                         \
    mg0 += 64;                                                                \
    __syncthreads();                                                          \
  }

__global__ void __launch_bounds__(256, 4) topk_mfma(
    const char* __restrict__ qhi, const char* __restrict__ qlo,
    const char* __restrict__ khi, const char* __restrict__ klo,
    const float* __restrict__ kn2, float* __restrict__ pd, int* __restrict__ pi)
{
  int bid = blockIdx.x;
  int h = bid & 15, ttile = (bid >> 4) & 15, mq = bid >> 8;
  int tid = threadIdx.x, lane = tid & 63, w = tid >> 6;
  int t0 = ttile * 64 + w * 16;
  __shared__ __align__(16) char smem[2 * BUFB];

  // B fragments: k rows from qkv HL (linear)
  short8 bhi[2], blo[2];
  {
    int t = t0 + (lane & 15);
    size_t rb = (size_t)t * 6144 + 2048 + h * 128;
#pragma unroll
    for (int kh = 0; kh < 2; ++kh) {
      size_t off = rb + ((kh * 4 + (lane >> 4)) << 4);
      bhi[kh] = *(const short8*)(qhi + off);
      blo[kh] = *(const short8*)(qlo + off);
    }
  }

  const char* ghi = khi + ((size_t)h * MM + (size_t)mq * MQS) * 128;
  const char* glo = klo + ((size_t)h * MM + (size_t)mq * MQS) * 128;
  const char* knp = (const char*)(kn2 + (size_t)h * MM + (size_t)mq * MQS + ((lane >> 4) << 2));

  float ba[4] = {-3.0e38f, -3.0e38f, -3.0e38f, -3.0e38f};
  int   bi_[4] = {-1, -1, -1, -1};

  // precomputed per-lane staging sources (linear global, XOR-swizzled chunk) and LDS dests
  const char* stsrc[4];
  char* stdst[4];
  {
    int rr = lane >> 3;
    size_t laneoff = (size_t)rr * 128 + (((lane & 7) ^ rr) << 4);
#pragma unroll
    for (int i2 = 0; i2 < 4; ++i2) {
      int s = w * 4 + i2;
      stsrc[i2] = ((s < 8) ? (ghi + s * 1024) : (glo + (s - 8) * 1024)) + laneoff;
      stdst[i2] = smem + s * 1024;
    }
  }
  // precomputed LDS fragment base addresses (8, loop-invariant)
  char* frg[8];
#pragma unroll
  for (int ms = 0; ms < 4; ++ms)
#pragma unroll
    for (int kh = 0; kh < 2; ++kh) {
      int mloc = ms * 16 + (lane & 15);
      int c = kh * 4 + (lane >> 4);
      frg[ms * 2 + kh] = smem + mloc * 128 + ((c ^ (mloc & 7)) << 4);
    }

  // prologue: stage tile 0 into buf0
#pragma unroll
  for (int i2 = 0; i2 < 4; ++i2) {
    __builtin_amdgcn_global_load_lds(
        (const __attribute__((address_space(1))) unsigned int*)stsrc[i2],
        (__attribute__((address_space(3))) unsigned int*)stdst[i2], 16, 0, 0);
    stsrc[i2] += 8192;
  }
  __syncthreads();

  int mg0 = mq * MQS + ((lane >> 4) << 2);
  for (int it2 = 0; it2 < 16; ++it2) {
    TOPK_STEP(0, true)                 // compute tile 2*it2 (buf0); stage 2*it2+1 -> buf1
    TOPK_STEP(16384, (it2 < 15))       // compute tile 2*it2+1 (buf1); stage 2*it2+2 -> buf0
  }

  // convert keys to ascending-d2 (-2x, monotone reversing), then lane butterfly merge
  float bd[4];
#pragma unroll
  for (int s = 0; s < 4; ++s) bd[s] = ba[s] * -2.0f;
#pragma unroll
  for (int st = 16; st <= 32; st <<= 1) {
    float sd[4]; int si[4];
#pragma unroll
    for (int s = 0; s < 4; ++s) {
      sd[s] = __shfl_xor(bd[s], st);
      si[s] = __shfl_xor(bi_[s], st);
    }
#pragma unroll
    for (int s = 0; s < 4; ++s) ins4(sd[s], si[s], bd, bi_);
  }
  if (lane < 16) {
    size_t o = (((size_t)mq * NH + h) * TT + (t0 + lane)) * 4;
#pragma unroll
    for (int s = 0; s < 4; ++s) { pd[o + s] = bd[s]; pi[o + s] = bi_[s]; }
  }
}

// ---------------- kNN attend: 1024-thr block = (h, 64 t's); LDS-transposed vT store ----------------
__global__ void __launch_bounds__(1024) knn_attend(
    const char* __restrict__ qhi, const char* __restrict__ qlo,
    const float* __restrict__ attlast,
    const float* __restrict__ pd, const int* __restrict__ pi,
    const float* __restrict__ kstore, const float* __restrict__ vstore,
    char* __restrict__ vThi, char* __restrict__ vTlo)
{
  __shared__ __align__(16) unsigned short hiT[64][72];
  __shared__ __align__(16) unsigned short loT[64][72];
  int tid = threadIdx.x, lane = tid & 63, w = tid >> 6;  // 16 waves
  int h = blockIdx.x >> 4, t0 = (blockIdx.x & 15) << 6;

#pragma unroll
  for (int i = 0; i < 4; ++i) {
    int t = t0 + w * 4 + i;
    int g = (h << 10) + t;

    float fd[4]; int fi[4];
    {
      size_t o = ((size_t)(lane & 3) * (NH * TT) + g) * 4;
#pragma unroll
      for (int s = 0; s < 4; ++s) { fd[s] = pd[o + s]; fi[s] = pi[o + s]; }
#pragma unroll
      for (int st = 1; st <= 2; st <<= 1) {
        float sd[4]; int si[4];
#pragma unroll
        for (int s = 0; s < 4; ++s) {
          sd[s] = __shfl_xor(fd[s], st);
          si[s] = __shfl_xor(fi[s], st);
        }
#pragma unroll
        for (int s = 0; s < 4; ++s) ins4(sd[s], si[s], fd, fi);
      }
    }

    size_t rb = (size_t)t * 6144 + h * 128 + lane * 2;
    float q = bf16f(*(const unsigned short*)(qhi + rb)) + bf16f(*(const unsigned short*)(qlo + rb));
    float k = bf16f(*(const unsigned short*)(qhi + rb + 2048)) + bf16f(*(const unsigned short*)(qlo + rb + 2048));
    float v = bf16f(*(const unsigned short*)(qhi + rb + 4096)) + bf16f(*(const unsigned short*)(qlo + rb + 4096));
    float al = attlast[g];
    bool sel = al >= (1.0f / 8192.0f);

    float attf[5], vf[5];
    attf[0] = wredsum(q * k) * 0.125f;
    vf[0] = v;
#pragma unroll
    for (int s = 1; s < 5; ++s) {
      int m = fi[s - 1];
      const float* kp = kstore + ((size_t)h * MM + m) * DD;
      const float* vp = vstore + ((size_t)h * MM + m) * DD;
      attf[s] = wredsum(q * kp[lane]) * 0.125f;
      vf[s] = vp[lane];
    }
    float mx = attf[0];
#pragma unroll
    for (int s = 1; s < 5; ++s) mx = fmaxf(mx, attf[s]);
    float wgt[5], sum = 0.f;
#pragma unroll
    for (int s = 0; s < 5; ++s) { wgt[s] = __expf(attf[s] - mx); sum += wgt[s]; }
    float inv = 1.0f / sum;
    float vals = 0.f;
#pragma unroll
    for (int s = 0; s < 5; ++s) vals = fmaf(wgt[s] * inv, vf[s], vals);
    float r = 0.5f * vals + 0.5f * v;
    float vn = sel ? r : v;

    unsigned hb = bf16rn(vn);
    hiT[lane][t - t0] = (unsigned short)hb;
    loT[lane][t - t0] = (unsigned short)bf16rn(vn - bf16f(hb));
  }
  __syncthreads();

  // contiguous stores: vT row (h*64+r), cols [t0, t0+64)
  int half = tid >> 9;
  int idx = tid & 511;
  int r = idx >> 3, c = idx & 7;
  const unsigned short* src = half ? &loT[r][c * 8] : &hiT[r][c * 8];
  uint4 vv = *(const uint4*)src;
  char* dst = (half ? vTlo : vThi) + (size_t)((h << 6) + r) * 2048 + ((size_t)t0 << 1) + (c << 4);
  *(uint4*)dst = vv;
}

// ---------------- att(linear HL) @ vnewT(linear HL) -> yhl (linear), causal kb skip ----------------
__global__ void __launch_bounds__(256) gemm_attv(
    const char* __restrict__ attB, const char* __restrict__ vThi, const char* __restrict__ vTlo,
    char* __restrict__ Yhi, char* __restrict__ Ylo)
{
  int h = blockIdx.y, m0 = blockIdx.x * 128;
  const char* aBase = attB + (size_t)h * 4194304;
  int tid = threadIdx.x, lane = tid & 63, w = tid >> 6;
  int wr = w >> 1, wc = w & 1;
  __shared__ __align__(16) char smem[49152];
  char* sAhi = smem;
  char* sAlo = smem + 16384;
  char* sBhi = smem + 32768;
  char* sBlo = smem + 40960;
  f32x4 acc[4][2];
#pragma unroll
  for (int i = 0; i < 4; ++i)
#pragma unroll
    for (int j = 0; j < 2; ++j) acc[i][j] = (f32x4){0.f, 0.f, 0.f, 0.f};
  int lr = lane & 15, lc = lane >> 4;
  int kbEnd = ((m0 + 127) >> 6) + 1;  // causal: att cols >= m0+128 are exact zeros
  if (kbEnd > 16) kbEnd = 16;
  for (int kb = 0; kb < kbEnd; ++kb) {
    if (kb) __syncthreads();
#pragma unroll
    for (int c8 = 0; c8 < 4; ++c8) {
      int r8 = w * 32 + c8 * 8;
      stage_rows8_swz(aBase + (size_t)(m0 + r8) * 4096 + (size_t)kb * 128, 4096, sAhi + r8 * 128, lane);
      stage_rows8_swz(aBase + (size_t)(m0 + r8) * 4096 + 2048 + (size_t)kb * 128, 4096, sAlo + r8 * 128, lane);
    }
#pragma unroll
    for (int c8 = 0; c8 < 2; ++c8) {
      int r8 = w * 16 + c8 * 8;
      stage_rows8_swz(vThi + (size_t)((h << 6) + r8) * 2048 + (size_t)kb * 128, 2048, sBhi + r8 * 128, lane);
      stage_rows8_swz(vTlo + (size_t)((h << 6) + r8) * 2048 + (size_t)kb * 128, 2048, sBlo + r8 * 128, lane);
    }
    __syncthreads();
#pragma unroll
    for (int kh = 0; kh < 2; ++kh) {
      short8 ah[4], al[4], bh[2], bl[2];
#pragma unroll
      for (int f = 0; f < 4; ++f) {
        int ra = wr * 64 + f * 16 + lr;
        int ca = ((kh * 4 + lc) ^ (ra & 7)) << 4;
        ah[f] = *(const short8*)(sAhi + ra * 128 + ca);
        al[f] = *(const short8*)(sAlo + ra * 128 + ca);
      }
#pragma unroll
      for (int f = 0; f < 2; ++f) {
        int rbr = wc * 32 + f * 16 + lr;
        int cb = ((kh * 4 + lc) ^ (rbr & 7)) << 4;
        bh[f] = *(const short8*)(sBhi + rbr * 128 + cb);
        bl[f] = *(const short8*)(sBlo + rbr * 128 + cb);
      }
#pragma unroll
      for (int mi = 0; mi < 4; ++mi)
#pragma unroll
        for (int nj = 0; nj < 2; ++nj) {
          acc[mi][nj] = __builtin_amdgcn_mfma_f32_16x16x32_bf16(ah[mi], bh[nj], acc[mi][nj], 0, 0, 0);
          acc[mi][nj] = __builtin_amdgcn_mfma_f32_16x16x32_bf16(al[mi], bh[nj], acc[mi][nj], 0, 0, 0);
          acc[mi][nj] = __builtin_amdgcn_mfma_f32_16x16x32_bf16(ah[mi], bl[nj], acc[mi][nj], 0, 0, 0);
        }
    }
  }
#pragma unroll
  for (int mi = 0; mi < 4; ++mi)
#pragma unroll
    for (int nj = 0; nj < 2; ++nj)
#pragma unroll
      for (int r = 0; r < 4; ++r) {
        int m = m0 + wr * 64 + mi * 16 + lc * 4 + r;
        int n = (h << 6) + wc * 32 + nj * 16 + lr;
        float v = acc[mi][nj][r];
        unsigned hb = bf16rn(v);
        size_t off = ((size_t)m * 1024 + n) * 2;
        *(unsigned short*)(Yhi + off) = (unsigned short)hb;
        *(unsigned short*)(Ylo + off) = (unsigned short)bf16rn(v - bf16f(hb));
      }
}

// ---------------- reduce proj K-split partials + bias ----------------
__global__ void __launch_bounds__(256) reduce_bias(
    const float* __restrict__ p, const float* __restrict__ bias, float* __restrict__ out)
{
  int i4 = blockIdx.x * 256 + threadIdx.x;
  const float4* P = (const float4*)p;
  float4 a = P[i4], b = P[i4 + 262144], c = P[i4 + 524288], d = P[i4 + 786432];
  float4 bb = ((const float4*)bias)[i4 & 255];
  float4 o;
  o.x = a.x + b.x + c.x + d.x + bb.x;
  o.y = a.y + b.y + c.y + d.y + bb.y;
  o.z = a.z + b.z + c.z + d.z + bb.z;
  o.w = a.w + b.w + c.w + d.w + bb.w;
  ((float4*)out)[i4] = o;
}

// ---------------- launch ----------------
extern "C" void kernel_launch(void* const* d_in, const int* in_sizes, int n_in,
                              void* d_out, int out_size, void* d_ws, size_t ws_size,
                              hipStream_t stream) {
  (void)in_sizes; (void)n_in; (void)out_size; (void)ws_size;
  const float* x  = (const float*)d_in[0];
  const float* Wa = (const float*)d_in[1];
  const float* ba = (const float*)d_in[2];
  const float* Wp = (const float*)d_in[3];
  const float* bp = (const float*)d_in[4];
  const float* Ks = (const float*)d_in[5];
  const float* Vs = (const float*)d_in[6];
  float* out = (float*)d_out;

  char* base = (char*)d_ws;
  char* xhi  = base;
  char* xlo  = base + 0x200000;
  char* wahi = base + 0x400000;
  char* walo = base + 0xA00000;
  char* khi  = base + 0x1000000;
  char* klo  = base + 0x2000000;
  float* qkvp = (float*)(base + 0x1000000);  // 2 x 12 MB partials overlay khl
  char*  attB = base;                        // att linear HL (h*4MB + i*4KB; hi 2KB + lo 2KB)
  float* pout = (float*)base;
  char* tail = base + 0x4000000;
  char* qhi = tail;
  char* qlo = tail + 0x600000;
  float* attlast = (float*)(tail + 0xC00000);
  float* kn2     = (float*)(tail + 0xC10000);
  float* pd      = (float*)(tail + 0xC90000);
  int*   pi      = (int*)(tail + 0xE90000);
  char* vThi = tail + 0x1090000;
  char* vTlo = tail + 0x1290000;
  char* yhi  = tail + 0x1490000;
  char* ylo  = tail + 0x1690000;
  char* wphi = tail + 0x1890000;
  char* wplo = tail + 0x1A90000;

  // 1) fused convert of x, Wa, Wp (linear HL)
  hipLaunchKernelGGL(convert_all, dim3(2560), dim3(256), 0, stream,
                     x, xhi, xlo, Wa, wahi, walo, Wp, wphi, wplo);
  // 2) qkv = x @ Wa^T (K-split 2, f32 partials into khl region)
  hipLaunchKernelGGL(gemm_hl, dim3(24, 8, 2), dim3(256), 0, stream,
                     (const char*)xhi, (const char*)xlo, 2048, 0, 0,
                     (const char*)wahi, (const char*)walo, 2048, 0, 0,
                     0, 8, 8,
                     qkvp, 3145728LL, 3072,
                     (const float*)nullptr, 1.0f);
  // 3) reduce partials + bias -> qhl (linear)
  hipLaunchKernelGGL(reduce_qkv, dim3(1536), dim3(256), 0, stream, qkvp, ba, qhi, qlo);
  // 4) K_store -> khl (linear) + pre-scaled norms (overwrites partials)
  hipLaunchKernelGGL(convert_kernel, dim3(NH * MM * 8 / 256), dim3(256), 0, stream, Ks, khi, klo, kn2);
  // 5) top-4 over key store
  hipLaunchKernelGGL(topk_mfma, dim3(16 * 16 * MQ), dim3(256), 0, stream,
                     (const char*)qhi, (const char*)qlo, (const char*)khi, (const char*)klo,
                     kn2, pd, pi);
  // 6) fused QK^T + causal softmax -> att linear HL + attlast
  hipLaunchKernelGGL(qk_softmax, dim3(32, 16), dim3(512), 0, stream,
                     (const char*)qhi, (const char*)qlo, attB, attlast);
  // 7) kNN attend (fused quarter merge; LDS-transposed linear vT stores)
  hipLaunchKernelGGL(knn_attend, dim3(256), dim3(1024), 0, stream,
                     (const char*)qhi, (const char*)qlo, attlast, pd, pi, Ks, Vs, vThi, vTlo);
  // 8) y = att @ v_new -> yhl (linear, causal kb skip)
  hipLaunchKernelGGL(gemm_attv, dim3(8, 16), dim3(256), 0, stream,
                     (const char*)attB, (const char*)vThi, (const char*)vTlo, yhi, ylo);
  // 9) out = y @ Wp^T + bp (K-split 4 + reduce)
  hipLaunchKernelGGL(gemm_hl, dim3(8, 8, 4), dim3(256), 0, stream,
                     (const char*)yhi, (const char*)ylo, 2048, 0, 0,
                     (const char*)wphi, (const char*)wplo, 2048, 0, 0,
                     0, 4, 4,
                     pout, 1048576LL, 1024,
                     (const float*)nullptr, 1.0f);
  hipLaunchKernelGGL(reduce_bias, dim3(1024), dim3(256), 0, stream, pout, bp, out);
}

// Round 14
// 216.989 us; speedup vs baseline: 1.4882x; 1.0411x over previous
//
#include <hip/hip_runtime.h>
#include <math.h>

#define NH 16
#define TT 1024
#define CC 1024
#define DD 64
#define MM 8192
#define MQ 4
#define MQS (MM / MQ)

typedef __attribute__((ext_vector_type(8))) short short8;
typedef __attribute__((ext_vector_type(4))) float f32x4;

// ---------------- helpers ----------------
__device__ __forceinline__ float wredsum(float x) {
#pragma unroll
  for (int o = 32; o; o >>= 1) x += __shfl_xor(x, o);
  return x;
}
__device__ __forceinline__ unsigned int bf16rn(float x) {
  unsigned int u = __float_as_uint(x);
  return (u + 0x7fffu + ((u >> 16) & 1u)) >> 16;
}
__device__ __forceinline__ float bf16f(unsigned int h) {
  return __uint_as_float(h << 16);
}

__device__ __forceinline__ void ins4(float d, int i, float vd[4], int vi[4]) {
  if (d < vd[3] || (d == vd[3] && i < vi[3])) {
    vd[3] = d; vi[3] = i;
#pragma unroll
    for (int s = 3; s > 0; --s) {
      bool sw = (vd[s] < vd[s - 1]) || (vd[s] == vd[s - 1] && vi[s] < vi[s - 1]);
      if (sw) {
        float td = vd[s]; vd[s] = vd[s - 1]; vd[s - 1] = td;
        int ti = vi[s]; vi[s] = vi[s - 1]; vi[s - 1] = ti;
      }
    }
  }
}

// ---------------- staging (global LINEAR -> LDS swizzled) ----------------
__device__ __forceinline__ void stage_rows8_swz(const char* gRow0, size_t gStride, char* lds, int lane) {
  int rr = lane >> 3;
  int c = (lane & 7) ^ rr;
  __builtin_amdgcn_global_load_lds(
      (const __attribute__((address_space(1))) unsigned int*)(gRow0 + (size_t)rr * gStride + (c << 4)),
      (__attribute__((address_space(3))) unsigned int*)lds, 16, 0, 0);
}

// ---------------- fused converts (x, Wa, Wp, K_store+norms) -> LINEAR HL ----------------
__device__ __forceinline__ void conv_chunk(const float* __restrict__ src,
                                           char* __restrict__ hi, char* __restrict__ lo, int gc) {
  const float* p = src + ((size_t)gc << 3);
  float4 f0 = *(const float4*)p;
  float4 f1 = *(const float4*)(p + 4);
  float f[8] = {f0.x, f0.y, f0.z, f0.w, f1.x, f1.y, f1.z, f1.w};
  short8 hv, lv;
#pragma unroll
  for (int e = 0; e < 8; ++e) {
    unsigned hb = bf16rn(f[e]);
    hv[e] = (short)hb;
    lv[e] = (short)bf16rn(f[e] - bf16f(hb));
  }
  size_t off = (size_t)gc << 4;
  *(short8*)(hi + off) = hv;
  *(short8*)(lo + off) = lv;
}

__global__ void __launch_bounds__(256) convert_all(
    const float* __restrict__ x, char* __restrict__ xhi, char* __restrict__ xlo,
    const float* __restrict__ Wa, char* __restrict__ wahi, char* __restrict__ walo,
    const float* __restrict__ Wp, char* __restrict__ wphi, char* __restrict__ wplo,
    const float* __restrict__ ks, char* __restrict__ khi, char* __restrict__ klo,
    float* __restrict__ kn2)
{
  int b = blockIdx.x, tid = threadIdx.x;
  if (b < 512) { conv_chunk(x, xhi, xlo, b * 256 + tid); return; }
  if (b < 2048) { conv_chunk(Wa, wahi, walo, (b - 512) * 256 + tid); return; }
  if (b < 2560) { conv_chunk(Wp, wphi, wplo, (b - 2048) * 256 + tid); return; }
  // K_store arm: one thread per 8-elem chunk; 8 threads/row + shfl norm reduce
  int gc = (b - 2560) * 256 + tid;
  const float* p = ks + ((size_t)gc << 3);
  float4 f0 = *(const float4*)p;
  float4 f1 = *(const float4*)(p + 4);
  float f[8] = {f0.x, f0.y, f0.z, f0.w, f1.x, f1.y, f1.z, f1.w};
  float s = 0.f;
  short8 hv, lv;
#pragma unroll
  for (int e = 0; e < 8; ++e) {
    s = fmaf(f[e], f[e], s);
    unsigned hb = bf16rn(f[e]);
    hv[e] = (short)hb;
    lv[e] = (short)bf16rn(f[e] - bf16f(hb));
  }
  size_t off = (size_t)gc << 4;
  *(short8*)(khi + off) = hv;
  *(short8*)(klo + off) = lv;
  s += __shfl_xor(s, 1);
  s += __shfl_xor(s, 2);
  s += __shfl_xor(s, 4);
  if ((tid & 7) == 0) kn2[gc >> 3] = -0.5f * s;
}

// ---------------- qkv = x @ Wa^T + ba -> linear HL (direct, no K-split) ----------------
// grid (24, 16): 128-col x 64-row tiles; 4 waves (wr=w>>1 m-half 32, wc=w&1 n-half 64)
__global__ void __launch_bounds__(256) gemm_qkv(
    const char* __restrict__ xhi, const char* __restrict__ xlo,
    const char* __restrict__ wahi, const char* __restrict__ walo,
    const float* __restrict__ ba, char* __restrict__ qhi, char* __restrict__ qlo)
{
  int n0 = blockIdx.x * 128, m0 = blockIdx.y * 64;
  int tid = threadIdx.x, lane = tid & 63, w = tid >> 6;
  int wr = w >> 1, wc = w & 1;
  int lr = lane & 15, lc = lane >> 4;
  __shared__ __align__(16) char smem[49152];
  char* sAhi = smem;
  char* sAlo = smem + 8192;
  char* sBhi = smem + 16384;
  char* sBlo = smem + 32768;
  f32x4 acc[2][4];
#pragma unroll
  for (int i = 0; i < 2; ++i)
#pragma unroll
    for (int j = 0; j < 4; ++j) acc[i][j] = (f32x4){0.f, 0.f, 0.f, 0.f};

  for (int kb = 0; kb < 16; ++kb) {
    if (kb) __syncthreads();
#pragma unroll
    for (int c8 = 0; c8 < 2; ++c8) {
      int r8 = w * 16 + c8 * 8;
      stage_rows8_swz(xhi + (size_t)(m0 + r8) * 2048 + (size_t)kb * 128, 2048, sAhi + r8 * 128, lane);
      stage_rows8_swz(xlo + (size_t)(m0 + r8) * 2048 + (size_t)kb * 128, 2048, sAlo + r8 * 128, lane);
    }
#pragma unroll
    for (int c8 = 0; c8 < 4; ++c8) {
      int r8 = w * 32 + c8 * 8;
      stage_rows8_swz(wahi + (size_t)(n0 + r8) * 2048 + (size_t)kb * 128, 2048, sBhi + r8 * 128, lane);
      stage_rows8_swz(walo + (size_t)(n0 + r8) * 2048 + (size_t)kb * 128, 2048, sBlo + r8 * 128, lane);
    }
    __syncthreads();
#pragma unroll
    for (int kh = 0; kh < 2; ++kh) {
      short8 ah[2], al[2], bh[4], bl[4];
#pragma unroll
      for (int mi = 0; mi < 2; ++mi) {
        int ra = wr * 32 + mi * 16 + lr;
        int ca = ((kh * 4 + lc) ^ (ra & 7)) << 4;
        ah[mi] = *(const short8*)(sAhi + ra * 128 + ca);
        al[mi] = *(const short8*)(sAlo + ra * 128 + ca);
      }
#pragma unroll
      for (int nj = 0; nj < 4; ++nj) {
        int rb = wc * 64 + nj * 16 + lr;
        int cb = ((kh * 4 + lc) ^ (rb & 7)) << 4;
        bh[nj] = *(const short8*)(sBhi + rb * 128 + cb);
        bl[nj] = *(const short8*)(sBlo + rb * 128 + cb);
      }
#pragma unroll
      for (int mi = 0; mi < 2; ++mi)
#pragma unroll
        for (int nj = 0; nj < 4; ++nj) {
          acc[mi][nj] = __builtin_amdgcn_mfma_f32_16x16x32_bf16(ah[mi], bh[nj], acc[mi][nj], 0, 0, 0);
          acc[mi][nj] = __builtin_amdgcn_mfma_f32_16x16x32_bf16(al[mi], bh[nj], acc[mi][nj], 0, 0, 0);
          acc[mi][nj] = __builtin_amdgcn_mfma_f32_16x16x32_bf16(ah[mi], bl[nj], acc[mi][nj], 0, 0, 0);
        }
    }
  }

  // epilogue: bias + HL, through reused staging LDS, contiguous 128B stores
  __syncthreads();
  char* hbuf = smem + w * 9216;        // 32 rows x 144B
  char* lbuf = hbuf + 4608;
#pragma unroll
  for (int mi = 0; mi < 2; ++mi)
#pragma unroll
    for (int nj = 0; nj < 4; ++nj)
#pragma unroll
      for (int r = 0; r < 4; ++r) {
        int row = mi * 16 + lc * 4 + r;
        int col = nj * 16 + lr;
        float v = acc[mi][nj][r] + ba[n0 + wc * 64 + col];
        unsigned hb = bf16rn(v);
        *(unsigned short*)(hbuf + row * 144 + col * 2) = (unsigned short)hb;
        *(unsigned short*)(lbuf + row * 144 + col * 2) = (unsigned short)bf16rn(v - bf16f(hb));
      }
  // same-wave LDS RAW: compiler inserts lgkmcnt; buffers are wave-private
#pragma unroll
  for (int ps = 0; ps < 4; ++ps) {
    int rr = ps * 8 + (lane >> 3);
    int c = lane & 7;
    size_t gb = ((size_t)(m0 + wr * 32 + rr) * 3072 + n0 + wc * 64) * 2 + (c << 4);
    *(uint4*)(qhi + gb) = *(const uint4*)(hbuf + rr * 144 + c * 16);
    *(uint4*)(qlo + gb) = *(const uint4*)(lbuf + rr * 144 + c * 16);
  }
}

// ---------------- fused QK^T + causal softmax -> att (linear HL) + attlast ----------------
#define QSLDS 2304  // 16 rows * 144B
__global__ void __launch_bounds__(512) qk_softmax(
    const char* __restrict__ qhi, const char* __restrict__ qlo,
    char* __restrict__ attB, float* __restrict__ attlast)
{
  int rb = blockIdx.x, h = blockIdx.y;
  int i0 = rb * 32;
  int tid = threadIdx.x, lane = tid & 63, w = tid >> 6;
  int wr = w >> 2, wcg = w & 3;
  int lr = lane & 15, lc = lane >> 4;
  __shared__ float redm[2][16][4];
  __shared__ float reds[2][16][4];
  __shared__ __align__(16) char tb[8][2 * QSLDS];

  int iq = i0 + wr * 16 + lr;
  short8 ah[2], al[2];
  {
    size_t qb = (size_t)iq * 6144 + h * 128;
#pragma unroll
    for (int kh = 0; kh < 2; ++kh) {
      size_t off = qb + ((kh * 4 + lc) << 4);
      ah[kh] = *(const short8*)(qhi + off);
      al[kh] = *(const short8*)(qlo + off);
    }
  }

  f32x4 acc[16];
#pragma unroll
  for (int nt = 0; nt < 16; ++nt) acc[nt] = (f32x4){0.f, 0.f, 0.f, 0.f};

  int maxj = i0 + 31;  // wave-uniform causal bound
#pragma unroll
  for (int nt = 0; nt < 16; ++nt) {
    if (wcg * 256 + nt * 16 <= maxj) {  // uniform branch; acc index static
      int jr = wcg * 256 + nt * 16 + lr;
      size_t kb = (size_t)jr * 6144 + 2048 + h * 128;
      short8 bh[2], bl[2];
#pragma unroll
      for (int kh = 0; kh < 2; ++kh) {
        size_t off = kb + ((kh * 4 + lc) << 4);
        bh[kh] = *(const short8*)(qhi + off);
        bl[kh] = *(const short8*)(qlo + off);
      }
#pragma unroll
      for (int kh = 0; kh < 2; ++kh) {
        acc[nt] = __builtin_amdgcn_mfma_f32_16x16x32_bf16(ah[kh], bh[kh], acc[nt], 0, 0, 0);
        acc[nt] = __builtin_amdgcn_mfma_f32_16x16x32_bf16(al[kh], bh[kh], acc[nt], 0, 0, 0);
        acc[nt] = __builtin_amdgcn_mfma_f32_16x16x32_bf16(ah[kh], bl[kh], acc[nt], 0, 0, 0);
      }
    }
  }

  int iv[4];
  float pmax[4];
#pragma unroll
  for (int r = 0; r < 4; ++r) {
    iv[r] = i0 + wr * 16 + lc * 4 + r;
    pmax[r] = -INFINITY;
  }
#pragma unroll
  for (int nt = 0; nt < 16; ++nt) {
    int j = wcg * 256 + nt * 16 + lr;
#pragma unroll
    for (int r = 0; r < 4; ++r) {
      float v = (j <= iv[r]) ? acc[nt][r] * 0.125f : -INFINITY;
      acc[nt][r] = v;
      pmax[r] = fmaxf(pmax[r], v);
    }
  }
#pragma unroll
  for (int o = 1; o <= 8; o <<= 1)
#pragma unroll
    for (int r = 0; r < 4; ++r) pmax[r] = fmaxf(pmax[r], __shfl_xor(pmax[r], o));
  if (lr == 0) {
#pragma unroll
    for (int r = 0; r < 4; ++r) redm[wr][lc * 4 + r][wcg] = pmax[r];
  }
  __syncthreads();
  float rowm[4];
#pragma unroll
  for (int r = 0; r < 4; ++r) {
    float* q = redm[wr][lc * 4 + r];
    rowm[r] = fmaxf(fmaxf(q[0], q[1]), fmaxf(q[2], q[3]));
  }

  float psum[4] = {0.f, 0.f, 0.f, 0.f};
#pragma unroll
  for (int nt = 0; nt < 16; ++nt)
#pragma unroll
    for (int r = 0; r < 4; ++r) {
      float e = __expf(acc[nt][r] - rowm[r]);
      acc[nt][r] = e;
      psum[r] += e;
    }
#pragma unroll
  for (int o = 1; o <= 8; o <<= 1)
#pragma unroll
    for (int r = 0; r < 4; ++r) psum[r] += __shfl_xor(psum[r], o);
  if (lr == 0) {
#pragma unroll
    for (int r = 0; r < 4; ++r) reds[wr][lc * 4 + r][wcg] = psum[r];
  }
  __syncthreads();
  float inv[4];
#pragma unroll
  for (int r = 0; r < 4; ++r) {
    float* q = reds[wr][lc * 4 + r];
    inv[r] = 1.0f / (q[0] + q[1] + q[2] + q[3]);
  }

  char* mybuf = tb[w];
  int iv0 = i0 + wr * 16;
#pragma unroll
  for (int cc = 0; cc < 4; ++cc) {
#pragma unroll
    for (int q = 0; q < 4; ++q) {
      int nt = cc * 4 + q;
      int col = q * 16 + lr;
#pragma unroll
      for (int r = 0; r < 4; ++r) {
        int row = lc * 4 + r;
        float v = acc[nt][r] * inv[r];
        unsigned hb = bf16rn(v);
        unsigned lb = bf16rn(v - bf16f(hb));
        *(unsigned short*)(mybuf + row * 144 + col * 2) = (unsigned short)hb;
        *(unsigned short*)(mybuf + QSLDS + row * 144 + col * 2) = (unsigned short)lb;
        if (iv[r] == 1023) attlast[(h << 10) + wcg * 256 + cc * 64 + col] = v;
      }
    }
    __syncthreads();
#pragma unroll
    for (int half = 0; half < 2; ++half) {
      int rr = (lane >> 3) + half * 8;
      int c = lane & 7;
      int rowg = iv0 + rr;
      uint4 hv = *(const uint4*)(mybuf + rr * 144 + c * 16);
      uint4 lv = *(const uint4*)(mybuf + QSLDS + rr * 144 + c * 16);
      size_t basep = ((size_t)h << 22) + ((size_t)rowg << 12)
                   + (size_t)(((wcg << 2) + cc) << 7) + (size_t)(c << 4);
      *(uint4*)(attB + basep) = hv;
      *(uint4*)(attB + basep + 2048) = lv;
    }
    __syncthreads();
  }
}

// ---------------- MFMA distance + top-4 (static addressing, 2-phase unroll) ----------------
#define BUFB 16384

#define TOPK_STEP(PAR, DO_STAGE)                                              \
  {                                                                           \
    if (DO_STAGE) {                                                           \
      _Pragma("unroll")                                                       \
      for (int i2 = 0; i2 < 4; ++i2) {                                        \
        __builtin_amdgcn_global_load_lds(                                     \
            (const __attribute__((address_space(1))) unsigned int*)stsrc[i2], \
            (__attribute__((address_space(3))) unsigned int*)(stdst[i2] + ((PAR) ^ 16384)), \
            16, 0, 0);                                                        \
        stsrc[i2] += 8192;                                                    \
      }                                                                       \
    }                                                                         \
    f32x4 acc[4];                                                             \
    _Pragma("unroll")                                                         \
    for (int ms = 0; ms < 4; ++ms)                                            \
      acc[ms] = *(const f32x4*)(knp + ms * 64);                               \
    knp += 256;                                                               \
    _Pragma("unroll")                                                         \
    for (int ms = 0; ms < 4; ++ms) {                                          \
      short8 ah0 = *(const short8*)(frg[ms * 2 + 0] + (PAR));                 \
      short8 al0 = *(const short8*)(frg[ms * 2 + 0] + (PAR) + 8192);          \
      short8 ah1 = *(const short8*)(frg[ms * 2 + 1] + (PAR));                 \
      short8 al1 = *(const short8*)(frg[ms * 2 + 1] + (PAR) + 8192);          \
      acc[ms] = __builtin_amdgcn_mfma_f32_16x16x32_bf16(ah0, bhi[0], acc[ms], 0, 0, 0); \
      acc[ms] = __builtin_amdgcn_mfma_f32_16x16x32_bf16(al0, bhi[0], acc[ms], 0, 0, 0); \
      acc[ms] = __builtin_amdgcn_mfma_f32_16x16x32_bf16(ah0, blo[0], acc[ms], 0, 0, 0); \
      acc[ms] = __builtin_amdgcn_mfma_f32_16x16x32_bf16(ah1, bhi[1], acc[ms], 0, 0, 0); \
      acc[ms] = __builtin_amdgcn_mfma_f32_16x16x32_bf16(al1, bhi[1], acc[ms], 0, 0, 0); \
      acc[ms] = __builtin_amdgcn_mfma_f32_16x16x32_bf16(ah1, blo[1], acc[ms], 0, 0, 0); \
    }                                                                         \
    float pk[16];                                                             \
    _Pragma("unroll")                                                         \
    for (int ms = 0; ms < 4; ++ms)                                            \
      _Pragma("unroll")                                                       \
      for (int r = 0; r < 4; ++r) {                                           \
        unsigned u = __float_as_uint(acc[ms][r]);                             \
        pk[ms * 4 + r] = __uint_as_float((u & ~15u) | (unsigned)(ms * 4 + r)); \
      }                                                                       \
    float mx = pk[0];                                                         \
    _Pragma("unroll")                                                         \
    for (int c = 1; c < 16; ++c) mx = fmaxf(mx, pk[c]);                       \
    while (mx > ba[3]) {                                                      \
      unsigned pb = __float_as_uint(mx);                                      \
      int cl = pb & 15;                                                       \
      ba[3] = mx; bi_[3] = mg0 + ((cl & 12) << 2) + (cl & 3);                 \
      _Pragma("unroll")                                                       \
      for (int s = 3; s > 0; --s)                                             \
        if (ba[s] > ba[s - 1]) {                                              \
          float td = ba[s]; ba[s] = ba[s - 1]; ba[s - 1] = td;                \
          int ti = bi_[s]; bi_[s] = bi_[s - 1]; bi_[s - 1] = ti;              \
        }                                                                     \
      _Pragma("unroll")                                                       \
      for (int c2 = 0; c2 < 16; ++c2)                                         \
        if (pk[c2] == mx) pk[c2] = -3.0e38f;                                  \
      mx = pk[0];                                                             \
      _Pragma("unroll")                                                       \
      for (int c2 = 1; c2 < 16; ++c2) mx = fmaxf(mx, pk[c2]);                 \
    }                                                                         \
    mg0 += 64;                                                                \
    __syncthreads();                                                          \
  }

__global__ void __launch_bounds__(256, 4) topk_mfma(
    const char* __restrict__ qhi, const char* __restrict__ qlo,
    const char* __restrict__ khi, const char* __restrict__ klo,
    const float* __restrict__ kn2, float* __restrict__ pd, int* __restrict__ pi)
{
  int bid = blockIdx.x;
  int h = bid & 15, ttile = (bid >> 4) & 15, mq = bid >> 8;
  int tid = threadIdx.x, lane = tid & 63, w = tid >> 6;
  int t0 = ttile * 64 + w * 16;
  __shared__ __align__(16) char smem[2 * BUFB];

  short8 bhi[2], blo[2];
  {
    int t = t0 + (lane & 15);
    size_t rb = (size_t)t * 6144 + 2048 + h * 128;
#pragma unroll
    for (int kh = 0; kh < 2; ++kh) {
      size_t off = rb + ((kh * 4 + (lane >> 4)) << 4);
      bhi[kh] = *(const short8*)(qhi + off);
      blo[kh] = *(const short8*)(qlo + off);
    }
  }

  const char* ghi = khi + ((size_t)h * MM + (size_t)mq * MQS) * 128;
  const char* glo = klo + ((size_t)h * MM + (size_t)mq * MQS) * 128;
  const char* knp = (const char*)(kn2 + (size_t)h * MM + (size_t)mq * MQS + ((lane >> 4) << 2));

  float ba[4] = {-3.0e38f, -3.0e38f, -3.0e38f, -3.0e38f};
  int   bi_[4] = {-1, -1, -1, -1};

  const char* stsrc[4];
  char* stdst[4];
  {
    int rr = lane >> 3;
    size_t laneoff = (size_t)rr * 128 + (((lane & 7) ^ rr) << 4);
#pragma unroll
    for (int i2 = 0; i2 < 4; ++i2) {
      int s = w * 4 + i2;
      stsrc[i2] = ((s < 8) ? (ghi + s * 1024) : (glo + (s - 8) * 1024)) + laneoff;
      stdst[i2] = smem + s * 1024;
    }
  }
  char* frg[8];
#pragma unroll
  for (int ms = 0; ms < 4; ++ms)
#pragma unroll
    for (int kh = 0; kh < 2; ++kh) {
      int mloc = ms * 16 + (lane & 15);
      int c = kh * 4 + (lane >> 4);
      frg[ms * 2 + kh] = smem + mloc * 128 + ((c ^ (mloc & 7)) << 4);
    }

#pragma unroll
  for (int i2 = 0; i2 < 4; ++i2) {
    __builtin_amdgcn_global_load_lds(
        (const __attribute__((address_space(1))) unsigned int*)stsrc[i2],
        (__attribute__((address_space(3))) unsigned int*)stdst[i2], 16, 0, 0);
    stsrc[i2] += 8192;
  }
  __syncthreads();

  int mg0 = mq * MQS + ((lane >> 4) << 2);
  for (int it2 = 0; it2 < 16; ++it2) {
    TOPK_STEP(0, true)
    TOPK_STEP(16384, (it2 < 15))
  }

  float bd[4];
#pragma unroll
  for (int s = 0; s < 4; ++s) bd[s] = ba[s] * -2.0f;
#pragma unroll
  for (int st = 16; st <= 32; st <<= 1) {
    float sd[4]; int si[4];
#pragma unroll
    for (int s = 0; s < 4; ++s) {
      sd[s] = __shfl_xor(bd[s], st);
      si[s] = __shfl_xor(bi_[s], st);
    }
#pragma unroll
    for (int s = 0; s < 4; ++s) ins4(sd[s], si[s], bd, bi_);
  }
  if (lane < 16) {
    size_t o = (((size_t)mq * NH + h) * TT + (t0 + lane)) * 4;
#pragma unroll
    for (int s = 0; s < 4; ++s) { pd[o + s] = bd[s]; pi[o + s] = bi_[s]; }
  }
}

// ---------------- kNN attend: 1024-thr block = (h, 64 t's); LDS-transposed vT store ----------------
__global__ void __launch_bounds__(1024) knn_attend(
    const char* __restrict__ qhi, const char* __restrict__ qlo,
    const float* __restrict__ attlast,
    const float* __restrict__ pd, const int* __restrict__ pi,
    const float* __restrict__ kstore, const float* __restrict__ vstore,
    char* __restrict__ vThi, char* __restrict__ vTlo)
{
  __shared__ __align__(16) unsigned short hiT[64][72];
  __shared__ __align__(16) unsigned short loT[64][72];
  int tid = threadIdx.x, lane = tid & 63, w = tid >> 6;  // 16 waves
  int h = blockIdx.x >> 4, t0 = (blockIdx.x & 15) << 6;

#pragma unroll
  for (int i = 0; i < 4; ++i) {
    int t = t0 + w * 4 + i;
    int g = (h << 10) + t;

    float fd[4]; int fi[4];
    {
      size_t o = ((size_t)(lane & 3) * (NH * TT) + g) * 4;
#pragma unroll
      for (int s = 0; s < 4; ++s) { fd[s] = pd[o + s]; fi[s] = pi[o + s]; }
#pragma unroll
      for (int st = 1; st <= 2; st <<= 1) {
        float sd[4]; int si[4];
#pragma unroll
        for (int s = 0; s < 4; ++s) {
          sd[s] = __shfl_xor(fd[s], st);
          si[s] = __shfl_xor(fi[s], st);
        }
#pragma unroll
        for (int s = 0; s < 4; ++s) ins4(sd[s], si[s], fd, fi);
      }
    }

    size_t rb = (size_t)t * 6144 + h * 128 + lane * 2;
    float q = bf16f(*(const unsigned short*)(qhi + rb)) + bf16f(*(const unsigned short*)(qlo + rb));
    float k = bf16f(*(const unsigned short*)(qhi + rb + 2048)) + bf16f(*(const unsigned short*)(qlo + rb + 2048));
    float v = bf16f(*(const unsigned short*)(qhi + rb + 4096)) + bf16f(*(const unsigned short*)(qlo + rb + 4096));
    float al = attlast[g];
    bool sel = al >= (1.0f / 8192.0f);

    float attf[5], vf[5];
    attf[0] = wredsum(q * k) * 0.125f;
    vf[0] = v;
#pragma unroll
    for (int s = 1; s < 5; ++s) {
      int m = fi[s - 1];
      const float* kp = kstore + ((size_t)h * MM + m) * DD;
      const float* vp = vstore + ((size_t)h * MM + m) * DD;
      attf[s] = wredsum(q * kp[lane]) * 0.125f;
      vf[s] = vp[lane];
    }
    float mx = attf[0];
#pragma unroll
    for (int s = 1; s < 5; ++s) mx = fmaxf(mx, attf[s]);
    float wgt[5], sum = 0.f;
#pragma unroll
    for (int s = 0; s < 5; ++s) { wgt[s] = __expf(attf[s] - mx); sum += wgt[s]; }
    float inv = 1.0f / sum;
    float vals = 0.f;
#pragma unroll
    for (int s = 0; s < 5; ++s) vals = fmaf(wgt[s] * inv, vf[s], vals);
    float r = 0.5f * vals + 0.5f * v;
    float vn = sel ? r : v;

    unsigned hb = bf16rn(vn);
    hiT[lane][t - t0] = (unsigned short)hb;
    loT[lane][t - t0] = (unsigned short)bf16rn(vn - bf16f(hb));
  }
  __syncthreads();

  int half = tid >> 9;
  int idx = tid & 511;
  int r = idx >> 3, c = idx & 7;
  const unsigned short* src = half ? &loT[r][c * 8] : &hiT[r][c * 8];
  uint4 vv = *(const uint4*)src;
  char* dst = (half ? vTlo : vThi) + (size_t)((h << 6) + r) * 2048 + ((size_t)t0 << 1) + (c << 4);
  *(uint4*)dst = vv;
}

// ---------------- att(linear HL) @ vnewT(linear HL) -> yhl (linear), causal kb skip ----------------
__global__ void __launch_bounds__(256) gemm_attv(
    const char* __restrict__ attB, const char* __restrict__ vThi, const char* __restrict__ vTlo,
    char* __restrict__ Yhi, char* __restrict__ Ylo)
{
  int h = blockIdx.y, m0 = blockIdx.x * 128;
  const char* aBase = attB + (size_t)h * 4194304;
  int tid = threadIdx.x, lane = tid & 63, w = tid >> 6;
  int wr = w >> 1, wc = w & 1;
  __shared__ __align__(16) char smem[49152];
  char* sAhi = smem;
  char* sAlo = smem + 16384;
  char* sBhi = smem + 32768;
  char* sBlo = smem + 40960;
  f32x4 acc[4][2];
#pragma unroll
  for (int i = 0; i < 4; ++i)
#pragma unroll
    for (int j = 0; j < 2; ++j) acc[i][j] = (f32x4){0.f, 0.f, 0.f, 0.f};
  int lr = lane & 15, lc = lane >> 4;
  int kbEnd = ((m0 + 127) >> 6) + 1;  // causal: att cols >= m0+128 are exact zeros
  if (kbEnd > 16) kbEnd = 16;
  for (int kb = 0; kb < kbEnd; ++kb) {
    if (kb) __syncthreads();
#pragma unroll
    for (int c8 = 0; c8 < 4; ++c8) {
      int r8 = w * 32 + c8 * 8;
      stage_rows8_swz(aBase + (size_t)(m0 + r8) * 4096 + (size_t)kb * 128, 4096, sAhi + r8 * 128, lane);
      stage_rows8_swz(aBase + (size_t)(m0 + r8) * 4096 + 2048 + (size_t)kb * 128, 4096, sAlo + r8 * 128, lane);
    }
#pragma unroll
    for (int c8 = 0; c8 < 2; ++c8) {
      int r8 = w * 16 + c8 * 8;
      stage_rows8_swz(vThi + (size_t)((h << 6) + r8) * 2048 + (size_t)kb * 128, 2048, sBhi + r8 * 128, lane);
      stage_rows8_swz(vTlo + (size_t)((h << 6) + r8) * 2048 + (size_t)kb * 128, 2048, sBlo + r8 * 128, lane);
    }
    __syncthreads();
#pragma unroll
    for (int kh = 0; kh < 2; ++kh) {
      short8 ah[4], al[4], bh[2], bl[2];
#pragma unroll
      for (int f = 0; f < 4; ++f) {
        int ra = wr * 64 + f * 16 + lr;
        int ca = ((kh * 4 + lc) ^ (ra & 7)) << 4;
        ah[f] = *(const short8*)(sAhi + ra * 128 + ca);
        al[f] = *(const short8*)(sAlo + ra * 128 + ca);
      }
#pragma unroll
      for (int f = 0; f < 2; ++f) {
        int rbr = wc * 32 + f * 16 + lr;
        int cb = ((kh * 4 + lc) ^ (rbr & 7)) << 4;
        bh[f] = *(const short8*)(sBhi + rbr * 128 + cb);
        bl[f] = *(const short8*)(sBlo + rbr * 128 + cb);
      }
#pragma unroll
      for (int mi = 0; mi < 4; ++mi)
#pragma unroll
        for (int nj = 0; nj < 2; ++nj) {
          acc[mi][nj] = __builtin_amdgcn_mfma_f32_16x16x32_bf16(ah[mi], bh[nj], acc[mi][nj], 0, 0, 0);
          acc[mi][nj] = __builtin_amdgcn_mfma_f32_16x16x32_bf16(al[mi], bh[nj], acc[mi][nj], 0, 0, 0);
          acc[mi][nj] = __builtin_amdgcn_mfma_f32_16x16x32_bf16(ah[mi], bl[nj], acc[mi][nj], 0, 0, 0);
        }
    }
  }
#pragma unroll
  for (int mi = 0; mi < 4; ++mi)
#pragma unroll
    for (int nj = 0; nj < 2; ++nj)
#pragma unroll
      for (int r = 0; r < 4; ++r) {
        int m = m0 + wr * 64 + mi * 16 + lc * 4 + r;
        int n = (h << 6) + wc * 32 + nj * 16 + lr;
        float v = acc[mi][nj][r];
        unsigned hb = bf16rn(v);
        size_t off = ((size_t)m * 1024 + n) * 2;
        *(unsigned short*)(Yhi + off) = (unsigned short)hb;
        *(unsigned short*)(Ylo + off) = (unsigned short)bf16rn(v - bf16f(hb));
      }
}

// ---------------- out = y @ Wp^T + bp (direct f32, 64x64 tiles) ----------------
__global__ void __launch_bounds__(256) gemm_out(
    const char* __restrict__ yhi, const char* __restrict__ ylo,
    const char* __restrict__ wphi, const char* __restrict__ wplo,
    const float* __restrict__ bp, float* __restrict__ out)
{
  int n0 = blockIdx.x * 64, m0 = blockIdx.y * 64;
  int tid = threadIdx.x, lane = tid & 63, w = tid >> 6;
  int wr = w >> 1, wc = w & 1;
  int lr = lane & 15, lc = lane >> 4;
  __shared__ __align__(16) char smem[32768];
  char* sAhi = smem;
  char* sAlo = smem + 8192;
  char* sBhi = smem + 16384;
  char* sBlo = smem + 24576;
  f32x4 acc[2][2];
#pragma unroll
  for (int i = 0; i < 2; ++i)
#pragma unroll
    for (int j = 0; j < 2; ++j) acc[i][j] = (f32x4){0.f, 0.f, 0.f, 0.f};

  for (int kb = 0; kb < 16; ++kb) {
    if (kb) __syncthreads();
#pragma unroll
    for (int c8 = 0; c8 < 2; ++c8) {
      int r8 = w * 16 + c8 * 8;
      stage_rows8_swz(yhi + (size_t)(m0 + r8) * 2048 + (size_t)kb * 128, 2048, sAhi + r8 * 128, lane);
      stage_rows8_swz(ylo + (size_t)(m0 + r8) * 2048 + (size_t)kb * 128, 2048, sAlo + r8 * 128, lane);
      stage_rows8_swz(wphi + (size_t)(n0 + r8) * 2048 + (size_t)kb * 128, 2048, sBhi + r8 * 128, lane);
      stage_rows8_swz(wplo + (size_t)(n0 + r8) * 2048 + (size_t)kb * 128, 2048, sBlo + r8 * 128, lane);
    }
    __syncthreads();
#pragma unroll
    for (int kh = 0; kh < 2; ++kh) {
      short8 ah[2], al[2], bh[2], bl[2];
#pragma unroll
      for (int mi = 0; mi < 2; ++mi) {
        int ra = wr * 32 + mi * 16 + lr;
        int ca = ((kh * 4 + lc) ^ (ra & 7)) << 4;
        ah[mi] = *(const short8*)(sAhi + ra * 128 + ca);
        al[mi] = *(const short8*)(sAlo + ra * 128 + ca);
      }
#pragma unroll
      for (int nj = 0; nj < 2; ++nj) {
        int rb = wc * 32 + nj * 16 + lr;
        int cb = ((kh * 4 + lc) ^ (rb & 7)) << 4;
        bh[nj] = *(const short8*)(sBhi + rb * 128 + cb);
        bl[nj] = *(const short8*)(sBlo + rb * 128 + cb);
      }
#pragma unroll
      for (int mi = 0; mi < 2; ++mi)
#pragma unroll
        for (int nj = 0; nj < 2; ++nj) {
          acc[mi][nj] = __builtin_amdgcn_mfma_f32_16x16x32_bf16(ah[mi], bh[nj], acc[mi][nj], 0, 0, 0);
          acc[mi][nj] = __builtin_amdgcn_mfma_f32_16x16x32_bf16(al[mi], bh[nj], acc[mi][nj], 0, 0, 0);
          acc[mi][nj] = __builtin_amdgcn_mfma_f32_16x16x32_bf16(ah[mi], bl[nj], acc[mi][nj], 0, 0, 0);
        }
    }
  }
#pragma unroll
  for (int mi = 0; mi < 2; ++mi)
#pragma unroll
    for (int nj = 0; nj < 2; ++nj)
#pragma unroll
      for (int r = 0; r < 4; ++r) {
        int m = m0 + wr * 32 + mi * 16 + lc * 4 + r;
        int n = n0 + wc * 32 + nj * 16 + lr;
        out[(size_t)m * 1024 + n] = acc[mi][nj][r] + bp[n];
      }
}

// ---------------- launch ----------------
extern "C" void kernel_launch(void* const* d_in, const int* in_sizes, int n_in,
                              void* d_out, int out_size, void* d_ws, size_t ws_size,
                              hipStream_t stream) {
  (void)in_sizes; (void)n_in; (void)out_size; (void)ws_size;
  const float* x  = (const float*)d_in[0];
  const float* Wa = (const float*)d_in[1];
  const float* ba = (const float*)d_in[2];
  const float* Wp = (const float*)d_in[3];
  const float* bp = (const float*)d_in[4];
  const float* Ks = (const float*)d_in[5];
  const float* Vs = (const float*)d_in[6];
  float* out = (float*)d_out;

  char* base = (char*)d_ws;
  char* xhi  = base;
  char* xlo  = base + 0x200000;
  char* wahi = base + 0x400000;
  char* walo = base + 0xA00000;
  char* khi  = base + 0x1000000;
  char* klo  = base + 0x2000000;
  char*  attB = base;                        // att linear HL overlays x/Wa/K regions (all dead)
  char* tail = base + 0x4000000;
  char* qhi = tail;
  char* qlo = tail + 0x600000;
  float* attlast = (float*)(tail + 0xC00000);
  float* kn2     = (float*)(tail + 0xC10000);
  float* pd      = (float*)(tail + 0xC90000);
  int*   pi      = (int*)(tail + 0xE90000);
  char* vThi = tail + 0x1090000;
  char* vTlo = tail + 0x1290000;
  char* yhi  = tail + 0x1490000;
  char* ylo  = tail + 0x1690000;
  char* wphi = tail + 0x1890000;
  char* wplo = tail + 0x1A90000;

  // 1) fused converts: x, Wa, Wp, K_store (+ pre-scaled norms), all linear HL
  hipLaunchKernelGGL(convert_all, dim3(6656), dim3(256), 0, stream,
                     x, xhi, xlo, Wa, wahi, walo, Wp, wphi, wplo, Ks, khi, klo, kn2);
  // 2) qkv = x @ Wa^T + ba -> qhl (direct, no K-split, no partials)
  hipLaunchKernelGGL(gemm_qkv, dim3(24, 16), dim3(256), 0, stream,
                     (const char*)xhi, (const char*)xlo, (const char*)wahi, (const char*)walo,
                     ba, qhi, qlo);
  // 3) top-4 over key store (partial per M-quarter; merged inside knn_attend)
  hipLaunchKernelGGL(topk_mfma, dim3(16 * 16 * MQ), dim3(256), 0, stream,
                     (const char*)qhi, (const char*)qlo, (const char*)khi, (const char*)klo,
                     kn2, pd, pi);
  // 4) fused QK^T + causal softmax -> att linear HL + attlast
  hipLaunchKernelGGL(qk_softmax, dim3(32, 16), dim3(512), 0, stream,
                     (const char*)qhi, (const char*)qlo, attB, attlast);
  // 5) kNN attend (fused quarter merge; LDS-transposed linear vT stores)
  hipLaunchKernelGGL(knn_attend, dim3(256), dim3(1024), 0, stream,
                     (const char*)qhi, (const char*)qlo, attlast, pd, pi, Ks, Vs, vThi, vTlo);
  // 6) y = att @ v_new -> yhl (linear, causal kb skip)
  hipLaunchKernelGGL(gemm_attv, dim3(8, 16), dim3(256), 0, stream,
                     (const char*)attB, (const char*)vThi, (const char*)vTlo, yhi, ylo);
  // 7) out = y @ Wp^T + bp (direct f32)
  hipLaunchKernelGGL(gemm_out, dim3(16, 16), dim3(256), 0, stream,
                     (const char*)yhi, (const char*)ylo, (const char*)wphi, (const char*)wplo,
                     bp, out);
}